// Round 1
// baseline (14915.472 us; speedup 1.0000x reference)
//
#include <hip/hip_runtime.h>
#include <math.h>

// Problem dims
constexpr int Bb  = 8;
constexpr int Ss  = 512;
constexpr int Hh  = 768;
constexpr int Ll  = 12;
constexpr int NHh = 12;
constexpr int Ff  = 3072;
constexpr int Vv  = 21128;
constexpr int DHh = 64;
constexpr int Mm  = Bb * Ss;   // 4096
constexpr int SEP_ID = 102;

// ---------------------------------------------------------------------------
// 1. Find first SEP per batch
//    info[b*4+0] = first index (0x7fffffff if none)
//    info[b*4+1] = has_sep
//    info[b*4+2] = min(first, S-2) (bias sep)
// ---------------------------------------------------------------------------
__global__ __launch_bounds__(512) void sep_kernel(const int* __restrict__ ids,
                                                  int* __restrict__ info)
{
    int b = blockIdx.x;
    int t = threadIdx.x;
    int v = (ids[b * Ss + t] == SEP_ID) ? t : 0x7FFFFFFF;
    #pragma unroll
    for (int off = 32; off; off >>= 1) {
        int o = __shfl_xor(v, off);
        v = min(v, o);
    }
    __shared__ int wmin[8];
    int lane = t & 63, wid = t >> 6;
    if (lane == 0) wmin[wid] = v;
    __syncthreads();
    if (t == 0) {
        int first = wmin[0];
        #pragma unroll
        for (int w = 1; w < 8; w++) first = min(first, wmin[w]);
        int has = (first != 0x7FFFFFFF) ? 1 : 0;
        info[b * 4 + 0] = first;
        info[b * 4 + 1] = has;
        info[b * 4 + 2] = has ? min(first, Ss - 2) : (Ss + 1);
    }
}

// ---------------------------------------------------------------------------
// 2. Embedding + LayerNorm (one block per token, 256 thr, 3 elems/thread)
// ---------------------------------------------------------------------------
__global__ __launch_bounds__(256) void embed_ln_kernel(
    const int* __restrict__ ids, const float* __restrict__ we,
    const float* __restrict__ pe, const float* __restrict__ te,
    const float* __restrict__ g, const float* __restrict__ bp,
    float* __restrict__ x)
{
    int tok = blockIdx.x;
    int s = tok & (Ss - 1);
    int tid = threadIdx.x;
    int id = ids[tok];
    float e[3];
    #pragma unroll
    for (int r = 0; r < 3; r++) {
        int h = tid + (r << 8);
        e[r] = we[(size_t)id * Hh + h] + pe[(size_t)s * Hh + h] + te[h];
    }
    float sum = e[0] + e[1] + e[2];
    float sq  = fmaf(e[0], e[0], fmaf(e[1], e[1], e[2] * e[2]));
    #pragma unroll
    for (int off = 32; off; off >>= 1) {
        sum += __shfl_xor(sum, off);
        sq  += __shfl_xor(sq, off);
    }
    __shared__ float red[8];
    int lane = tid & 63, wid = tid >> 6;
    if (lane == 0) { red[wid] = sum; red[4 + wid] = sq; }
    __syncthreads();
    sum = red[0] + red[1] + red[2] + red[3];
    sq  = red[4] + red[5] + red[6] + red[7];
    float mean = sum * (1.0f / Hh);
    float var  = sq * (1.0f / Hh) - mean * mean;
    float rstd = rsqrtf(var + 1e-12f);
    #pragma unroll
    for (int r = 0; r < 3; r++) {
        int h = tid + (r << 8);
        x[(size_t)tok * Hh + h] = (e[r] - mean) * rstd * g[h] + bp[h];
    }
}

// ---------------------------------------------------------------------------
// 3. Residual + LayerNorm: out = LN(resid + y)
// ---------------------------------------------------------------------------
__global__ __launch_bounds__(256) void resid_ln_kernel(
    const float* __restrict__ resid, const float* __restrict__ y,
    const float* __restrict__ g, const float* __restrict__ bp,
    float* __restrict__ out)
{
    int tok = blockIdx.x;
    int tid = threadIdx.x;
    float e[3];
    #pragma unroll
    for (int r = 0; r < 3; r++) {
        int h = tid + (r << 8);
        size_t idx = (size_t)tok * Hh + h;
        e[r] = resid[idx] + y[idx];
    }
    float sum = e[0] + e[1] + e[2];
    float sq  = fmaf(e[0], e[0], fmaf(e[1], e[1], e[2] * e[2]));
    #pragma unroll
    for (int off = 32; off; off >>= 1) {
        sum += __shfl_xor(sum, off);
        sq  += __shfl_xor(sq, off);
    }
    __shared__ float red[8];
    int lane = tid & 63, wid = tid >> 6;
    if (lane == 0) { red[wid] = sum; red[4 + wid] = sq; }
    __syncthreads();
    sum = red[0] + red[1] + red[2] + red[3];
    sq  = red[4] + red[5] + red[6] + red[7];
    float mean = sum * (1.0f / Hh);
    float var  = sq * (1.0f / Hh) - mean * mean;
    float rstd = rsqrtf(var + 1e-12f);
    #pragma unroll
    for (int r = 0; r < 3; r++) {
        int h = tid + (r << 8);
        out[(size_t)tok * Hh + h] = (e[r] - mean) * rstd * g[h] + bp[h];
    }
}

// ---------------------------------------------------------------------------
// 4. Generic fp32 GEMM: C[M,N] = A[M,K] @ W[K,N] + bias, opt. exact GELU.
//    64x64 tile, BK=16, 256 threads, 4x4 per thread.
// ---------------------------------------------------------------------------
template <int ACT>
__global__ __launch_bounds__(256) void sgemm_kernel(
    const float* __restrict__ A, const float* __restrict__ W,
    const float* __restrict__ bias, float* __restrict__ C,
    int N, int K)
{
    __shared__ float As[16][64];   // [k][m] (transposed A tile)
    __shared__ float Bs[16][64];   // [k][n]
    int tid = threadIdx.x;
    int n0 = blockIdx.x * 64;
    int m0 = blockIdx.y * 64;
    int ar = tid >> 2,  ak = (tid & 3) << 2;
    int br = tid >> 4,  bc = (tid & 15) << 2;
    int r0 = (tid >> 4) << 2, c0 = (tid & 15) << 2;
    const float* Ap = A + (size_t)(m0 + ar) * K + ak;
    const float* Wp = W + (size_t)br * N + n0 + bc;
    float acc[4][4] = {};
    for (int k0 = 0; k0 < K; k0 += 16) {
        float4 av = *(const float4*)(Ap + k0);
        float4 wv = *(const float4*)(Wp + (size_t)k0 * N);
        __syncthreads();
        As[ak + 0][ar] = av.x;
        As[ak + 1][ar] = av.y;
        As[ak + 2][ar] = av.z;
        As[ak + 3][ar] = av.w;
        *(float4*)&Bs[br][bc] = wv;
        __syncthreads();
        #pragma unroll
        for (int k = 0; k < 16; k++) {
            float4 a4 = *(const float4*)&As[k][r0];
            float4 b4 = *(const float4*)&Bs[k][c0];
            float aa[4] = { a4.x, a4.y, a4.z, a4.w };
            float bb[4] = { b4.x, b4.y, b4.z, b4.w };
            #pragma unroll
            for (int i = 0; i < 4; i++)
                #pragma unroll
                for (int j = 0; j < 4; j++)
                    acc[i][j] = fmaf(aa[i], bb[j], acc[i][j]);
        }
    }
    #pragma unroll
    for (int i = 0; i < 4; i++) {
        #pragma unroll
        for (int j = 0; j < 4; j++) {
            float v = acc[i][j] + bias[n0 + c0 + j];
            if (ACT == 1) v = 0.5f * v * (1.0f + erff(v * 0.70710678118654752f));
            C[(size_t)(m0 + r0 + i) * N + n0 + c0 + j] = v;
        }
    }
}

// ---------------------------------------------------------------------------
// 5. Attention scores: scores[b,h,i,j] = (q . k)/8 + mask_bias
// ---------------------------------------------------------------------------
__global__ __launch_bounds__(256) void scores_kernel(
    const float* __restrict__ q, const float* __restrict__ kk,
    const int* __restrict__ info, float* __restrict__ sc)
{
    int bh = blockIdx.z;
    int b = bh / NHh, h = bh % NHh;
    int i0 = blockIdx.y * 64, j0 = blockIdx.x * 64;
    __shared__ float qs[64][68];
    __shared__ float ks[64][68];
    int tid = threadIdx.x;
    const float* qg = q  + ((size_t)b * Ss + i0) * Hh + h * DHh;
    const float* kg = kk + ((size_t)b * Ss + j0) * Hh + h * DHh;
    for (int e = tid; e < 64 * 16; e += 256) {
        int r = e >> 4;
        int c = (e & 15) << 2;
        *(float4*)&qs[r][c] = *(const float4*)&qg[(size_t)r * Hh + c];
        *(float4*)&ks[r][c] = *(const float4*)&kg[(size_t)r * Hh + c];
    }
    __syncthreads();
    int r0 = (tid >> 4) << 2, c0 = (tid & 15) << 2;
    float acc[4][4] = {};
    #pragma unroll
    for (int d = 0; d < 64; d += 4) {
        float4 qa[4], kb[4];
        #pragma unroll
        for (int i = 0; i < 4; i++) qa[i] = *(const float4*)&qs[r0 + i][d];
        #pragma unroll
        for (int j = 0; j < 4; j++) kb[j] = *(const float4*)&ks[c0 + j][d];
        #pragma unroll
        for (int i = 0; i < 4; i++)
            #pragma unroll
            for (int j = 0; j < 4; j++) {
                acc[i][j] = fmaf(qa[i].x, kb[j].x, acc[i][j]);
                acc[i][j] = fmaf(qa[i].y, kb[j].y, acc[i][j]);
                acc[i][j] = fmaf(qa[i].z, kb[j].z, acc[i][j]);
                acc[i][j] = fmaf(qa[i].w, kb[j].w, acc[i][j]);
            }
    }
    int has = info[b * 4 + 1];
    int sep = info[b * 4 + 2];
    #pragma unroll
    for (int i = 0; i < 4; i++) {
        int gi = i0 + r0 + i;
        #pragma unroll
        for (int j = 0; j < 4; j++) {
            int gj = j0 + c0 + j;
            bool vis = (!has) || (gj <= sep) || ((gi > sep) && (gj <= gi));
            sc[((size_t)bh * Ss + gi) * Ss + gj] =
                acc[i][j] * 0.125f + (vis ? 0.0f : -1000000000.0f);
        }
    }
}

// ---------------------------------------------------------------------------
// 6. Row softmax over S=512 (one block per row)
// ---------------------------------------------------------------------------
__global__ __launch_bounds__(256) void softmax_kernel(float* __restrict__ sc)
{
    size_t row = blockIdx.x;
    float* p = sc + row * (size_t)Ss;
    int tid = threadIdx.x;
    float a = p[tid], b = p[tid + 256];
    float mx = fmaxf(a, b);
    #pragma unroll
    for (int off = 32; off; off >>= 1) mx = fmaxf(mx, __shfl_xor(mx, off));
    __shared__ float red[4];
    int lane = tid & 63, wid = tid >> 6;
    if (lane == 0) red[wid] = mx;
    __syncthreads();
    mx = fmaxf(fmaxf(red[0], red[1]), fmaxf(red[2], red[3]));
    float ea = __expf(a - mx), eb = __expf(b - mx);
    float s = ea + eb;
    #pragma unroll
    for (int off = 32; off; off >>= 1) s += __shfl_xor(s, off);
    __syncthreads();
    if (lane == 0) red[wid] = s;
    __syncthreads();
    s = red[0] + red[1] + red[2] + red[3];
    float inv = 1.0f / s;
    p[tid] = ea * inv;
    p[tid + 256] = eb * inv;
}

// ---------------------------------------------------------------------------
// 7. ctx = probs @ v  (per (b,h): 512x512 @ 512x64), output in (B,S,H) layout
// ---------------------------------------------------------------------------
__global__ __launch_bounds__(256) void ctx_kernel(
    const float* __restrict__ P, const float* __restrict__ Vb,
    float* __restrict__ ctx)
{
    int bh = blockIdx.y;
    int b = bh / NHh, h = bh % NHh;
    int i0 = blockIdx.x * 64;
    __shared__ float Ps[16][64];   // [k][i]
    __shared__ float Vs[16][64];   // [k][d]
    int tid = threadIdx.x;
    int pr = tid >> 2,  pk = (tid & 3) << 2;
    int vr = tid >> 4,  vc = (tid & 15) << 2;
    int r0 = (tid >> 4) << 2, c0 = (tid & 15) << 2;
    const float* Pp = P  + ((size_t)bh * Ss + i0 + pr) * Ss + pk;
    const float* Vp = Vb + ((size_t)b * Ss + vr) * Hh + h * DHh + vc;
    float acc[4][4] = {};
    for (int k0 = 0; k0 < Ss; k0 += 16) {
        float4 pv = *(const float4*)(Pp + k0);
        float4 vv = *(const float4*)(Vp + (size_t)k0 * Hh);
        __syncthreads();
        Ps[pk + 0][pr] = pv.x;
        Ps[pk + 1][pr] = pv.y;
        Ps[pk + 2][pr] = pv.z;
        Ps[pk + 3][pr] = pv.w;
        *(float4*)&Vs[vr][vc] = vv;
        __syncthreads();
        #pragma unroll
        for (int k = 0; k < 16; k++) {
            float4 a4 = *(const float4*)&Ps[k][r0];
            float4 b4 = *(const float4*)&Vs[k][c0];
            float aa[4] = { a4.x, a4.y, a4.z, a4.w };
            float bb[4] = { b4.x, b4.y, b4.z, b4.w };
            #pragma unroll
            for (int i = 0; i < 4; i++)
                #pragma unroll
                for (int j = 0; j < 4; j++)
                    acc[i][j] = fmaf(aa[i], bb[j], acc[i][j]);
        }
    }
    #pragma unroll
    for (int i = 0; i < 4; i++)
        #pragma unroll
        for (int j = 0; j < 4; j++)
            ctx[((size_t)b * Ss + i0 + r0 + i) * Hh + h * DHh + c0 + j] = acc[i][j];
}

// ---------------------------------------------------------------------------
// 8. Classifier + CE, streaming online logsumexp (no logits buffer).
//    Block = 16 rows x 512 threads; each thread owns 4 vocab cols per chunk.
// ---------------------------------------------------------------------------
constexpr int CLS_ROWS = 16;
__global__ __launch_bounds__(512) void cls_ce_kernel(
    const float* __restrict__ x, const float* __restrict__ W,
    const float* __restrict__ cb, const int* __restrict__ labels,
    float* __restrict__ ce)
{
    __shared__ float xs[CLS_ROWS][Hh];
    __shared__ int   lab[CLS_ROWS];
    __shared__ float ll[CLS_ROWS];
    __shared__ float wm[8][CLS_ROWS], wsv[8][CLS_ROWS];
    int tid = threadIdx.x;
    int row0 = blockIdx.x * CLS_ROWS;
    for (int e = tid; e < CLS_ROWS * (Hh / 4); e += 512) {
        int r = e / (Hh / 4), c = (e % (Hh / 4)) << 2;
        *(float4*)&xs[r][c] = *(const float4*)&x[(size_t)(row0 + r) * Hh + c];
    }
    if (tid < CLS_ROWS) lab[tid] = labels[row0 + tid];
    __syncthreads();

    float m[CLS_ROWS], sv[CLS_ROWS];
    #pragma unroll
    for (int r = 0; r < CLS_ROWS; r++) { m[r] = -3.0e38f; sv[r] = 0.0f; }

    #pragma unroll 1
    for (int v0 = 0; v0 < Vv; v0 += 2048) {
        int v = v0 + tid * 4;
        if (v < Vv) {
            float4 acc[CLS_ROWS];
            #pragma unroll
            for (int r = 0; r < CLS_ROWS; r++) { acc[r].x = 0.f; acc[r].y = 0.f; acc[r].z = 0.f; acc[r].w = 0.f; }
            const float* wp = W + v;
            #pragma unroll 4
            for (int h = 0; h < Hh; h++) {
                float4 w4 = *(const float4*)(wp + (size_t)h * Vv);
                #pragma unroll
                for (int r = 0; r < CLS_ROWS; r++) {
                    float xv = xs[r][h];
                    acc[r].x = fmaf(xv, w4.x, acc[r].x);
                    acc[r].y = fmaf(xv, w4.y, acc[r].y);
                    acc[r].z = fmaf(xv, w4.z, acc[r].z);
                    acc[r].w = fmaf(xv, w4.w, acc[r].w);
                }
            }
            float4 cb4 = *(const float4*)&cb[v];
            #pragma unroll
            for (int r = 0; r < CLS_ROWS; r++) {
                float lx = acc[r].x + cb4.x;
                float ly = acc[r].y + cb4.y;
                float lz = acc[r].z + cb4.z;
                float lw = acc[r].w + cb4.w;
                int lr = lab[r];
                if (lr == v)          ll[r] = lx;
                else if (lr == v + 1) ll[r] = ly;
                else if (lr == v + 2) ll[r] = lz;
                else if (lr == v + 3) ll[r] = lw;
                float mx = fmaxf(fmaxf(lx, ly), fmaxf(lz, lw));
                float nm = fmaxf(m[r], mx);
                sv[r] = sv[r] * __expf(m[r] - nm)
                      + __expf(lx - nm) + __expf(ly - nm)
                      + __expf(lz - nm) + __expf(lw - nm);
                m[r] = nm;
            }
        }
    }

    // cross-lane merge (logsumexp combine)
    int lane = tid & 63, wid = tid >> 6;
    #pragma unroll
    for (int r = 0; r < CLS_ROWS; r++) {
        float mm = m[r], ss = sv[r];
        #pragma unroll
        for (int off = 1; off < 64; off <<= 1) {
            float om = __shfl_xor(mm, off);
            float os = __shfl_xor(ss, off);
            float nm = fmaxf(mm, om);
            ss = ss * __expf(mm - nm) + os * __expf(om - nm);
            mm = nm;
        }
        if (lane == 0) { wm[wid][r] = mm; wsv[wid][r] = ss; }
    }
    __syncthreads();
    if (tid < CLS_ROWS) {
        int r = tid;
        float mm = wm[0][r], ss = wsv[0][r];
        #pragma unroll
        for (int w = 1; w < 8; w++) {
            float om = wm[w][r], os = wsv[w][r];
            float nm = fmaxf(mm, om);
            ss = ss * __expf(mm - nm) + os * __expf(om - nm);
            mm = nm;
        }
        ce[row0 + r] = (mm + logf(ss)) - ll[r];
    }
}

// ---------------------------------------------------------------------------
// 9. Masked per-sample mean, then final scalar
// ---------------------------------------------------------------------------
__global__ __launch_bounds__(256) void ce_reduce_kernel(
    const float* __restrict__ ce, const int* __restrict__ info,
    float* __restrict__ ps)
{
    int b = blockIdx.x, tid = threadIdx.x;
    int first = info[b * 4 + 0], has = info[b * 4 + 1];
    float sum = 0.0f;
    for (int s = tid; s < Ss; s += 256) {
        bool mv = has ? (s > first) : true;
        if (mv) sum += ce[b * Ss + s];
    }
    #pragma unroll
    for (int off = 32; off; off >>= 1) sum += __shfl_xor(sum, off);
    __shared__ float red[4];
    int lane = tid & 63, wid = tid >> 6;
    if (lane == 0) red[wid] = sum;
    __syncthreads();
    if (tid == 0) {
        float tot = red[0] + red[1] + red[2] + red[3];
        float cnt = has ? (float)(Ss - 1 - first) : (float)Ss;
        ps[b] = tot / cnt;
    }
}

__global__ void final_kernel(const float* __restrict__ ps, float* __restrict__ out)
{
    if (threadIdx.x == 0 && blockIdx.x == 0) {
        float t = 0.0f;
        #pragma unroll
        for (int b = 0; b < Bb; b++) t += ps[b];
        out[0] = t * (1.0f / Bb);
    }
}

// ---------------------------------------------------------------------------
// Host launcher
// ---------------------------------------------------------------------------
extern "C" void kernel_launch(void* const* d_in, const int* in_sizes, int n_in,
                              void* d_out, int out_size, void* d_ws, size_t ws_size,
                              hipStream_t stream)
{
    const int*   ids    = (const int*)d_in[0];
    const int*   labels = (const int*)d_in[1];
    const float* we     = (const float*)d_in[2];
    const float* pe     = (const float*)d_in[3];
    const float* te     = (const float*)d_in[4];
    const float* eg     = (const float*)d_in[5];
    const float* ebp    = (const float*)d_in[6];
    const float* Wq     = (const float*)d_in[7];
    const float* bq     = (const float*)d_in[8];
    const float* Wk     = (const float*)d_in[9];
    const float* bk     = (const float*)d_in[10];
    const float* Wv     = (const float*)d_in[11];
    const float* bv     = (const float*)d_in[12];
    const float* Wo     = (const float*)d_in[13];
    const float* bo     = (const float*)d_in[14];
    const float* l1g    = (const float*)d_in[15];
    const float* l1b    = (const float*)d_in[16];
    const float* W1     = (const float*)d_in[17];
    const float* b1     = (const float*)d_in[18];
    const float* W2     = (const float*)d_in[19];
    const float* b2     = (const float*)d_in[20];
    const float* l2g    = (const float*)d_in[21];
    const float* l2b    = (const float*)d_in[22];
    const float* cW     = (const float*)d_in[23];
    const float* cbias  = (const float*)d_in[24];

    float* ws = (float*)d_ws;
    const size_t MH = (size_t)Mm * Hh;                 // 3.15M
    const size_t MF = (size_t)Mm * Ff;                 // 12.6M
    const size_t SC = (size_t)Bb * NHh * Ss * Ss;      // 25.2M
    float* x      = ws;
    float* q      = x + MH;
    float* kbuf   = q + MH;
    float* vbuf   = kbuf + MH;
    float* tmp    = vbuf + MH;
    float* ctx    = tmp + MH;
    float* ffn1   = ctx + MH;
    float* scores = ffn1 + MF;
    float* ce     = scores + SC;
    float* ps     = ce + Mm;
    int*   info   = (int*)(ps + 16);

    sep_kernel<<<Bb, 512, 0, stream>>>(ids, info);
    embed_ln_kernel<<<Mm, 256, 0, stream>>>(ids, we, pe, te, eg, ebp, x);

    dim3 gQ(Hh / 64, Mm / 64);            // (12, 64)
    dim3 gF1(Ff / 64, Mm / 64);           // (48, 64)
    dim3 gS(Ss / 64, Ss / 64, Bb * NHh);  // (8, 8, 96)
    dim3 gC(Ss / 64, Bb * NHh);           // (8, 96)

    for (int l = 0; l < Ll; l++) {
        const float* wq = Wq + (size_t)l * Hh * Hh;
        const float* wk = Wk + (size_t)l * Hh * Hh;
        const float* wv = Wv + (size_t)l * Hh * Hh;
        const float* wo = Wo + (size_t)l * Hh * Hh;
        const float* w1 = W1 + (size_t)l * Hh * Ff;
        const float* w2 = W2 + (size_t)l * Ff * Hh;
        const float* bq_l = bq + (size_t)l * Hh;
        const float* bk_l = bk + (size_t)l * Hh;
        const float* bv_l = bv + (size_t)l * Hh;
        const float* bo_l = bo + (size_t)l * Hh;
        const float* b1_l = b1 + (size_t)l * Ff;
        const float* b2_l = b2 + (size_t)l * Hh;
        const float* g1 = l1g + (size_t)l * Hh;
        const float* be1 = l1b + (size_t)l * Hh;
        const float* g2 = l2g + (size_t)l * Hh;
        const float* be2 = l2b + (size_t)l * Hh;

        sgemm_kernel<0><<<gQ, 256, 0, stream>>>(x, wq, bq_l, q,    Hh, Hh);
        sgemm_kernel<0><<<gQ, 256, 0, stream>>>(x, wk, bk_l, kbuf, Hh, Hh);
        sgemm_kernel<0><<<gQ, 256, 0, stream>>>(x, wv, bv_l, vbuf, Hh, Hh);

        scores_kernel<<<gS, 256, 0, stream>>>(q, kbuf, info, scores);
        softmax_kernel<<<Bb * NHh * Ss, 256, 0, stream>>>(scores);
        ctx_kernel<<<gC, 256, 0, stream>>>(scores, vbuf, ctx);

        sgemm_kernel<0><<<gQ, 256, 0, stream>>>(ctx, wo, bo_l, tmp, Hh, Hh);
        resid_ln_kernel<<<Mm, 256, 0, stream>>>(x, tmp, g1, be1, x);

        sgemm_kernel<1><<<gF1, 256, 0, stream>>>(x, w1, b1_l, ffn1, Ff, Hh);
        sgemm_kernel<0><<<gQ, 256, 0, stream>>>(ffn1, w2, b2_l, tmp, Hh, Ff);
        resid_ln_kernel<<<Mm, 256, 0, stream>>>(x, tmp, g2, be2, x);
    }

    cls_ce_kernel<<<Mm / CLS_ROWS, 512, 0, stream>>>(x, cW, cbias, labels, ce);
    ce_reduce_kernel<<<Bb, 256, 0, stream>>>(ce, info, ps);
    final_kernel<<<1, 64, 0, stream>>>(ps, (float*)d_out);
}

// Round 4
// 7349.506 us; speedup vs baseline: 2.0295x; 2.0295x over previous
//
#include <hip/hip_runtime.h>
#include <math.h>

typedef unsigned short ushort;
typedef __bf16 bf16x8 __attribute__((ext_vector_type(8)));
typedef float f32x4 __attribute__((ext_vector_type(4)));

// Problem dims
constexpr int Bb  = 8;
constexpr int Ss  = 512;
constexpr int Hh  = 768;
constexpr int Ll  = 12;
constexpr int NHh = 12;
constexpr int Ff  = 3072;
constexpr int Vv  = 21128;
constexpr int DHh = 64;
constexpr int Mm  = Bb * Ss;   // 4096
constexpr int SEP_ID = 102;

static __device__ __forceinline__ ushort f2bf(float f) {
    unsigned u = __float_as_uint(f);
    unsigned r = (u + 0x7fffu + ((u >> 16) & 1u)) >> 16;
    return (ushort)r;
}
static __device__ __forceinline__ float bf2f(unsigned x) {
    return __uint_as_float(x << 16);
}

// ---------------------------------------------------------------------------
// 1. Find first SEP per batch
// ---------------------------------------------------------------------------
__global__ __launch_bounds__(512) void sep_kernel(const int* __restrict__ ids,
                                                  int* __restrict__ info)
{
    int b = blockIdx.x;
    int t = threadIdx.x;
    int v = (ids[b * Ss + t] == SEP_ID) ? t : 0x7FFFFFFF;
    #pragma unroll
    for (int off = 32; off; off >>= 1) {
        int o = __shfl_xor(v, off);
        v = min(v, o);
    }
    __shared__ int wmin[8];
    int lane = t & 63, wid = t >> 6;
    if (lane == 0) wmin[wid] = v;
    __syncthreads();
    if (t == 0) {
        int first = wmin[0];
        #pragma unroll
        for (int w = 1; w < 8; w++) first = min(first, wmin[w]);
        int has = (first != 0x7FFFFFFF) ? 1 : 0;
        info[b * 4 + 0] = first;
        info[b * 4 + 1] = has;
        info[b * 4 + 2] = has ? min(first, Ss - 2) : (Ss + 1);
    }
}

// ---------------------------------------------------------------------------
// 2. Embedding + LayerNorm -> fp32 x and bf16 xb
// ---------------------------------------------------------------------------
__global__ __launch_bounds__(256) void embed_ln_kernel(
    const int* __restrict__ ids, const float* __restrict__ we,
    const float* __restrict__ pe, const float* __restrict__ te,
    const float* __restrict__ g, const float* __restrict__ bp,
    float* __restrict__ x, ushort* __restrict__ xb)
{
    int tok = blockIdx.x;
    int s = tok & (Ss - 1);
    int tid = threadIdx.x;
    int id = ids[tok];
    float e[3];
    #pragma unroll
    for (int r = 0; r < 3; r++) {
        int h = tid + (r << 8);
        e[r] = we[(size_t)id * Hh + h] + pe[(size_t)s * Hh + h] + te[h];
    }
    float sum = e[0] + e[1] + e[2];
    float sq  = fmaf(e[0], e[0], fmaf(e[1], e[1], e[2] * e[2]));
    #pragma unroll
    for (int off = 32; off; off >>= 1) {
        sum += __shfl_xor(sum, off);
        sq  += __shfl_xor(sq, off);
    }
    __shared__ float red[8];
    int lane = tid & 63, wid = tid >> 6;
    if (lane == 0) { red[wid] = sum; red[4 + wid] = sq; }
    __syncthreads();
    sum = red[0] + red[1] + red[2] + red[3];
    sq  = red[4] + red[5] + red[6] + red[7];
    float mean = sum * (1.0f / Hh);
    float var  = sq * (1.0f / Hh) - mean * mean;
    float rstd = rsqrtf(var + 1e-12f);
    #pragma unroll
    for (int r = 0; r < 3; r++) {
        int h = tid + (r << 8);
        float v = (e[r] - mean) * rstd * g[h] + bp[h];
        x[(size_t)tok * Hh + h] = v;
        xb[(size_t)tok * Hh + h] = f2bf(v);
    }
}

// ---------------------------------------------------------------------------
// 3. Residual + LayerNorm -> fp32 out and bf16 outb
// ---------------------------------------------------------------------------
__global__ __launch_bounds__(256) void resid_ln_kernel(
    const float* __restrict__ resid, const float* __restrict__ y,
    const float* __restrict__ g, const float* __restrict__ bp,
    float* __restrict__ out, ushort* __restrict__ outb)
{
    int tok = blockIdx.x;
    int tid = threadIdx.x;
    float e[3];
    #pragma unroll
    for (int r = 0; r < 3; r++) {
        int h = tid + (r << 8);
        size_t idx = (size_t)tok * Hh + h;
        e[r] = resid[idx] + y[idx];
    }
    float sum = e[0] + e[1] + e[2];
    float sq  = fmaf(e[0], e[0], fmaf(e[1], e[1], e[2] * e[2]));
    #pragma unroll
    for (int off = 32; off; off >>= 1) {
        sum += __shfl_xor(sum, off);
        sq  += __shfl_xor(sq, off);
    }
    __shared__ float red[8];
    int lane = tid & 63, wid = tid >> 6;
    if (lane == 0) { red[wid] = sum; red[4 + wid] = sq; }
    __syncthreads();
    sum = red[0] + red[1] + red[2] + red[3];
    sq  = red[4] + red[5] + red[6] + red[7];
    float mean = sum * (1.0f / Hh);
    float var  = sq * (1.0f / Hh) - mean * mean;
    float rstd = rsqrtf(var + 1e-12f);
    #pragma unroll
    for (int r = 0; r < 3; r++) {
        int h = tid + (r << 8);
        float v = (e[r] - mean) * rstd * g[h] + bp[h];
        out[(size_t)tok * Hh + h] = v;
        outb[(size_t)tok * Hh + h] = f2bf(v);
    }
}

// ---------------------------------------------------------------------------
// 4. Weight convert+transpose: Wt[n][k] = bf16(W[k][n]); K,N multiples of 32
// ---------------------------------------------------------------------------
__global__ __launch_bounds__(256) void transpose_kernel(
    const float* __restrict__ W, ushort* __restrict__ Wt, int K, int N)
{
    __shared__ float ts[32][33];
    int n0 = blockIdx.x * 32, k0 = blockIdx.y * 32;
    int tx = threadIdx.x & 31, ty = threadIdx.x >> 5;
    #pragma unroll
    for (int i = 0; i < 32; i += 8)
        ts[ty + i][tx] = W[(size_t)(k0 + ty + i) * N + n0 + tx];
    __syncthreads();
    #pragma unroll
    for (int i = 0; i < 32; i += 8)
        Wt[(size_t)(n0 + ty + i) * K + k0 + tx] = f2bf(ts[tx][ty + i]);
}

// ---------------------------------------------------------------------------
// 5. bf16 MFMA GEMM (m97-pattern, linear LDS, no swizzle):
//    C[M,N] = A[M,K] @ Bt[N,K]^T + bias (opt. exact GELU)
//    128x128 tile, BK=32, 4 waves (2x2), wave tile 64x64 (4x4 frags 16x16x32)
// ---------------------------------------------------------------------------
template <int ACT, int OUT_BF>
__global__ __launch_bounds__(256) void mfma_gemm(
    const ushort* __restrict__ A,   // [M][K] bf16
    const ushort* __restrict__ Bt,  // [N][K] bf16
    const float* __restrict__ bias, // [N]
    void* __restrict__ C,           // [M][N] f32 or bf16
    int N, int K)
{
    __shared__ __align__(16) ushort As[128 * 32];
    __shared__ __align__(16) ushort Bs[128 * 32];
    const int tid = threadIdx.x;
    const int lane = tid & 63, wid = tid >> 6;
    const int m0 = blockIdx.y * 128, n0 = blockIdx.x * 128;
    const int wr = (wid >> 1) * 64, wc = (wid & 1) * 64;
    const int lr = lane & 15;
    const int kg = (lane >> 4) << 3;   // k element offset within BK=32

    f32x4 acc[4][4];
    #pragma unroll
    for (int mi = 0; mi < 4; ++mi)
        #pragma unroll
        for (int ni = 0; ni < 4; ++ni)
            acc[mi][ni] = (f32x4){0.f, 0.f, 0.f, 0.f};

    for (int k0 = 0; k0 < K; k0 += 32) {
        // Stage A-tile [128][32] and B-tile [128][32], linear row-major LDS.
        #pragma unroll
        for (int i = 0; i < 2; ++i) {
            int idx = i * 256 + tid;
            int r = idx >> 2, c = (idx & 3) << 3;
            __builtin_amdgcn_global_load_lds(
                (const __attribute__((address_space(1))) void*)(A + (size_t)(m0 + r) * K + k0 + c),
                (__attribute__((address_space(3))) void*)(As + (size_t)(i * 256 + (wid << 6)) * 8),
                16, 0, 0);
        }
        #pragma unroll
        for (int i = 0; i < 2; ++i) {
            int idx = i * 256 + tid;
            int r = idx >> 2, c = (idx & 3) << 3;
            __builtin_amdgcn_global_load_lds(
                (const __attribute__((address_space(1))) void*)(Bt + (size_t)(n0 + r) * K + k0 + c),
                (__attribute__((address_space(3))) void*)(Bs + (size_t)(i * 256 + (wid << 6)) * 8),
                16, 0, 0);
        }
        __syncthreads();

        bf16x8 af[4], bfr[4];
        #pragma unroll
        for (int mi = 0; mi < 4; ++mi)
            af[mi] = *(const bf16x8*)(As + (size_t)(wr + mi * 16 + lr) * 32 + kg);
        #pragma unroll
        for (int ni = 0; ni < 4; ++ni)
            bfr[ni] = *(const bf16x8*)(Bs + (size_t)(wc + ni * 16 + lr) * 32 + kg);

        #pragma unroll
        for (int mi = 0; mi < 4; ++mi)
            #pragma unroll
            for (int ni = 0; ni < 4; ++ni)
                acc[mi][ni] = __builtin_amdgcn_mfma_f32_16x16x32_bf16(
                    af[mi], bfr[ni], acc[mi][ni], 0, 0, 0);
        __syncthreads();
    }

    // Epilogue: bias (+GELU), store. C/D layout: col=lane&15, row=(lane>>4)*4+q.
    #pragma unroll
    for (int ni = 0; ni < 4; ++ni) {
        int col = n0 + wc + ni * 16 + lr;
        float bsv = bias[col];
        #pragma unroll
        for (int mi = 0; mi < 4; ++mi) {
            f32x4 v = acc[mi][ni];
            #pragma unroll
            for (int q = 0; q < 4; ++q) {
                int row = m0 + wr + mi * 16 + ((lane >> 4) << 2) + q;
                float val = v[q] + bsv;
                if (ACT == 1) val = 0.5f * val * (1.0f + erff(val * 0.70710678118654752f));
                if (OUT_BF)
                    ((ushort*)C)[(size_t)row * N + col] = f2bf(val);
                else
                    ((float*)C)[(size_t)row * N + col] = val;
            }
        }
    }
}

// ---------------------------------------------------------------------------
// 6. Attention scores (fp32 compute, bf16 q/k inputs)
// ---------------------------------------------------------------------------
__global__ __launch_bounds__(256) void scores_kernel(
    const ushort* __restrict__ q, const ushort* __restrict__ kk,
    const int* __restrict__ info, float* __restrict__ sc)
{
    int bh = blockIdx.z;
    int b = bh / NHh, h = bh % NHh;
    int i0 = blockIdx.y * 64, j0 = blockIdx.x * 64;
    __shared__ float qs[64][68];
    __shared__ float ks[64][68];
    int tid = threadIdx.x;
    const ushort* qg = q  + ((size_t)b * Ss + i0) * Hh + h * DHh;
    const ushort* kg = kk + ((size_t)b * Ss + j0) * Hh + h * DHh;
    for (int e = tid; e < 64 * 8; e += 256) {
        int r = e >> 3;
        int c = (e & 7) << 3;
        uint4 u = *(const uint4*)&qg[(size_t)r * Hh + c];
        float* dq = &qs[r][c];
        dq[0] = bf2f(u.x & 0xffff); dq[1] = bf2f(u.x >> 16);
        dq[2] = bf2f(u.y & 0xffff); dq[3] = bf2f(u.y >> 16);
        dq[4] = bf2f(u.z & 0xffff); dq[5] = bf2f(u.z >> 16);
        dq[6] = bf2f(u.w & 0xffff); dq[7] = bf2f(u.w >> 16);
        uint4 w = *(const uint4*)&kg[(size_t)r * Hh + c];
        float* dk = &ks[r][c];
        dk[0] = bf2f(w.x & 0xffff); dk[1] = bf2f(w.x >> 16);
        dk[2] = bf2f(w.y & 0xffff); dk[3] = bf2f(w.y >> 16);
        dk[4] = bf2f(w.z & 0xffff); dk[5] = bf2f(w.z >> 16);
        dk[6] = bf2f(w.w & 0xffff); dk[7] = bf2f(w.w >> 16);
    }
    __syncthreads();
    int r0 = (tid >> 4) << 2, c0 = (tid & 15) << 2;
    float acc[4][4] = {};
    #pragma unroll
    for (int d = 0; d < 64; d += 4) {
        float4 qa[4], kb[4];
        #pragma unroll
        for (int i = 0; i < 4; i++) qa[i] = *(const float4*)&qs[r0 + i][d];
        #pragma unroll
        for (int j = 0; j < 4; j++) kb[j] = *(const float4*)&ks[c0 + j][d];
        #pragma unroll
        for (int i = 0; i < 4; i++)
            #pragma unroll
            for (int j = 0; j < 4; j++) {
                acc[i][j] = fmaf(qa[i].x, kb[j].x, acc[i][j]);
                acc[i][j] = fmaf(qa[i].y, kb[j].y, acc[i][j]);
                acc[i][j] = fmaf(qa[i].z, kb[j].z, acc[i][j]);
                acc[i][j] = fmaf(qa[i].w, kb[j].w, acc[i][j]);
            }
    }
    int has = info[b * 4 + 1];
    int sep = info[b * 4 + 2];
    #pragma unroll
    for (int i = 0; i < 4; i++) {
        int gi = i0 + r0 + i;
        #pragma unroll
        for (int j = 0; j < 4; j++) {
            int gj = j0 + c0 + j;
            bool vis = (!has) || (gj <= sep) || ((gi > sep) && (gj <= gi));
            sc[((size_t)bh * Ss + gi) * Ss + gj] =
                acc[i][j] * 0.125f + (vis ? 0.0f : -1000000000.0f);
        }
    }
}

// ---------------------------------------------------------------------------
// 7. Row softmax over S=512
// ---------------------------------------------------------------------------
__global__ __launch_bounds__(256) void softmax_kernel(float* __restrict__ sc)
{
    size_t row = blockIdx.x;
    float* p = sc + row * (size_t)Ss;
    int tid = threadIdx.x;
    float a = p[tid], b = p[tid + 256];
    float mx = fmaxf(a, b);
    #pragma unroll
    for (int off = 32; off; off >>= 1) mx = fmaxf(mx, __shfl_xor(mx, off));
    __shared__ float red[4];
    int lane = tid & 63, wid = tid >> 6;
    if (lane == 0) red[wid] = mx;
    __syncthreads();
    mx = fmaxf(fmaxf(red[0], red[1]), fmaxf(red[2], red[3]));
    float ea = __expf(a - mx), eb = __expf(b - mx);
    float s = ea + eb;
    #pragma unroll
    for (int off = 32; off; off >>= 1) s += __shfl_xor(s, off);
    __syncthreads();
    if (lane == 0) red[wid] = s;
    __syncthreads();
    s = red[0] + red[1] + red[2] + red[3];
    float inv = 1.0f / s;
    p[tid] = ea * inv;
    p[tid + 256] = eb * inv;
}

// ---------------------------------------------------------------------------
// 8. ctx = probs @ v  (fp32 P, bf16 V in, bf16 ctx out)
// ---------------------------------------------------------------------------
__global__ __launch_bounds__(256) void ctx_kernel(
    const float* __restrict__ P, const ushort* __restrict__ Vb,
    ushort* __restrict__ ctx)
{
    int bh = blockIdx.y;
    int b = bh / NHh, h = bh % NHh;
    int i0 = blockIdx.x * 64;
    __shared__ float Ps[16][64];   // [k][i]
    __shared__ float Vs[16][64];   // [k][d]
    int tid = threadIdx.x;
    int pr = tid >> 2,  pk = (tid & 3) << 2;
    int vr = tid >> 4,  vc = (tid & 15) << 2;
    int r0 = (tid >> 4) << 2, c0 = (tid & 15) << 2;
    const float*  Pp = P  + ((size_t)bh * Ss + i0 + pr) * Ss + pk;
    const ushort* Vp = Vb + ((size_t)b * Ss + vr) * Hh + h * DHh + vc;
    float acc[4][4] = {};
    for (int k0 = 0; k0 < Ss; k0 += 16) {
        float4 pv = *(const float4*)(Pp + k0);
        uint2 vv = *(const uint2*)(Vp + (size_t)k0 * Hh);
        __syncthreads();
        Ps[pk + 0][pr] = pv.x;
        Ps[pk + 1][pr] = pv.y;
        Ps[pk + 2][pr] = pv.z;
        Ps[pk + 3][pr] = pv.w;
        Vs[vr][vc + 0] = bf2f(vv.x & 0xffff);
        Vs[vr][vc + 1] = bf2f(vv.x >> 16);
        Vs[vr][vc + 2] = bf2f(vv.y & 0xffff);
        Vs[vr][vc + 3] = bf2f(vv.y >> 16);
        __syncthreads();
        #pragma unroll
        for (int k = 0; k < 16; k++) {
            float4 a4 = *(const float4*)&Ps[k][r0];
            float4 b4 = *(const float4*)&Vs[k][c0];
            float aa[4] = { a4.x, a4.y, a4.z, a4.w };
            float bb[4] = { b4.x, b4.y, b4.z, b4.w };
            #pragma unroll
            for (int i = 0; i < 4; i++)
                #pragma unroll
                for (int j = 0; j < 4; j++)
                    acc[i][j] = fmaf(aa[i], bb[j], acc[i][j]);
        }
    }
    #pragma unroll
    for (int i = 0; i < 4; i++)
        #pragma unroll
        for (int j = 0; j < 4; j++)
            ctx[((size_t)b * Ss + i0 + r0 + i) * Hh + h * DHh + c0 + j] = f2bf(acc[i][j]);
}

// ---------------------------------------------------------------------------
// 9. Classifier + CE, streaming online logsumexp (fp32)
// ---------------------------------------------------------------------------
constexpr int CLS_ROWS = 16;
__global__ __launch_bounds__(512) void cls_ce_kernel(
    const float* __restrict__ x, const float* __restrict__ W,
    const float* __restrict__ cb, const int* __restrict__ labels,
    float* __restrict__ ce)
{
    __shared__ float xs[CLS_ROWS][Hh];
    __shared__ int   lab[CLS_ROWS];
    __shared__ float ll[CLS_ROWS];
    __shared__ float wm[8][CLS_ROWS], wsv[8][CLS_ROWS];
    int tid = threadIdx.x;
    int row0 = blockIdx.x * CLS_ROWS;
    for (int e = tid; e < CLS_ROWS * (Hh / 4); e += 512) {
        int r = e / (Hh / 4), c = (e % (Hh / 4)) << 2;
        *(float4*)&xs[r][c] = *(const float4*)&x[(size_t)(row0 + r) * Hh + c];
    }
    if (tid < CLS_ROWS) lab[tid] = labels[row0 + tid];
    __syncthreads();

    float m[CLS_ROWS], sv[CLS_ROWS];
    #pragma unroll
    for (int r = 0; r < CLS_ROWS; r++) { m[r] = -3.0e38f; sv[r] = 0.0f; }

    #pragma unroll 1
    for (int v0 = 0; v0 < Vv; v0 += 2048) {
        int v = v0 + tid * 4;
        if (v < Vv) {
            float4 acc[CLS_ROWS];
            #pragma unroll
            for (int r = 0; r < CLS_ROWS; r++) { acc[r].x = 0.f; acc[r].y = 0.f; acc[r].z = 0.f; acc[r].w = 0.f; }
            const float* wp = W + v;
            #pragma unroll 4
            for (int h = 0; h < Hh; h++) {
                float4 w4 = *(const float4*)(wp + (size_t)h * Vv);
                #pragma unroll
                for (int r = 0; r < CLS_ROWS; r++) {
                    float xv = xs[r][h];
                    acc[r].x = fmaf(xv, w4.x, acc[r].x);
                    acc[r].y = fmaf(xv, w4.y, acc[r].y);
                    acc[r].z = fmaf(xv, w4.z, acc[r].z);
                    acc[r].w = fmaf(xv, w4.w, acc[r].w);
                }
            }
            float4 cb4 = *(const float4*)&cb[v];
            #pragma unroll
            for (int r = 0; r < CLS_ROWS; r++) {
                float lx = acc[r].x + cb4.x;
                float ly = acc[r].y + cb4.y;
                float lz = acc[r].z + cb4.z;
                float lw = acc[r].w + cb4.w;
                int lr = lab[r];
                if (lr == v)          ll[r] = lx;
                else if (lr == v + 1) ll[r] = ly;
                else if (lr == v + 2) ll[r] = lz;
                else if (lr == v + 3) ll[r] = lw;
                float mx = fmaxf(fmaxf(lx, ly), fmaxf(lz, lw));
                float nm = fmaxf(m[r], mx);
                sv[r] = sv[r] * __expf(m[r] - nm)
                      + __expf(lx - nm) + __expf(ly - nm)
                      + __expf(lz - nm) + __expf(lw - nm);
                m[r] = nm;
            }
        }
    }

    int lane = tid & 63, wid = tid >> 6;
    #pragma unroll
    for (int r = 0; r < CLS_ROWS; r++) {
        float mm = m[r], ss = sv[r];
        #pragma unroll
        for (int off = 1; off < 64; off <<= 1) {
            float om = __shfl_xor(mm, off);
            float os = __shfl_xor(ss, off);
            float nm = fmaxf(mm, om);
            ss = ss * __expf(mm - nm) + os * __expf(om - nm);
            mm = nm;
        }
        if (lane == 0) { wm[wid][r] = mm; wsv[wid][r] = ss; }
    }
    __syncthreads();
    if (tid < CLS_ROWS) {
        int r = tid;
        float mm = wm[0][r], ss = wsv[0][r];
        #pragma unroll
        for (int w = 1; w < 8; w++) {
            float om = wm[w][r], os = wsv[w][r];
            float nm = fmaxf(mm, om);
            ss = ss * __expf(mm - nm) + os * __expf(om - nm);
            mm = nm;
        }
        ce[row0 + r] = (mm + logf(ss)) - ll[r];
    }
}

// ---------------------------------------------------------------------------
// 10. Masked per-sample mean, final scalar
// ---------------------------------------------------------------------------
__global__ __launch_bounds__(256) void ce_reduce_kernel(
    const float* __restrict__ ce, const int* __restrict__ info,
    float* __restrict__ ps)
{
    int b = blockIdx.x, tid = threadIdx.x;
    int first = info[b * 4 + 0], has = info[b * 4 + 1];
    float sum = 0.0f;
    for (int s = tid; s < Ss; s += 256) {
        bool mv = has ? (s > first) : true;
        if (mv) sum += ce[b * Ss + s];
    }
    #pragma unroll
    for (int off = 32; off; off >>= 1) sum += __shfl_xor(sum, off);
    __shared__ float red[4];
    int lane = tid & 63, wid = tid >> 6;
    if (lane == 0) red[wid] = sum;
    __syncthreads();
    if (tid == 0) {
        float tot = red[0] + red[1] + red[2] + red[3];
        float cnt = has ? (float)(Ss - 1 - first) : (float)Ss;
        ps[b] = tot / cnt;
    }
}

__global__ void final_kernel(const float* __restrict__ ps, float* __restrict__ out)
{
    if (threadIdx.x == 0 && blockIdx.x == 0) {
        float t = 0.0f;
        #pragma unroll
        for (int b = 0; b < Bb; b++) t += ps[b];
        out[0] = t * (1.0f / Bb);
    }
}

// ---------------------------------------------------------------------------
// Host launcher
// ---------------------------------------------------------------------------
extern "C" void kernel_launch(void* const* d_in, const int* in_sizes, int n_in,
                              void* d_out, int out_size, void* d_ws, size_t ws_size,
                              hipStream_t stream)
{
    const int*   ids    = (const int*)d_in[0];
    const int*   labels = (const int*)d_in[1];
    const float* we     = (const float*)d_in[2];
    const float* pe     = (const float*)d_in[3];
    const float* te     = (const float*)d_in[4];
    const float* eg     = (const float*)d_in[5];
    const float* ebp    = (const float*)d_in[6];
    const float* Wq     = (const float*)d_in[7];
    const float* bq     = (const float*)d_in[8];
    const float* Wk     = (const float*)d_in[9];
    const float* bk     = (const float*)d_in[10];
    const float* Wv     = (const float*)d_in[11];
    const float* bv     = (const float*)d_in[12];
    const float* Wo     = (const float*)d_in[13];
    const float* bo     = (const float*)d_in[14];
    const float* l1g    = (const float*)d_in[15];
    const float* l1b    = (const float*)d_in[16];
    const float* W1     = (const float*)d_in[17];
    const float* b1     = (const float*)d_in[18];
    const float* W2     = (const float*)d_in[19];
    const float* b2     = (const float*)d_in[20];
    const float* l2g    = (const float*)d_in[21];
    const float* l2b    = (const float*)d_in[22];
    const float* cW     = (const float*)d_in[23];
    const float* cbias  = (const float*)d_in[24];

    const size_t MH  = (size_t)Mm * Hh;                 // 3.15M
    const size_t MF  = (size_t)Mm * Ff;                 // 12.6M
    const size_t SC  = (size_t)Bb * NHh * Ss * Ss;      // 25.2M
    const size_t HHe = (size_t)Hh * Hh;
    const size_t HFe = (size_t)Hh * Ff;

    // Workspace layout (~197 MB total; round-1 proved >= 226.5 MB available)
    float* ws = (float*)d_ws;
    float* x      = ws;                                // MH f32
    float* tmp    = x + MH;                            // MH f32
    float* scores = tmp + MH;                          // SC f32
    float* ce     = scores + SC;                       // Mm f32
    float* ps     = ce + Mm;                           // 16 f32
    int*   info   = (int*)(ps + 16);                   // uses 32 ints (b*4+2, b<8)
    ushort* xb    = (ushort*)(info + 64);              // FIX r3->r4: was info+16,
                                                       // clobbered info[16..31]
                                                       // (batches 4-7) -> loss/2
    ushort* qb    = xb + MH;                           // MH
    ushort* kb    = qb + MH;                           // MH
    ushort* vb    = kb + MH;                           // MH
    ushort* ctxb  = vb + MH;                           // MH
    ushort* f1b   = ctxb + MH;                         // MF
    ushort* wscr  = f1b + MF;                          // 4*HHe + 2*HFe (per-layer)
    ushort* wqT = wscr;
    ushort* wkT = wqT + HHe;
    ushort* wvT = wkT + HHe;
    ushort* woT = wvT + HHe;
    ushort* w1T = woT + HHe;                           // [F][H]
    ushort* w2T = w1T + HFe;                           // [H][F]

    sep_kernel<<<Bb, 512, 0, stream>>>(ids, info);
    embed_ln_kernel<<<Mm, 256, 0, stream>>>(ids, we, pe, te, eg, ebp, x, xb);

    dim3 gH(Hh / 128, Mm / 128);          // (6, 32)
    dim3 gF(Ff / 128, Mm / 128);          // (24, 32)
    dim3 gS(Ss / 64, Ss / 64, Bb * NHh);  // (8, 8, 96)
    dim3 gC(Ss / 64, Bb * NHh);           // (8, 96)
    dim3 tHH(Hh / 32, Hh / 32);           // (24, 24)
    dim3 tHF(Ff / 32, Hh / 32);           // (96, 24)
    dim3 tFH(Hh / 32, Ff / 32);           // (24, 96)

    for (int l = 0; l < Ll; l++) {
        const float* bq_l = bq + (size_t)l * Hh;
        const float* bk_l = bk + (size_t)l * Hh;
        const float* bv_l = bv + (size_t)l * Hh;
        const float* bo_l = bo + (size_t)l * Hh;
        const float* b1_l = b1 + (size_t)l * Ff;
        const float* b2_l = b2 + (size_t)l * Hh;
        const float* g1  = l1g + (size_t)l * Hh;
        const float* be1 = l1b + (size_t)l * Hh;
        const float* g2  = l2g + (size_t)l * Hh;
        const float* be2 = l2b + (size_t)l * Hh;

        // Per-layer weight transpose+convert into reused scratch
        transpose_kernel<<<tHH, 256, 0, stream>>>(Wq + (size_t)l * HHe, wqT, Hh, Hh);
        transpose_kernel<<<tHH, 256, 0, stream>>>(Wk + (size_t)l * HHe, wkT, Hh, Hh);
        transpose_kernel<<<tHH, 256, 0, stream>>>(Wv + (size_t)l * HHe, wvT, Hh, Hh);
        transpose_kernel<<<tHH, 256, 0, stream>>>(Wo + (size_t)l * HHe, woT, Hh, Hh);
        transpose_kernel<<<tHF, 256, 0, stream>>>(W1 + (size_t)l * HFe, w1T, Hh, Ff);
        transpose_kernel<<<tFH, 256, 0, stream>>>(W2 + (size_t)l * HFe, w2T, Ff, Hh);

        mfma_gemm<0, 1><<<gH, 256, 0, stream>>>(xb, wqT, bq_l, qb, Hh, Hh);
        mfma_gemm<0, 1><<<gH, 256, 0, stream>>>(xb, wkT, bk_l, kb, Hh, Hh);
        mfma_gemm<0, 1><<<gH, 256, 0, stream>>>(xb, wvT, bv_l, vb, Hh, Hh);

        scores_kernel<<<gS, 256, 0, stream>>>(qb, kb, info, scores);
        softmax_kernel<<<Bb * NHh * Ss, 256, 0, stream>>>(scores);
        ctx_kernel<<<gC, 256, 0, stream>>>(scores, vb, ctxb);

        mfma_gemm<0, 0><<<gH, 256, 0, stream>>>(ctxb, woT, bo_l, tmp, Hh, Hh);
        resid_ln_kernel<<<Mm, 256, 0, stream>>>(x, tmp, g1, be1, x, xb);

        mfma_gemm<1, 1><<<gF, 256, 0, stream>>>(xb, w1T, b1_l, f1b, Ff, Hh);
        mfma_gemm<0, 0><<<gH, 256, 0, stream>>>(f1b, w2T, b2_l, tmp, Hh, Ff);
        resid_ln_kernel<<<Mm, 256, 0, stream>>>(x, tmp, g2, be2, x, xb);
    }

    cls_ce_kernel<<<Mm / CLS_ROWS, 512, 0, stream>>>(x, cW, cbias, labels, ce);
    ce_reduce_kernel<<<Bb, 256, 0, stream>>>(ce, info, ps);
    final_kernel<<<1, 64, 0, stream>>>(ps, (float*)d_out);
}

// Round 5
// 5990.882 us; speedup vs baseline: 2.4897x; 1.2268x over previous
//
#include <hip/hip_runtime.h>
#include <math.h>

typedef unsigned short ushort;
typedef __bf16 bf16x8 __attribute__((ext_vector_type(8)));
typedef float f32x4 __attribute__((ext_vector_type(4)));

// Problem dims
constexpr int Bb  = 8;
constexpr int Ss  = 512;
constexpr int Hh  = 768;
constexpr int Ll  = 12;
constexpr int NHh = 12;
constexpr int Ff  = 3072;
constexpr int Vv  = 21128;
constexpr int DHh = 64;
constexpr int Mm  = Bb * Ss;   // 4096
constexpr int SEP_ID = 102;
constexpr int VP  = 21504;     // vocab padded to 168*128
constexpr int NCH = 24;        // vocab chunks (cls grid x)
constexpr int TPC = 7;         // 128-col tiles per chunk (24*7*128 = 21504)

static __device__ __forceinline__ ushort f2bf(float f) {
    unsigned u = __float_as_uint(f);
    unsigned r = (u + 0x7fffu + ((u >> 16) & 1u)) >> 16;
    return (ushort)r;
}
static __device__ __forceinline__ float bf2f(unsigned x) {
    return __uint_as_float(x << 16);
}

// ---------------------------------------------------------------------------
// 1. Find first SEP per batch
// ---------------------------------------------------------------------------
__global__ __launch_bounds__(512) void sep_kernel(const int* __restrict__ ids,
                                                  int* __restrict__ info)
{
    int b = blockIdx.x;
    int t = threadIdx.x;
    int v = (ids[b * Ss + t] == SEP_ID) ? t : 0x7FFFFFFF;
    #pragma unroll
    for (int off = 32; off; off >>= 1) {
        int o = __shfl_xor(v, off);
        v = min(v, o);
    }
    __shared__ int wmin[8];
    int lane = t & 63, wid = t >> 6;
    if (lane == 0) wmin[wid] = v;
    __syncthreads();
    if (t == 0) {
        int first = wmin[0];
        #pragma unroll
        for (int w = 1; w < 8; w++) first = min(first, wmin[w]);
        int has = (first != 0x7FFFFFFF) ? 1 : 0;
        info[b * 4 + 0] = first;
        info[b * 4 + 1] = has;
        info[b * 4 + 2] = has ? min(first, Ss - 2) : (Ss + 1);
    }
}

// ---------------------------------------------------------------------------
// 2. Embedding + LayerNorm -> fp32 x and bf16 xb
// ---------------------------------------------------------------------------
__global__ __launch_bounds__(256) void embed_ln_kernel(
    const int* __restrict__ ids, const float* __restrict__ we,
    const float* __restrict__ pe, const float* __restrict__ te,
    const float* __restrict__ g, const float* __restrict__ bp,
    float* __restrict__ x, ushort* __restrict__ xb)
{
    int tok = blockIdx.x;
    int s = tok & (Ss - 1);
    int tid = threadIdx.x;
    int id = ids[tok];
    float e[3];
    #pragma unroll
    for (int r = 0; r < 3; r++) {
        int h = tid + (r << 8);
        e[r] = we[(size_t)id * Hh + h] + pe[(size_t)s * Hh + h] + te[h];
    }
    float sum = e[0] + e[1] + e[2];
    float sq  = fmaf(e[0], e[0], fmaf(e[1], e[1], e[2] * e[2]));
    #pragma unroll
    for (int off = 32; off; off >>= 1) {
        sum += __shfl_xor(sum, off);
        sq  += __shfl_xor(sq, off);
    }
    __shared__ float red[8];
    int lane = tid & 63, wid = tid >> 6;
    if (lane == 0) { red[wid] = sum; red[4 + wid] = sq; }
    __syncthreads();
    sum = red[0] + red[1] + red[2] + red[3];
    sq  = red[4] + red[5] + red[6] + red[7];
    float mean = sum * (1.0f / Hh);
    float var  = sq * (1.0f / Hh) - mean * mean;
    float rstd = rsqrtf(var + 1e-12f);
    #pragma unroll
    for (int r = 0; r < 3; r++) {
        int h = tid + (r << 8);
        float v = (e[r] - mean) * rstd * g[h] + bp[h];
        x[(size_t)tok * Hh + h] = v;
        xb[(size_t)tok * Hh + h] = f2bf(v);
    }
}

// ---------------------------------------------------------------------------
// 3. Residual + LayerNorm -> fp32 out and bf16 outb
// ---------------------------------------------------------------------------
__global__ __launch_bounds__(256) void resid_ln_kernel(
    const float* __restrict__ resid, const float* __restrict__ y,
    const float* __restrict__ g, const float* __restrict__ bp,
    float* __restrict__ out, ushort* __restrict__ outb)
{
    int tok = blockIdx.x;
    int tid = threadIdx.x;
    float e[3];
    #pragma unroll
    for (int r = 0; r < 3; r++) {
        int h = tid + (r << 8);
        size_t idx = (size_t)tok * Hh + h;
        e[r] = resid[idx] + y[idx];
    }
    float sum = e[0] + e[1] + e[2];
    float sq  = fmaf(e[0], e[0], fmaf(e[1], e[1], e[2] * e[2]));
    #pragma unroll
    for (int off = 32; off; off >>= 1) {
        sum += __shfl_xor(sum, off);
        sq  += __shfl_xor(sq, off);
    }
    __shared__ float red[8];
    int lane = tid & 63, wid = tid >> 6;
    if (lane == 0) { red[wid] = sum; red[4 + wid] = sq; }
    __syncthreads();
    sum = red[0] + red[1] + red[2] + red[3];
    sq  = red[4] + red[5] + red[6] + red[7];
    float mean = sum * (1.0f / Hh);
    float var  = sq * (1.0f / Hh) - mean * mean;
    float rstd = rsqrtf(var + 1e-12f);
    #pragma unroll
    for (int r = 0; r < 3; r++) {
        int h = tid + (r << 8);
        float v = (e[r] - mean) * rstd * g[h] + bp[h];
        out[(size_t)tok * Hh + h] = v;
        outb[(size_t)tok * Hh + h] = f2bf(v);
    }
}

// ---------------------------------------------------------------------------
// 4. Weight convert+transpose: Wt[n][k] = bf16(W[k][n]); K,N multiples of 32
// ---------------------------------------------------------------------------
__global__ __launch_bounds__(256) void transpose_kernel(
    const float* __restrict__ W, ushort* __restrict__ Wt, int K, int N)
{
    __shared__ float ts[32][33];
    int n0 = blockIdx.x * 32, k0 = blockIdx.y * 32;
    int tx = threadIdx.x & 31, ty = threadIdx.x >> 5;
    #pragma unroll
    for (int i = 0; i < 32; i += 8)
        ts[ty + i][tx] = W[(size_t)(k0 + ty + i) * N + n0 + tx];
    __syncthreads();
    #pragma unroll
    for (int i = 0; i < 32; i += 8)
        Wt[(size_t)(n0 + ty + i) * K + k0 + tx] = f2bf(ts[tx][ty + i]);
}

// 4b. Padded transpose for classifier: src N=Vv, dst rows padded to VP (zeros)
__global__ __launch_bounds__(256) void pad_transpose_kernel(
    const float* __restrict__ W, ushort* __restrict__ Wt, int K, int N)
{
    __shared__ float ts[32][33];
    int n0 = blockIdx.x * 32, k0 = blockIdx.y * 32;
    int tx = threadIdx.x & 31, ty = threadIdx.x >> 5;
    #pragma unroll
    for (int i = 0; i < 32; i += 8) {
        int n = n0 + tx;
        ts[ty + i][tx] = (n < N) ? W[(size_t)(k0 + ty + i) * N + n] : 0.f;
    }
    __syncthreads();
    #pragma unroll
    for (int i = 0; i < 32; i += 8)
        Wt[(size_t)(n0 + ty + i) * K + k0 + tx] = f2bf(ts[tx][ty + i]);
}

__global__ __launch_bounds__(256) void bias_pad_kernel(
    const float* __restrict__ cb, float* __restrict__ cbp)
{
    int i = blockIdx.x * 256 + threadIdx.x;
    if (i < VP) cbp[i] = (i < Vv) ? cb[i] : -1.0e9f;
}

// ---------------------------------------------------------------------------
// 5. bf16 MFMA GEMM (m97-pattern, linear LDS):
//    C[M,N] = A[M,K] @ Bt[N,K]^T + bias (opt. exact GELU)
//    128x128 tile, BK=32, 4 waves (2x2), wave tile 64x64 (4x4 frags 16x16x32)
// ---------------------------------------------------------------------------
template <int ACT, int OUT_BF>
__global__ __launch_bounds__(256) void mfma_gemm(
    const ushort* __restrict__ A,   // [M][K] bf16
    const ushort* __restrict__ Bt,  // [N][K] bf16
    const float* __restrict__ bias, // [N]
    void* __restrict__ C,           // [M][N] f32 or bf16
    int N, int K)
{
    __shared__ __align__(16) ushort As[128 * 32];
    __shared__ __align__(16) ushort Bs[128 * 32];
    const int tid = threadIdx.x;
    const int lane = tid & 63, wid = tid >> 6;
    const int m0 = blockIdx.y * 128, n0 = blockIdx.x * 128;
    const int wr = (wid >> 1) * 64, wc = (wid & 1) * 64;
    const int lr = lane & 15;
    const int kg = (lane >> 4) << 3;   // k element offset within BK=32

    f32x4 acc[4][4];
    #pragma unroll
    for (int mi = 0; mi < 4; ++mi)
        #pragma unroll
        for (int ni = 0; ni < 4; ++ni)
            acc[mi][ni] = (f32x4){0.f, 0.f, 0.f, 0.f};

    for (int k0 = 0; k0 < K; k0 += 32) {
        #pragma unroll
        for (int i = 0; i < 2; ++i) {
            int idx = i * 256 + tid;
            int r = idx >> 2, c = (idx & 3) << 3;
            __builtin_amdgcn_global_load_lds(
                (const __attribute__((address_space(1))) void*)(A + (size_t)(m0 + r) * K + k0 + c),
                (__attribute__((address_space(3))) void*)(As + (size_t)(i * 256 + (wid << 6)) * 8),
                16, 0, 0);
        }
        #pragma unroll
        for (int i = 0; i < 2; ++i) {
            int idx = i * 256 + tid;
            int r = idx >> 2, c = (idx & 3) << 3;
            __builtin_amdgcn_global_load_lds(
                (const __attribute__((address_space(1))) void*)(Bt + (size_t)(n0 + r) * K + k0 + c),
                (__attribute__((address_space(3))) void*)(Bs + (size_t)(i * 256 + (wid << 6)) * 8),
                16, 0, 0);
        }
        __syncthreads();

        bf16x8 af[4], bfr[4];
        #pragma unroll
        for (int mi = 0; mi < 4; ++mi)
            af[mi] = *(const bf16x8*)(As + (size_t)(wr + mi * 16 + lr) * 32 + kg);
        #pragma unroll
        for (int ni = 0; ni < 4; ++ni)
            bfr[ni] = *(const bf16x8*)(Bs + (size_t)(wc + ni * 16 + lr) * 32 + kg);

        #pragma unroll
        for (int mi = 0; mi < 4; ++mi)
            #pragma unroll
            for (int ni = 0; ni < 4; ++ni)
                acc[mi][ni] = __builtin_amdgcn_mfma_f32_16x16x32_bf16(
                    af[mi], bfr[ni], acc[mi][ni], 0, 0, 0);
        __syncthreads();
    }

    // Epilogue: bias (+GELU), store. C/D layout: col=lane&15, row=(lane>>4)*4+q.
    #pragma unroll
    for (int ni = 0; ni < 4; ++ni) {
        int col = n0 + wc + ni * 16 + lr;
        float bsv = bias[col];
        #pragma unroll
        for (int mi = 0; mi < 4; ++mi) {
            f32x4 v = acc[mi][ni];
            #pragma unroll
            for (int q = 0; q < 4; ++q) {
                int row = m0 + wr + mi * 16 + ((lane >> 4) << 2) + q;
                float val = v[q] + bsv;
                if (ACT == 1) val = 0.5f * val * (1.0f + erff(val * 0.70710678118654752f));
                if (OUT_BF)
                    ((ushort*)C)[(size_t)row * N + col] = f2bf(val);
                else
                    ((float*)C)[(size_t)row * N + col] = val;
            }
        }
    }
}

// ---------------------------------------------------------------------------
// 6. Attention scores (fp32 compute, bf16 q/k inputs)
// ---------------------------------------------------------------------------
__global__ __launch_bounds__(256) void scores_kernel(
    const ushort* __restrict__ q, const ushort* __restrict__ kk,
    const int* __restrict__ info, float* __restrict__ sc)
{
    int bh = blockIdx.z;
    int b = bh / NHh, h = bh % NHh;
    int i0 = blockIdx.y * 64, j0 = blockIdx.x * 64;
    __shared__ float qs[64][68];
    __shared__ float ks[64][68];
    int tid = threadIdx.x;
    const ushort* qg = q  + ((size_t)b * Ss + i0) * Hh + h * DHh;
    const ushort* kg = kk + ((size_t)b * Ss + j0) * Hh + h * DHh;
    for (int e = tid; e < 64 * 8; e += 256) {
        int r = e >> 3;
        int c = (e & 7) << 3;
        uint4 u = *(const uint4*)&qg[(size_t)r * Hh + c];
        float* dq = &qs[r][c];
        dq[0] = bf2f(u.x & 0xffff); dq[1] = bf2f(u.x >> 16);
        dq[2] = bf2f(u.y & 0xffff); dq[3] = bf2f(u.y >> 16);
        dq[4] = bf2f(u.z & 0xffff); dq[5] = bf2f(u.z >> 16);
        dq[6] = bf2f(u.w & 0xffff); dq[7] = bf2f(u.w >> 16);
        uint4 w = *(const uint4*)&kg[(size_t)r * Hh + c];
        float* dk = &ks[r][c];
        dk[0] = bf2f(w.x & 0xffff); dk[1] = bf2f(w.x >> 16);
        dk[2] = bf2f(w.y & 0xffff); dk[3] = bf2f(w.y >> 16);
        dk[4] = bf2f(w.z & 0xffff); dk[5] = bf2f(w.z >> 16);
        dk[6] = bf2f(w.w & 0xffff); dk[7] = bf2f(w.w >> 16);
    }
    __syncthreads();
    int r0 = (tid >> 4) << 2, c0 = (tid & 15) << 2;
    float acc[4][4] = {};
    #pragma unroll
    for (int d = 0; d < 64; d += 4) {
        float4 qa[4], kb[4];
        #pragma unroll
        for (int i = 0; i < 4; i++) qa[i] = *(const float4*)&qs[r0 + i][d];
        #pragma unroll
        for (int j = 0; j < 4; j++) kb[j] = *(const float4*)&ks[c0 + j][d];
        #pragma unroll
        for (int i = 0; i < 4; i++)
            #pragma unroll
            for (int j = 0; j < 4; j++) {
                acc[i][j] = fmaf(qa[i].x, kb[j].x, acc[i][j]);
                acc[i][j] = fmaf(qa[i].y, kb[j].y, acc[i][j]);
                acc[i][j] = fmaf(qa[i].z, kb[j].z, acc[i][j]);
                acc[i][j] = fmaf(qa[i].w, kb[j].w, acc[i][j]);
            }
    }
    int has = info[b * 4 + 1];
    int sep = info[b * 4 + 2];
    #pragma unroll
    for (int i = 0; i < 4; i++) {
        int gi = i0 + r0 + i;
        #pragma unroll
        for (int j = 0; j < 4; j++) {
            int gj = j0 + c0 + j;
            bool vis = (!has) || (gj <= sep) || ((gi > sep) && (gj <= gi));
            sc[((size_t)bh * Ss + gi) * Ss + gj] =
                acc[i][j] * 0.125f + (vis ? 0.0f : -1000000000.0f);
        }
    }
}

// ---------------------------------------------------------------------------
// 7. Row softmax over S=512
// ---------------------------------------------------------------------------
__global__ __launch_bounds__(256) void softmax_kernel(float* __restrict__ sc)
{
    size_t row = blockIdx.x;
    float* p = sc + row * (size_t)Ss;
    int tid = threadIdx.x;
    float a = p[tid], b = p[tid + 256];
    float mx = fmaxf(a, b);
    #pragma unroll
    for (int off = 32; off; off >>= 1) mx = fmaxf(mx, __shfl_xor(mx, off));
    __shared__ float red[4];
    int lane = tid & 63, wid = tid >> 6;
    if (lane == 0) red[wid] = mx;
    __syncthreads();
    mx = fmaxf(fmaxf(red[0], red[1]), fmaxf(red[2], red[3]));
    float ea = __expf(a - mx), eb = __expf(b - mx);
    float s = ea + eb;
    #pragma unroll
    for (int off = 32; off; off >>= 1) s += __shfl_xor(s, off);
    __syncthreads();
    if (lane == 0) red[wid] = s;
    __syncthreads();
    s = red[0] + red[1] + red[2] + red[3];
    float inv = 1.0f / s;
    p[tid] = ea * inv;
    p[tid + 256] = eb * inv;
}

// ---------------------------------------------------------------------------
// 8. ctx = probs @ v  (fp32 P, bf16 V in, bf16 ctx out)
// ---------------------------------------------------------------------------
__global__ __launch_bounds__(256) void ctx_kernel(
    const float* __restrict__ P, const ushort* __restrict__ Vb,
    ushort* __restrict__ ctx)
{
    int bh = blockIdx.y;
    int b = bh / NHh, h = bh % NHh;
    int i0 = blockIdx.x * 64;
    __shared__ float Ps[16][64];   // [k][i]
    __shared__ float Vs[16][64];   // [k][d]
    int tid = threadIdx.x;
    int pr = tid >> 2,  pk = (tid & 3) << 2;
    int vr = tid >> 4,  vc = (tid & 15) << 2;
    int r0 = (tid >> 4) << 2, c0 = (tid & 15) << 2;
    const float*  Pp = P  + ((size_t)bh * Ss + i0 + pr) * Ss + pk;
    const ushort* Vp = Vb + ((size_t)b * Ss + vr) * Hh + h * DHh + vc;
    float acc[4][4] = {};
    for (int k0 = 0; k0 < Ss; k0 += 16) {
        float4 pv = *(const float4*)(Pp + k0);
        uint2 vv = *(const uint2*)(Vp + (size_t)k0 * Hh);
        __syncthreads();
        Ps[pk + 0][pr] = pv.x;
        Ps[pk + 1][pr] = pv.y;
        Ps[pk + 2][pr] = pv.z;
        Ps[pk + 3][pr] = pv.w;
        Vs[vr][vc + 0] = bf2f(vv.x & 0xffff);
        Vs[vr][vc + 1] = bf2f(vv.x >> 16);
        Vs[vr][vc + 2] = bf2f(vv.y & 0xffff);
        Vs[vr][vc + 3] = bf2f(vv.y >> 16);
        __syncthreads();
        #pragma unroll
        for (int k = 0; k < 16; k++) {
            float4 a4 = *(const float4*)&Ps[k][r0];
            float4 b4 = *(const float4*)&Vs[k][c0];
            float aa[4] = { a4.x, a4.y, a4.z, a4.w };
            float bb[4] = { b4.x, b4.y, b4.z, b4.w };
            #pragma unroll
            for (int i = 0; i < 4; i++)
                #pragma unroll
                for (int j = 0; j < 4; j++)
                    acc[i][j] = fmaf(aa[i], bb[j], acc[i][j]);
        }
    }
    #pragma unroll
    for (int i = 0; i < 4; i++)
        #pragma unroll
        for (int j = 0; j < 4; j++)
            ctx[((size_t)b * Ss + i0 + r0 + i) * Hh + h * DHh + c0 + j] = f2bf(acc[i][j]);
}

// ---------------------------------------------------------------------------
// 9. Fused MFMA classifier + online logsumexp partials.
//    Grid (NCH, Mm/128). Each block: 128 rows x TPC*128 cols, K=768.
// ---------------------------------------------------------------------------
__global__ __launch_bounds__(256) void cls_lse_kernel(
    const ushort* __restrict__ A,    // xb [Mm][Hh] bf16
    const ushort* __restrict__ WT,   // [VP][Hh] bf16
    const float* __restrict__ cbp,   // [VP] padded bias
    const int* __restrict__ labels,
    float* __restrict__ pm, float* __restrict__ psv, float* __restrict__ pll)
{
    __shared__ __align__(16) ushort As[128 * 32];
    __shared__ __align__(16) ushort Bs[128 * 32];
    __shared__ float sm[2][128], ssum[2][128], sll[128];
    __shared__ int lab[128];
    const int tid = threadIdx.x;
    const int lane = tid & 63, wid = tid >> 6;
    const int m0 = blockIdx.y * 128;
    const int chunk = blockIdx.x;
    if (tid < 128) {
        sm[0][tid] = -3.0e38f; sm[1][tid] = -3.0e38f;
        ssum[0][tid] = 0.f; ssum[1][tid] = 0.f;
        sll[tid] = 0.f;
        lab[tid] = labels[m0 + tid];
    }
    __syncthreads();
    const int wr = (wid >> 1) * 64, wcid = wid & 1, wc = wcid * 64;
    const int lr = lane & 15;
    const int kg = (lane >> 4) << 3;

    for (int t = 0; t < TPC; ++t) {
        const int n0 = (chunk * TPC + t) * 128;
        f32x4 acc[4][4];
        #pragma unroll
        for (int mi = 0; mi < 4; ++mi)
            #pragma unroll
            for (int ni = 0; ni < 4; ++ni)
                acc[mi][ni] = (f32x4){0.f, 0.f, 0.f, 0.f};

        for (int k0 = 0; k0 < Hh; k0 += 32) {
            #pragma unroll
            for (int i = 0; i < 2; ++i) {
                int idx = i * 256 + tid;
                int r = idx >> 2, c = (idx & 3) << 3;
                __builtin_amdgcn_global_load_lds(
                    (const __attribute__((address_space(1))) void*)(A + (size_t)(m0 + r) * Hh + k0 + c),
                    (__attribute__((address_space(3))) void*)(As + (size_t)(i * 256 + (wid << 6)) * 8),
                    16, 0, 0);
            }
            #pragma unroll
            for (int i = 0; i < 2; ++i) {
                int idx = i * 256 + tid;
                int r = idx >> 2, c = (idx & 3) << 3;
                __builtin_amdgcn_global_load_lds(
                    (const __attribute__((address_space(1))) void*)(WT + (size_t)(n0 + r) * Hh + k0 + c),
                    (__attribute__((address_space(3))) void*)(Bs + (size_t)(i * 256 + (wid << 6)) * 8),
                    16, 0, 0);
            }
            __syncthreads();

            bf16x8 af[4], bfr[4];
            #pragma unroll
            for (int mi = 0; mi < 4; ++mi)
                af[mi] = *(const bf16x8*)(As + (size_t)(wr + mi * 16 + lr) * 32 + kg);
            #pragma unroll
            for (int ni = 0; ni < 4; ++ni)
                bfr[ni] = *(const bf16x8*)(Bs + (size_t)(wc + ni * 16 + lr) * 32 + kg);

            #pragma unroll
            for (int mi = 0; mi < 4; ++mi)
                #pragma unroll
                for (int ni = 0; ni < 4; ++ni)
                    acc[mi][ni] = __builtin_amdgcn_mfma_f32_16x16x32_bf16(
                        af[mi], bfr[ni], acc[mi][ni], 0, 0, 0);
            __syncthreads();
        }

        // Online-logsumexp epilogue for this 128x128 tile.
        float bvs[4];
        int cols[4];
        #pragma unroll
        for (int ni = 0; ni < 4; ++ni) {
            cols[ni] = n0 + wc + ni * 16 + lr;
            bvs[ni] = cbp[cols[ni]];
        }
        #pragma unroll
        for (int mi = 0; mi < 4; ++mi) {
            #pragma unroll
            for (int q = 0; q < 4; ++q) {
                int rl = wr + mi * 16 + ((lane >> 4) << 2) + q;
                float v0 = acc[mi][0][q] + bvs[0];
                float v1 = acc[mi][1][q] + bvs[1];
                float v2 = acc[mi][2][q] + bvs[2];
                float v3 = acc[mi][3][q] + bvs[3];
                int lb = lab[rl];
                if (lb == cols[0]) sll[rl] = v0;
                if (lb == cols[1]) sll[rl] = v1;
                if (lb == cols[2]) sll[rl] = v2;
                if (lb == cols[3]) sll[rl] = v3;
                float vmax = fmaxf(fmaxf(v0, v1), fmaxf(v2, v3));
                #pragma unroll
                for (int off = 1; off < 16; off <<= 1)
                    vmax = fmaxf(vmax, __shfl_xor(vmax, off));
                float se = __expf(v0 - vmax) + __expf(v1 - vmax)
                         + __expf(v2 - vmax) + __expf(v3 - vmax);
                #pragma unroll
                for (int off = 1; off < 16; off <<= 1)
                    se += __shfl_xor(se, off);
                if (lr == 0) {
                    float om = sm[wcid][rl], os = ssum[wcid][rl];
                    float nm = fmaxf(om, vmax);
                    ssum[wcid][rl] = os * __expf(om - nm) + se * __expf(vmax - nm);
                    sm[wcid][rl] = nm;
                }
            }
        }
    }
    __syncthreads();
    if (tid < 128) {
        float am = sm[0][tid], as = ssum[0][tid];
        float bm = sm[1][tid], bs = ssum[1][tid];
        float nm = fmaxf(am, bm);
        float s = as * __expf(am - nm) + bs * __expf(bm - nm);
        pm [(size_t)chunk * Mm + m0 + tid] = nm;
        psv[(size_t)chunk * Mm + m0 + tid] = s;
        pll[(size_t)chunk * Mm + m0 + tid] = sll[tid];
    }
}

// 9b. Merge vocab-chunk partials -> per-token CE
__global__ __launch_bounds__(256) void cls_merge_kernel(
    const float* __restrict__ pm, const float* __restrict__ psv,
    const float* __restrict__ pll, float* __restrict__ ce)
{
    int row = blockIdx.x * 256 + threadIdx.x;
    float m = -3.0e38f, s = 0.f, l = 0.f;
    #pragma unroll 1
    for (int c = 0; c < NCH; ++c) {
        float cm = pm[(size_t)c * Mm + row];
        float cs = psv[(size_t)c * Mm + row];
        float nm = fmaxf(m, cm);
        s = s * __expf(m - nm) + cs * __expf(cm - nm);
        m = nm;
        l += pll[(size_t)c * Mm + row];
    }
    ce[row] = (m + logf(s)) - l;
}

// ---------------------------------------------------------------------------
// 10. Masked per-sample mean, final scalar
// ---------------------------------------------------------------------------
__global__ __launch_bounds__(256) void ce_reduce_kernel(
    const float* __restrict__ ce, const int* __restrict__ info,
    float* __restrict__ ps)
{
    int b = blockIdx.x, tid = threadIdx.x;
    int first = info[b * 4 + 0], has = info[b * 4 + 1];
    float sum = 0.0f;
    for (int s = tid; s < Ss; s += 256) {
        bool mv = has ? (s > first) : true;
        if (mv) sum += ce[b * Ss + s];
    }
    #pragma unroll
    for (int off = 32; off; off >>= 1) sum += __shfl_xor(sum, off);
    __shared__ float red[4];
    int lane = tid & 63, wid = tid >> 6;
    if (lane == 0) red[wid] = sum;
    __syncthreads();
    if (tid == 0) {
        float tot = red[0] + red[1] + red[2] + red[3];
        float cnt = has ? (float)(Ss - 1 - first) : (float)Ss;
        ps[b] = tot / cnt;
    }
}

__global__ void final_kernel(const float* __restrict__ ps, float* __restrict__ out)
{
    if (threadIdx.x == 0 && blockIdx.x == 0) {
        float t = 0.0f;
        #pragma unroll
        for (int b = 0; b < Bb; b++) t += ps[b];
        out[0] = t * (1.0f / Bb);
    }
}

// ---------------------------------------------------------------------------
// Host launcher
// ---------------------------------------------------------------------------
extern "C" void kernel_launch(void* const* d_in, const int* in_sizes, int n_in,
                              void* d_out, int out_size, void* d_ws, size_t ws_size,
                              hipStream_t stream)
{
    const int*   ids    = (const int*)d_in[0];
    const int*   labels = (const int*)d_in[1];
    const float* we     = (const float*)d_in[2];
    const float* pe     = (const float*)d_in[3];
    const float* te     = (const float*)d_in[4];
    const float* eg     = (const float*)d_in[5];
    const float* ebp    = (const float*)d_in[6];
    const float* Wq     = (const float*)d_in[7];
    const float* bq     = (const float*)d_in[8];
    const float* Wk     = (const float*)d_in[9];
    const float* bk     = (const float*)d_in[10];
    const float* Wv     = (const float*)d_in[11];
    const float* bv     = (const float*)d_in[12];
    const float* Wo     = (const float*)d_in[13];
    const float* bo     = (const float*)d_in[14];
    const float* l1g    = (const float*)d_in[15];
    const float* l1b    = (const float*)d_in[16];
    const float* W1     = (const float*)d_in[17];
    const float* b1     = (const float*)d_in[18];
    const float* W2     = (const float*)d_in[19];
    const float* b2     = (const float*)d_in[20];
    const float* l2g    = (const float*)d_in[21];
    const float* l2b    = (const float*)d_in[22];
    const float* cW     = (const float*)d_in[23];
    const float* cbias  = (const float*)d_in[24];

    const size_t MH  = (size_t)Mm * Hh;                 // 3.15M
    const size_t MF  = (size_t)Mm * Ff;                 // 12.6M
    const size_t SC  = (size_t)Bb * NHh * Ss * Ss;      // 25.2M
    const size_t HHe = (size_t)Hh * Hh;
    const size_t HFe = (size_t)Hh * Ff;

    // Workspace layout (~198 MB; proven safe in round 4)
    float* ws = (float*)d_ws;
    float* x      = ws;                                // MH f32
    float* tmp    = x + MH;                            // MH f32
    float* scores = tmp + MH;                          // SC f32
    float* ce     = scores + SC;                       // Mm f32
    float* ps     = ce + Mm;                           // 16 f32
    int*   info   = (int*)(ps + 16);                   // 64 ints reserved
    ushort* xb    = (ushort*)(info + 64);              // MH bf16
    ushort* qb    = xb + MH;                           // MH
    ushort* kb    = qb + MH;                           // MH
    ushort* vb    = kb + MH;                           // MH
    ushort* ctxb  = vb + MH;                           // MH
    ushort* f1b   = ctxb + MH;                         // MF
    ushort* wscr  = f1b + MF;                          // 4*HHe + 2*HFe bf16
    ushort* wqT = wscr;
    ushort* wkT = wqT + HHe;
    ushort* wvT = wkT + HHe;
    ushort* woT = wvT + HHe;
    ushort* w1T = woT + HHe;                           // [F][H]
    ushort* w2T = w1T + HFe;                           // [H][F]

    // Classifier-phase aliases (all dead after the layer loop):
    ushort* cWT = qb;                  // VP*Hh = 16.5M ushort <= qb..f1b (25.2M)
    float* cbp  = scores;                              // VP floats
    float* pm   = scores + 32768;                      // NCH*Mm
    float* psv  = pm + (size_t)NCH * Mm;               // NCH*Mm
    float* pll  = psv + (size_t)NCH * Mm;              // NCH*Mm

    sep_kernel<<<Bb, 512, 0, stream>>>(ids, info);
    embed_ln_kernel<<<Mm, 256, 0, stream>>>(ids, we, pe, te, eg, ebp, x, xb);

    dim3 gH(Hh / 128, Mm / 128);          // (6, 32)
    dim3 gF(Ff / 128, Mm / 128);          // (24, 32)
    dim3 gS(Ss / 64, Ss / 64, Bb * NHh);  // (8, 8, 96)
    dim3 gC(Ss / 64, Bb * NHh);           // (8, 96)
    dim3 tHH(Hh / 32, Hh / 32);           // (24, 24)
    dim3 tHF(Ff / 32, Hh / 32);           // (96, 24)
    dim3 tFH(Hh / 32, Ff / 32);           // (24, 96)

    for (int l = 0; l < Ll; l++) {
        const float* bq_l = bq + (size_t)l * Hh;
        const float* bk_l = bk + (size_t)l * Hh;
        const float* bv_l = bv + (size_t)l * Hh;
        const float* bo_l = bo + (size_t)l * Hh;
        const float* b1_l = b1 + (size_t)l * Ff;
        const float* b2_l = b2 + (size_t)l * Hh;
        const float* g1  = l1g + (size_t)l * Hh;
        const float* be1 = l1b + (size_t)l * Hh;
        const float* g2  = l2g + (size_t)l * Hh;
        const float* be2 = l2b + (size_t)l * Hh;

        transpose_kernel<<<tHH, 256, 0, stream>>>(Wq + (size_t)l * HHe, wqT, Hh, Hh);
        transpose_kernel<<<tHH, 256, 0, stream>>>(Wk + (size_t)l * HHe, wkT, Hh, Hh);
        transpose_kernel<<<tHH, 256, 0, stream>>>(Wv + (size_t)l * HHe, wvT, Hh, Hh);
        transpose_kernel<<<tHH, 256, 0, stream>>>(Wo + (size_t)l * HHe, woT, Hh, Hh);
        transpose_kernel<<<tHF, 256, 0, stream>>>(W1 + (size_t)l * HFe, w1T, Hh, Ff);
        transpose_kernel<<<tFH, 256, 0, stream>>>(W2 + (size_t)l * HFe, w2T, Ff, Hh);

        mfma_gemm<0, 1><<<gH, 256, 0, stream>>>(xb, wqT, bq_l, qb, Hh, Hh);
        mfma_gemm<0, 1><<<gH, 256, 0, stream>>>(xb, wkT, bk_l, kb, Hh, Hh);
        mfma_gemm<0, 1><<<gH, 256, 0, stream>>>(xb, wvT, bv_l, vb, Hh, Hh);

        scores_kernel<<<gS, 256, 0, stream>>>(qb, kb, info, scores);
        softmax_kernel<<<Bb * NHh * Ss, 256, 0, stream>>>(scores);
        ctx_kernel<<<gC, 256, 0, stream>>>(scores, vb, ctxb);

        mfma_gemm<0, 0><<<gH, 256, 0, stream>>>(ctxb, woT, bo_l, tmp, Hh, Hh);
        resid_ln_kernel<<<Mm, 256, 0, stream>>>(x, tmp, g1, be1, x, xb);

        mfma_gemm<1, 1><<<gF, 256, 0, stream>>>(xb, w1T, b1_l, f1b, Ff, Hh);
        mfma_gemm<0, 0><<<gH, 256, 0, stream>>>(f1b, w2T, b2_l, tmp, Hh, Ff);
        resid_ln_kernel<<<Mm, 256, 0, stream>>>(x, tmp, g2, be2, x, xb);
    }

    // Classifier: pad/transpose weights, fused MFMA + online logsumexp
    pad_transpose_kernel<<<dim3(VP / 32, Hh / 32), 256, 0, stream>>>(cW, cWT, Hh, Vv);
    bias_pad_kernel<<<(VP + 255) / 256, 256, 0, stream>>>(cbias, cbp);
    cls_lse_kernel<<<dim3(NCH, Mm / 128), 256, 0, stream>>>(
        xb, cWT, cbp, labels, pm, psv, pll);
    cls_merge_kernel<<<Mm / 256, 256, 0, stream>>>(pm, psv, pll, ce);
    ce_reduce_kernel<<<Bb, 256, 0, stream>>>(ce, info, ps);
    final_kernel<<<1, 64, 0, stream>>>(ps, (float*)d_out);
}

// Round 6
// 3159.432 us; speedup vs baseline: 4.7209x; 1.8962x over previous
//
#include <hip/hip_runtime.h>
#include <math.h>

typedef unsigned short ushort;
typedef __bf16 bf16x8 __attribute__((ext_vector_type(8)));
typedef float f32x4 __attribute__((ext_vector_type(4)));

// Problem dims
constexpr int Bb  = 8;
constexpr int Ss  = 512;
constexpr int Hh  = 768;
constexpr int Ll  = 12;
constexpr int NHh = 12;
constexpr int Ff  = 3072;
constexpr int Vv  = 21128;
constexpr int DHh = 64;
constexpr int Mm  = Bb * Ss;   // 4096
constexpr int SEP_ID = 102;
constexpr int VP  = 21504;     // vocab padded to 168*128
constexpr int NCH = 24;        // vocab chunks (cls grid x)
constexpr int TPC = 7;         // 128-col tiles per chunk
constexpr int QKVN = 3 * Hh;   // 2304

static __device__ __forceinline__ ushort f2bf(float f) {
    unsigned u = __float_as_uint(f);
    unsigned r = (u + 0x7fffu + ((u >> 16) & 1u)) >> 16;
    return (ushort)r;
}
static __device__ __forceinline__ float bf2f(unsigned x) {
    return __uint_as_float(x << 16);
}

// ---------------------------------------------------------------------------
// 1. Find first SEP per batch
// ---------------------------------------------------------------------------
__global__ __launch_bounds__(512) void sep_kernel(const int* __restrict__ ids,
                                                  int* __restrict__ info)
{
    int b = blockIdx.x;
    int t = threadIdx.x;
    int v = (ids[b * Ss + t] == SEP_ID) ? t : 0x7FFFFFFF;
    #pragma unroll
    for (int off = 32; off; off >>= 1) {
        int o = __shfl_xor(v, off);
        v = min(v, o);
    }
    __shared__ int wmin[8];
    int lane = t & 63, wid = t >> 6;
    if (lane == 0) wmin[wid] = v;
    __syncthreads();
    if (t == 0) {
        int first = wmin[0];
        #pragma unroll
        for (int w = 1; w < 8; w++) first = min(first, wmin[w]);
        int has = (first != 0x7FFFFFFF) ? 1 : 0;
        info[b * 4 + 0] = first;
        info[b * 4 + 1] = has;
        info[b * 4 + 2] = has ? min(first, Ss - 2) : (Ss + 1);
    }
}

// ---------------------------------------------------------------------------
// 2. Embedding + LayerNorm -> fp32 x and bf16 xb
// ---------------------------------------------------------------------------
__global__ __launch_bounds__(256) void embed_ln_kernel(
    const int* __restrict__ ids, const float* __restrict__ we,
    const float* __restrict__ pe, const float* __restrict__ te,
    const float* __restrict__ g, const float* __restrict__ bp,
    float* __restrict__ x, ushort* __restrict__ xb)
{
    int tok = blockIdx.x;
    int s = tok & (Ss - 1);
    int tid = threadIdx.x;
    int id = ids[tok];
    float e[3];
    #pragma unroll
    for (int r = 0; r < 3; r++) {
        int h = tid + (r << 8);
        e[r] = we[(size_t)id * Hh + h] + pe[(size_t)s * Hh + h] + te[h];
    }
    float sum = e[0] + e[1] + e[2];
    float sq  = fmaf(e[0], e[0], fmaf(e[1], e[1], e[2] * e[2]));
    #pragma unroll
    for (int off = 32; off; off >>= 1) {
        sum += __shfl_xor(sum, off);
        sq  += __shfl_xor(sq, off);
    }
    __shared__ float red[8];
    int lane = tid & 63, wid = tid >> 6;
    if (lane == 0) { red[wid] = sum; red[4 + wid] = sq; }
    __syncthreads();
    sum = red[0] + red[1] + red[2] + red[3];
    sq  = red[4] + red[5] + red[6] + red[7];
    float mean = sum * (1.0f / Hh);
    float var  = sq * (1.0f / Hh) - mean * mean;
    float rstd = rsqrtf(var + 1e-12f);
    #pragma unroll
    for (int r = 0; r < 3; r++) {
        int h = tid + (r << 8);
        float v = (e[r] - mean) * rstd * g[h] + bp[h];
        x[(size_t)tok * Hh + h] = v;
        xb[(size_t)tok * Hh + h] = f2bf(v);
    }
}

// ---------------------------------------------------------------------------
// 3. Residual + LayerNorm -> fp32 out and bf16 outb
// ---------------------------------------------------------------------------
__global__ __launch_bounds__(256) void resid_ln_kernel(
    const float* __restrict__ resid, const float* __restrict__ y,
    const float* __restrict__ g, const float* __restrict__ bp,
    float* __restrict__ out, ushort* __restrict__ outb)
{
    int tok = blockIdx.x;
    int tid = threadIdx.x;
    float e[3];
    #pragma unroll
    for (int r = 0; r < 3; r++) {
        int h = tid + (r << 8);
        size_t idx = (size_t)tok * Hh + h;
        e[r] = resid[idx] + y[idx];
    }
    float sum = e[0] + e[1] + e[2];
    float sq  = fmaf(e[0], e[0], fmaf(e[1], e[1], e[2] * e[2]));
    #pragma unroll
    for (int off = 32; off; off >>= 1) {
        sum += __shfl_xor(sum, off);
        sq  += __shfl_xor(sq, off);
    }
    __shared__ float red[8];
    int lane = tid & 63, wid = tid >> 6;
    if (lane == 0) { red[wid] = sum; red[4 + wid] = sq; }
    __syncthreads();
    sum = red[0] + red[1] + red[2] + red[3];
    sq  = red[4] + red[5] + red[6] + red[7];
    float mean = sum * (1.0f / Hh);
    float var  = sq * (1.0f / Hh) - mean * mean;
    float rstd = rsqrtf(var + 1e-12f);
    #pragma unroll
    for (int r = 0; r < 3; r++) {
        int h = tid + (r << 8);
        float v = (e[r] - mean) * rstd * g[h] + bp[h];
        out[(size_t)tok * Hh + h] = v;
        outb[(size_t)tok * Hh + h] = f2bf(v);
    }
}

// ---------------------------------------------------------------------------
// 4. Weight convert+transpose; padded variant; bias helpers
// ---------------------------------------------------------------------------
__global__ __launch_bounds__(256) void transpose_kernel(
    const float* __restrict__ W, ushort* __restrict__ Wt, int K, int N)
{
    __shared__ float ts[32][33];
    int n0 = blockIdx.x * 32, k0 = blockIdx.y * 32;
    int tx = threadIdx.x & 31, ty = threadIdx.x >> 5;
    #pragma unroll
    for (int i = 0; i < 32; i += 8)
        ts[ty + i][tx] = W[(size_t)(k0 + ty + i) * N + n0 + tx];
    __syncthreads();
    #pragma unroll
    for (int i = 0; i < 32; i += 8)
        Wt[(size_t)(n0 + ty + i) * K + k0 + tx] = f2bf(ts[tx][ty + i]);
}

__global__ __launch_bounds__(256) void pad_transpose_kernel(
    const float* __restrict__ W, ushort* __restrict__ Wt, int K, int N)
{
    __shared__ float ts[32][33];
    int n0 = blockIdx.x * 32, k0 = blockIdx.y * 32;
    int tx = threadIdx.x & 31, ty = threadIdx.x >> 5;
    #pragma unroll
    for (int i = 0; i < 32; i += 8) {
        int n = n0 + tx;
        ts[ty + i][tx] = (n < N) ? W[(size_t)(k0 + ty + i) * N + n] : 0.f;
    }
    __syncthreads();
    #pragma unroll
    for (int i = 0; i < 32; i += 8)
        Wt[(size_t)(n0 + ty + i) * K + k0 + tx] = f2bf(ts[tx][ty + i]);
}

__global__ __launch_bounds__(256) void bias_pad_kernel(
    const float* __restrict__ cb, float* __restrict__ cbp)
{
    int i = blockIdx.x * 256 + threadIdx.x;
    if (i < VP) cbp[i] = (i < Vv) ? cb[i] : -1.0e9f;
}

__global__ __launch_bounds__(256) void bias_concat_kernel(
    const float* __restrict__ a, const float* __restrict__ b,
    const float* __restrict__ c, float* __restrict__ out)
{
    int i = blockIdx.x * 256 + threadIdx.x;
    if (i < Hh) {
        out[i] = a[i];
        out[Hh + i] = b[i];
        out[2 * Hh + i] = c[i];
    }
}

// ---------------------------------------------------------------------------
// 5. bf16 MFMA GEMM (m97-pattern): C[M,N] = A[M,K] @ Bt[N,K]^T + bias
// ---------------------------------------------------------------------------
template <int ACT, int OUT_BF>
__global__ __launch_bounds__(256) void mfma_gemm(
    const ushort* __restrict__ A,   // [M][K] bf16
    const ushort* __restrict__ Bt,  // [N][K] bf16
    const float* __restrict__ bias, // [N]
    void* __restrict__ C,           // [M][N] f32 or bf16
    int N, int K)
{
    __shared__ __align__(16) ushort As[128 * 32];
    __shared__ __align__(16) ushort Bs[128 * 32];
    const int tid = threadIdx.x;
    const int lane = tid & 63, wid = tid >> 6;
    const int m0 = blockIdx.y * 128, n0 = blockIdx.x * 128;
    const int wr = (wid >> 1) * 64, wc = (wid & 1) * 64;
    const int lr = lane & 15;
    const int kg = (lane >> 4) << 3;

    f32x4 acc[4][4];
    #pragma unroll
    for (int mi = 0; mi < 4; ++mi)
        #pragma unroll
        for (int ni = 0; ni < 4; ++ni)
            acc[mi][ni] = (f32x4){0.f, 0.f, 0.f, 0.f};

    for (int k0 = 0; k0 < K; k0 += 32) {
        #pragma unroll
        for (int i = 0; i < 2; ++i) {
            int idx = i * 256 + tid;
            int r = idx >> 2, c = (idx & 3) << 3;
            __builtin_amdgcn_global_load_lds(
                (const __attribute__((address_space(1))) void*)(A + (size_t)(m0 + r) * K + k0 + c),
                (__attribute__((address_space(3))) void*)(As + (size_t)(i * 256 + (wid << 6)) * 8),
                16, 0, 0);
        }
        #pragma unroll
        for (int i = 0; i < 2; ++i) {
            int idx = i * 256 + tid;
            int r = idx >> 2, c = (idx & 3) << 3;
            __builtin_amdgcn_global_load_lds(
                (const __attribute__((address_space(1))) void*)(Bt + (size_t)(n0 + r) * K + k0 + c),
                (__attribute__((address_space(3))) void*)(Bs + (size_t)(i * 256 + (wid << 6)) * 8),
                16, 0, 0);
        }
        __syncthreads();

        bf16x8 af[4], bfr[4];
        #pragma unroll
        for (int mi = 0; mi < 4; ++mi)
            af[mi] = *(const bf16x8*)(As + (size_t)(wr + mi * 16 + lr) * 32 + kg);
        #pragma unroll
        for (int ni = 0; ni < 4; ++ni)
            bfr[ni] = *(const bf16x8*)(Bs + (size_t)(wc + ni * 16 + lr) * 32 + kg);

        #pragma unroll
        for (int mi = 0; mi < 4; ++mi)
            #pragma unroll
            for (int ni = 0; ni < 4; ++ni)
                acc[mi][ni] = __builtin_amdgcn_mfma_f32_16x16x32_bf16(
                    af[mi], bfr[ni], acc[mi][ni], 0, 0, 0);
        __syncthreads();
    }

    #pragma unroll
    for (int ni = 0; ni < 4; ++ni) {
        int col = n0 + wc + ni * 16 + lr;
        float bsv = bias[col];
        #pragma unroll
        for (int mi = 0; mi < 4; ++mi) {
            f32x4 v = acc[mi][ni];
            #pragma unroll
            for (int q = 0; q < 4; ++q) {
                int row = m0 + wr + mi * 16 + ((lane >> 4) << 2) + q;
                float val = v[q] + bsv;
                if (ACT == 1) val = 0.5f * val * (1.0f + erff(val * 0.70710678118654752f));
                if (OUT_BF)
                    ((ushort*)C)[(size_t)row * N + col] = f2bf(val);
                else
                    ((float*)C)[(size_t)row * N + col] = val;
            }
        }
    }
}

// ---------------------------------------------------------------------------
// 6. Fused MFMA flash attention.
//    qkv: [Mm][2304] bf16 (q|k|v per token). ctx out: [Mm][768] bf16.
//    Block: 64 q-rows x one (b,h). 4 waves, wave tile 32x32. 8 KV tiles of 64.
// ---------------------------------------------------------------------------
constexpr int SP = 65;   // S_lds stride (f32)
constexpr int PS = 72;   // P_lds stride (u16), 16B-aligned rows
constexpr int VS = 72;   // Vt_lds stride (u16)

__global__ __launch_bounds__(256) void flash_attn_kernel(
    const ushort* __restrict__ qkv, const int* __restrict__ info,
    ushort* __restrict__ ctx)
{
    __shared__ __align__(16) ushort K_lds[64 * 64];
    __shared__ __align__(16) ushort Vt_lds[64 * VS];
    __shared__ __align__(16) ushort P_lds[64 * PS];
    __shared__ float S_lds[64 * SP];
    __shared__ float m_s[64], l_s[64], rf_s[64];

    const int tid = threadIdx.x;
    const int lane = tid & 63, wid = tid >> 6;
    const int bh = blockIdx.y, b = bh / NHh, h = bh % NHh;
    const int i0 = blockIdx.x * 64;
    const int lr = lane & 15, hi = lane >> 4;
    const int kg = hi << 3;
    const int wr = (wid >> 1) * 32;   // wave q-row offset
    const int wc = (wid & 1) * 32;    // wave kv-col (QK) / d-col (PV) offset
    const int has = info[b * 4 + 1], sep = info[b * 4 + 2];
    const size_t tok0 = (size_t)b * Ss;

    // Q fragments, held across all KV tiles
    bf16x8 qf[2][2];
    #pragma unroll
    for (int mi = 0; mi < 2; ++mi)
        #pragma unroll
        for (int kk = 0; kk < 2; ++kk)
            qf[mi][kk] = *(const bf16x8*)&qkv[(tok0 + i0 + wr + mi * 16 + lr) * QKVN
                                             + h * DHh + kk * 32 + kg];

    f32x4 o[2][2];
    #pragma unroll
    for (int mi = 0; mi < 2; ++mi)
        #pragma unroll
        for (int ni = 0; ni < 2; ++ni)
            o[mi][ni] = (f32x4){0.f, 0.f, 0.f, 0.f};

    if (tid < 64) { m_s[tid] = -3.0e38f; l_s[tid] = 0.f; }
    __syncthreads();

    for (int j0 = 0; j0 < Ss; j0 += 64) {
        // stage K tile [kv=64][d=64] via global_load_lds (linear)
        #pragma unroll
        for (int i = 0; i < 2; ++i) {
            int idx = i * 256 + tid;
            int r = idx >> 3, c = (idx & 7) << 3;
            __builtin_amdgcn_global_load_lds(
                (const __attribute__((address_space(1))) void*)
                    (qkv + (tok0 + j0 + r) * QKVN + Hh + h * DHh + c),
                (__attribute__((address_space(3))) void*)(K_lds + (size_t)idx * 8),
                16, 0, 0);
        }
        // stage V transposed: Vt[d][kv] via 4x4 register transpose
        {
            int kv0 = (tid & 15) * 4;
            int d0 = (tid >> 4) * 4;
            uint2 rv[4];
            #pragma unroll
            for (int r = 0; r < 4; ++r)
                rv[r] = *(const uint2*)&qkv[(tok0 + j0 + kv0 + r) * QKVN
                                            + 2 * Hh + h * DHh + d0];
            #pragma unroll
            for (int c = 0; c < 4; ++c) {
                unsigned e0 = (c < 2) ? (rv[0].x >> (16 * c)) : (rv[0].y >> (16 * (c - 2)));
                unsigned e1 = (c < 2) ? (rv[1].x >> (16 * c)) : (rv[1].y >> (16 * (c - 2)));
                unsigned e2 = (c < 2) ? (rv[2].x >> (16 * c)) : (rv[2].y >> (16 * (c - 2)));
                unsigned e3 = (c < 2) ? (rv[3].x >> (16 * c)) : (rv[3].y >> (16 * (c - 2)));
                uint2 packed;
                packed.x = (e0 & 0xffffu) | (e1 << 16);
                packed.y = (e2 & 0xffffu) | (e3 << 16);
                *(uint2*)&Vt_lds[(size_t)(d0 + c) * VS + kv0] = packed;
            }
        }
        __syncthreads();

        // QK^T MFMA -> S fragments
        f32x4 s[2][2];
        #pragma unroll
        for (int mi = 0; mi < 2; ++mi)
            #pragma unroll
            for (int ni = 0; ni < 2; ++ni)
                s[mi][ni] = (f32x4){0.f, 0.f, 0.f, 0.f};
        #pragma unroll
        for (int ni = 0; ni < 2; ++ni)
            #pragma unroll
            for (int kk = 0; kk < 2; ++kk) {
                bf16x8 kf = *(const bf16x8*)&K_lds[(size_t)(wc + ni * 16 + lr) * 64
                                                   + kk * 32 + kg];
                #pragma unroll
                for (int mi = 0; mi < 2; ++mi)
                    s[mi][ni] = __builtin_amdgcn_mfma_f32_16x16x32_bf16(
                        qf[mi][kk], kf, s[mi][ni], 0, 0, 0);
            }
        // store S with scale + visibility bias
        #pragma unroll
        for (int mi = 0; mi < 2; ++mi)
            #pragma unroll
            for (int ni = 0; ni < 2; ++ni)
                #pragma unroll
                for (int q = 0; q < 4; ++q) {
                    int rl = wr + mi * 16 + hi * 4 + q;
                    int cl = wc + ni * 16 + lr;
                    int gi = i0 + rl, gj = j0 + cl;
                    bool vis = (!has) || (gj <= sep) || ((gi > sep) && (gj <= gi));
                    S_lds[rl * SP + cl] = s[mi][ni][q] * 0.125f
                                          + (vis ? 0.0f : -1000000000.0f);
                }
        __syncthreads();

        // online softmax: 4 threads per row, 16 cols each (same-wave rows)
        {
            int r = tid >> 2, c0 = (tid & 3) * 16;
            float mold = m_s[r];
            float sv[16];
            float tmax = -3.0e38f;
            #pragma unroll
            for (int c = 0; c < 16; ++c) {
                sv[c] = S_lds[r * SP + c0 + c];
                tmax = fmaxf(tmax, sv[c]);
            }
            tmax = fmaxf(tmax, __shfl_xor(tmax, 1));
            tmax = fmaxf(tmax, __shfl_xor(tmax, 2));
            float mnew = fmaxf(mold, tmax);
            float sum = 0.f;
            #pragma unroll
            for (int c = 0; c < 16; ++c) {
                float p = __expf(sv[c] - mnew);
                P_lds[r * PS + c0 + c] = f2bf(p);
                sum += p;
            }
            sum += __shfl_xor(sum, 1);
            sum += __shfl_xor(sum, 2);
            if ((tid & 3) == 0) {
                float rf = __expf(mold - mnew);
                rf_s[r] = rf;
                l_s[r] = l_s[r] * rf + sum;
                m_s[r] = mnew;
            }
        }
        __syncthreads();

        // rescale O, then PV MFMA
        #pragma unroll
        for (int mi = 0; mi < 2; ++mi)
            #pragma unroll
            for (int q = 0; q < 4; ++q) {
                float rf = rf_s[wr + mi * 16 + hi * 4 + q];
                #pragma unroll
                for (int ni = 0; ni < 2; ++ni)
                    o[mi][ni][q] *= rf;
            }
        #pragma unroll
        for (int kk = 0; kk < 2; ++kk) {
            bf16x8 pf[2];
            #pragma unroll
            for (int mi = 0; mi < 2; ++mi)
                pf[mi] = *(const bf16x8*)&P_lds[(size_t)(wr + mi * 16 + lr) * PS
                                                + kk * 32 + kg];
            #pragma unroll
            for (int ni = 0; ni < 2; ++ni) {
                bf16x8 vf = *(const bf16x8*)&Vt_lds[(size_t)(wc + ni * 16 + lr) * VS
                                                    + kk * 32 + kg];
                #pragma unroll
                for (int mi = 0; mi < 2; ++mi)
                    o[mi][ni] = __builtin_amdgcn_mfma_f32_16x16x32_bf16(
                        pf[mi], vf, o[mi][ni], 0, 0, 0);
            }
        }
        __syncthreads();   // protect K/Vt/S/P before next staging
    }

    // epilogue: divide by l, store ctx
    #pragma unroll
    for (int mi = 0; mi < 2; ++mi)
        #pragma unroll
        for (int q = 0; q < 4; ++q) {
            int rl = wr + mi * 16 + hi * 4 + q;
            float inv = 1.0f / l_s[rl];
            #pragma unroll
            for (int ni = 0; ni < 2; ++ni)
                ctx[(tok0 + i0 + rl) * Hh + h * DHh + wc + ni * 16 + lr]
                    = f2bf(o[mi][ni][q] * inv);
        }
}

// ---------------------------------------------------------------------------
// 7. Fused MFMA classifier + online logsumexp partials
// ---------------------------------------------------------------------------
__global__ __launch_bounds__(256) void cls_lse_kernel(
    const ushort* __restrict__ A,    // xb [Mm][Hh] bf16
    const ushort* __restrict__ WT,   // [VP][Hh] bf16
    const float* __restrict__ cbp,   // [VP] padded bias
    const int* __restrict__ labels,
    float* __restrict__ pm, float* __restrict__ psv, float* __restrict__ pll)
{
    __shared__ __align__(16) ushort As[128 * 32];
    __shared__ __align__(16) ushort Bs[128 * 32];
    __shared__ float sm[2][128], ssum[2][128], sll[128];
    __shared__ int lab[128];
    const int tid = threadIdx.x;
    const int lane = tid & 63, wid = tid >> 6;
    const int m0 = blockIdx.y * 128;
    const int chunk = blockIdx.x;
    if (tid < 128) {
        sm[0][tid] = -3.0e38f; sm[1][tid] = -3.0e38f;
        ssum[0][tid] = 0.f; ssum[1][tid] = 0.f;
        sll[tid] = 0.f;
        lab[tid] = labels[m0 + tid];
    }
    __syncthreads();
    const int wr = (wid >> 1) * 64, wcid = wid & 1, wc = wcid * 64;
    const int lr = lane & 15;
    const int kg = (lane >> 4) << 3;

    for (int t = 0; t < TPC; ++t) {
        const int n0 = (chunk * TPC + t) * 128;
        f32x4 acc[4][4];
        #pragma unroll
        for (int mi = 0; mi < 4; ++mi)
            #pragma unroll
            for (int ni = 0; ni < 4; ++ni)
                acc[mi][ni] = (f32x4){0.f, 0.f, 0.f, 0.f};

        for (int k0 = 0; k0 < Hh; k0 += 32) {
            #pragma unroll
            for (int i = 0; i < 2; ++i) {
                int idx = i * 256 + tid;
                int r = idx >> 2, c = (idx & 3) << 3;
                __builtin_amdgcn_global_load_lds(
                    (const __attribute__((address_space(1))) void*)(A + (size_t)(m0 + r) * Hh + k0 + c),
                    (__attribute__((address_space(3))) void*)(As + (size_t)(i * 256 + (wid << 6)) * 8),
                    16, 0, 0);
            }
            #pragma unroll
            for (int i = 0; i < 2; ++i) {
                int idx = i * 256 + tid;
                int r = idx >> 2, c = (idx & 3) << 3;
                __builtin_amdgcn_global_load_lds(
                    (const __attribute__((address_space(1))) void*)(WT + (size_t)(n0 + r) * Hh + k0 + c),
                    (__attribute__((address_space(3))) void*)(Bs + (size_t)(i * 256 + (wid << 6)) * 8),
                    16, 0, 0);
            }
            __syncthreads();

            bf16x8 af[4], bfr[4];
            #pragma unroll
            for (int mi = 0; mi < 4; ++mi)
                af[mi] = *(const bf16x8*)(As + (size_t)(wr + mi * 16 + lr) * 32 + kg);
            #pragma unroll
            for (int ni = 0; ni < 4; ++ni)
                bfr[ni] = *(const bf16x8*)(Bs + (size_t)(wc + ni * 16 + lr) * 32 + kg);

            #pragma unroll
            for (int mi = 0; mi < 4; ++mi)
                #pragma unroll
                for (int ni = 0; ni < 4; ++ni)
                    acc[mi][ni] = __builtin_amdgcn_mfma_f32_16x16x32_bf16(
                        af[mi], bfr[ni], acc[mi][ni], 0, 0, 0);
            __syncthreads();
        }

        float bvs[4];
        int cols[4];
        #pragma unroll
        for (int ni = 0; ni < 4; ++ni) {
            cols[ni] = n0 + wc + ni * 16 + lr;
            bvs[ni] = cbp[cols[ni]];
        }
        #pragma unroll
        for (int mi = 0; mi < 4; ++mi) {
            #pragma unroll
            for (int q = 0; q < 4; ++q) {
                int rl = wr + mi * 16 + ((lane >> 4) << 2) + q;
                float v0 = acc[mi][0][q] + bvs[0];
                float v1 = acc[mi][1][q] + bvs[1];
                float v2 = acc[mi][2][q] + bvs[2];
                float v3 = acc[mi][3][q] + bvs[3];
                int lb = lab[rl];
                if (lb == cols[0]) sll[rl] = v0;
                if (lb == cols[1]) sll[rl] = v1;
                if (lb == cols[2]) sll[rl] = v2;
                if (lb == cols[3]) sll[rl] = v3;
                float vmax = fmaxf(fmaxf(v0, v1), fmaxf(v2, v3));
                #pragma unroll
                for (int off = 1; off < 16; off <<= 1)
                    vmax = fmaxf(vmax, __shfl_xor(vmax, off));
                float se = __expf(v0 - vmax) + __expf(v1 - vmax)
                         + __expf(v2 - vmax) + __expf(v3 - vmax);
                #pragma unroll
                for (int off = 1; off < 16; off <<= 1)
                    se += __shfl_xor(se, off);
                if (lr == 0) {
                    float om = sm[wcid][rl], os = ssum[wcid][rl];
                    float nm = fmaxf(om, vmax);
                    ssum[wcid][rl] = os * __expf(om - nm) + se * __expf(vmax - nm);
                    sm[wcid][rl] = nm;
                }
            }
        }
    }
    __syncthreads();
    if (tid < 128) {
        float am = sm[0][tid], as = ssum[0][tid];
        float bm = sm[1][tid], bs = ssum[1][tid];
        float nm = fmaxf(am, bm);
        float s = as * __expf(am - nm) + bs * __expf(bm - nm);
        pm [(size_t)chunk * Mm + m0 + tid] = nm;
        psv[(size_t)chunk * Mm + m0 + tid] = s;
        pll[(size_t)chunk * Mm + m0 + tid] = sll[tid];
    }
}

__global__ __launch_bounds__(256) void cls_merge_kernel(
    const float* __restrict__ pm, const float* __restrict__ psv,
    const float* __restrict__ pll, float* __restrict__ ce)
{
    int row = blockIdx.x * 256 + threadIdx.x;
    float m = -3.0e38f, s = 0.f, l = 0.f;
    #pragma unroll 1
    for (int c = 0; c < NCH; ++c) {
        float cm = pm[(size_t)c * Mm + row];
        float cs = psv[(size_t)c * Mm + row];
        float nm = fmaxf(m, cm);
        s = s * __expf(m - nm) + cs * __expf(cm - nm);
        m = nm;
        l += pll[(size_t)c * Mm + row];
    }
    ce[row] = (m + logf(s)) - l;
}

// ---------------------------------------------------------------------------
// 8. Masked per-sample mean, final scalar
// ---------------------------------------------------------------------------
__global__ __launch_bounds__(256) void ce_reduce_kernel(
    const float* __restrict__ ce, const int* __restrict__ info,
    float* __restrict__ ps)
{
    int b = blockIdx.x, tid = threadIdx.x;
    int first = info[b * 4 + 0], has = info[b * 4 + 1];
    float sum = 0.0f;
    for (int s = tid; s < Ss; s += 256) {
        bool mv = has ? (s > first) : true;
        if (mv) sum += ce[b * Ss + s];
    }
    #pragma unroll
    for (int off = 32; off; off >>= 1) sum += __shfl_xor(sum, off);
    __shared__ float red[4];
    int lane = tid & 63, wid = tid >> 6;
    if (lane == 0) red[wid] = sum;
    __syncthreads();
    if (tid == 0) {
        float tot = red[0] + red[1] + red[2] + red[3];
        float cnt = has ? (float)(Ss - 1 - first) : (float)Ss;
        ps[b] = tot / cnt;
    }
}

__global__ void final_kernel(const float* __restrict__ ps, float* __restrict__ out)
{
    if (threadIdx.x == 0 && blockIdx.x == 0) {
        float t = 0.0f;
        #pragma unroll
        for (int b = 0; b < Bb; b++) t += ps[b];
        out[0] = t * (1.0f / Bb);
    }
}

// ---------------------------------------------------------------------------
// Host launcher
// ---------------------------------------------------------------------------
extern "C" void kernel_launch(void* const* d_in, const int* in_sizes, int n_in,
                              void* d_out, int out_size, void* d_ws, size_t ws_size,
                              hipStream_t stream)
{
    const int*   ids    = (const int*)d_in[0];
    const int*   labels = (const int*)d_in[1];
    const float* we     = (const float*)d_in[2];
    const float* pe     = (const float*)d_in[3];
    const float* te     = (const float*)d_in[4];
    const float* eg     = (const float*)d_in[5];
    const float* ebp    = (const float*)d_in[6];
    const float* Wq     = (const float*)d_in[7];
    const float* bq     = (const float*)d_in[8];
    const float* Wk     = (const float*)d_in[9];
    const float* bk     = (const float*)d_in[10];
    const float* Wv     = (const float*)d_in[11];
    const float* bv     = (const float*)d_in[12];
    const float* Wo     = (const float*)d_in[13];
    const float* bo     = (const float*)d_in[14];
    const float* l1g    = (const float*)d_in[15];
    const float* l1b    = (const float*)d_in[16];
    const float* W1     = (const float*)d_in[17];
    const float* b1     = (const float*)d_in[18];
    const float* W2     = (const float*)d_in[19];
    const float* b2     = (const float*)d_in[20];
    const float* l2g    = (const float*)d_in[21];
    const float* l2b    = (const float*)d_in[22];
    const float* cW     = (const float*)d_in[23];
    const float* cbias  = (const float*)d_in[24];

    const size_t MH  = (size_t)Mm * Hh;                 // 3.15M
    const size_t MF  = (size_t)Mm * Ff;                 // 12.6M
    const size_t HHe = (size_t)Hh * Hh;
    const size_t HFe = (size_t)Hh * Ff;

    // Workspace layout (~97 MB; well under the 198 MB proven in round 5)
    float* ws = (float*)d_ws;
    float* x      = ws;                                // MH f32
    float* tmp    = x + MH;                            // MH f32
    float* ce     = tmp + MH;                          // Mm f32
    float* ps     = ce + Mm;                           // 16 f32
    int*   info   = (int*)(ps + 16);                   // 64 ints reserved
    float* bqkv   = (float*)(info + 64);               // 2304 f32
    ushort* xb    = (ushort*)(bqkv + QKVN);            // MH bf16
    ushort* qkvb  = xb + MH;                           // 3*MH bf16 (stride 2304)
    ushort* ctxb  = qkvb + 3 * MH;                     // MH
    ushort* f1b   = ctxb + MH;                         // MF
    ushort* wscr  = f1b + MF;                          // 4*HHe + 2*HFe bf16
    ushort* wqT = wscr;                                // [768][768] (rows 0-767 of QKV)
    ushort* wkT = wqT + HHe;                           // rows 768-1535
    ushort* wvT = wkT + HHe;                           // rows 1536-2303
    ushort* woT = wvT + HHe;
    ushort* w1T = woT + HHe;                           // [F][H]
    ushort* w2T = w1T + HFe;                           // [H][F]
    float* clsf = (float*)(w2T + HFe);
    float* cbp  = clsf;                                // VP
    float* pm   = cbp + VP;                            // NCH*Mm
    float* psv  = pm + (size_t)NCH * Mm;               // NCH*Mm
    float* pll  = psv + (size_t)NCH * Mm;              // NCH*Mm
    // cls weight alias: qkvb..f1b region is dead at classifier time
    ushort* cWT = qkvb;                                // needs VP*Hh = 16.5M u16

    sep_kernel<<<Bb, 512, 0, stream>>>(ids, info);
    embed_ln_kernel<<<Mm, 256, 0, stream>>>(ids, we, pe, te, eg, ebp, x, xb);

    dim3 gQKV(QKVN / 128, Mm / 128);      // (18, 32)
    dim3 gH(Hh / 128, Mm / 128);          // (6, 32)
    dim3 gF(Ff / 128, Mm / 128);          // (24, 32)
    dim3 gA(Ss / 64, Bb * NHh);           // (8, 96)
    dim3 tHH(Hh / 32, Hh / 32);           // (24, 24)
    dim3 tHF(Ff / 32, Hh / 32);           // (96, 24)
    dim3 tFH(Hh / 32, Ff / 32);           // (24, 96)

    for (int l = 0; l < Ll; l++) {
        const float* bq_l = bq + (size_t)l * Hh;
        const float* bk_l = bk + (size_t)l * Hh;
        const float* bv_l = bv + (size_t)l * Hh;
        const float* bo_l = bo + (size_t)l * Hh;
        const float* b1_l = b1 + (size_t)l * Ff;
        const float* b2_l = b2 + (size_t)l * Hh;
        const float* g1  = l1g + (size_t)l * Hh;
        const float* be1 = l1b + (size_t)l * Hh;
        const float* g2  = l2g + (size_t)l * Hh;
        const float* be2 = l2b + (size_t)l * Hh;

        transpose_kernel<<<tHH, 256, 0, stream>>>(Wq + (size_t)l * HHe, wqT, Hh, Hh);
        transpose_kernel<<<tHH, 256, 0, stream>>>(Wk + (size_t)l * HHe, wkT, Hh, Hh);
        transpose_kernel<<<tHH, 256, 0, stream>>>(Wv + (size_t)l * HHe, wvT, Hh, Hh);
        transpose_kernel<<<tHH, 256, 0, stream>>>(Wo + (size_t)l * HHe, woT, Hh, Hh);
        transpose_kernel<<<tHF, 256, 0, stream>>>(W1 + (size_t)l * HFe, w1T, Hh, Ff);
        transpose_kernel<<<tFH, 256, 0, stream>>>(W2 + (size_t)l * HFe, w2T, Ff, Hh);
        bias_concat_kernel<<<3, 256, 0, stream>>>(bq_l, bk_l, bv_l, bqkv);

        // Fused QKV projection: [M][768] @ [2304][768]^T -> [M][2304]
        mfma_gemm<0, 1><<<gQKV, 256, 0, stream>>>(xb, wqT, bqkv, qkvb, QKVN, Hh);

        flash_attn_kernel<<<gA, 256, 0, stream>>>(qkvb, info, ctxb);

        mfma_gemm<0, 0><<<gH, 256, 0, stream>>>(ctxb, woT, bo_l, tmp, Hh, Hh);
        resid_ln_kernel<<<Mm, 256, 0, stream>>>(x, tmp, g1, be1, x, xb);

        mfma_gemm<1, 1><<<gF, 256, 0, stream>>>(xb, w1T, b1_l, f1b, Ff, Hh);
        mfma_gemm<0, 0><<<gH, 256, 0, stream>>>(f1b, w2T, b2_l, tmp, Hh, Ff);
        resid_ln_kernel<<<Mm, 256, 0, stream>>>(x, tmp, g2, be2, x, xb);
    }

    // Classifier
    pad_transpose_kernel<<<dim3(VP / 32, Hh / 32), 256, 0, stream>>>(cW, cWT, Hh, Vv);
    bias_pad_kernel<<<(VP + 255) / 256, 256, 0, stream>>>(cbias, cbp);
    cls_lse_kernel<<<dim3(NCH, Mm / 128), 256, 0, stream>>>(
        xb, cWT, cbp, labels, pm, psv, pll);
    cls_merge_kernel<<<Mm / 256, 256, 0, stream>>>(pm, psv, pll, ce);
    ce_reduce_kernel<<<Bb, 256, 0, stream>>>(ce, info, ps);
    final_kernel<<<1, 64, 0, stream>>>(ps, (float*)d_out);
}

// Round 7
// 2721.317 us; speedup vs baseline: 5.4810x; 1.1610x over previous
//
#include <hip/hip_runtime.h>
#include <math.h>

typedef unsigned short ushort;
typedef __bf16 bf16x8 __attribute__((ext_vector_type(8)));
typedef float f32x4 __attribute__((ext_vector_type(4)));

// Problem dims
constexpr int Bb  = 8;
constexpr int Ss  = 512;
constexpr int Hh  = 768;
constexpr int Ll  = 12;
constexpr int NHh = 12;
constexpr int Ff  = 3072;
constexpr int Vv  = 21128;
constexpr int DHh = 64;
constexpr int Mm  = Bb * Ss;   // 4096
constexpr int SEP_ID = 102;
constexpr int VP  = 21504;     // vocab padded to 168*128
constexpr int NCH = 24;        // vocab chunks (cls grid x)
constexpr int TPC = 7;         // 128-col tiles per chunk
constexpr int QKVN = 3 * Hh;   // 2304
constexpr float LSE_SHIFT = 20.0f;  // fixed shift; logits sigma~0.55, |v|<<88

static __device__ __forceinline__ ushort f2bf(float f) {
    unsigned u = __float_as_uint(f);
    unsigned r = (u + 0x7fffu + ((u >> 16) & 1u)) >> 16;
    return (ushort)r;
}
static __device__ __forceinline__ float bf2f(unsigned x) {
    return __uint_as_float(x << 16);
}

// ---------------------------------------------------------------------------
// 1. Find first SEP per batch
// ---------------------------------------------------------------------------
__global__ __launch_bounds__(512) void sep_kernel(const int* __restrict__ ids,
                                                  int* __restrict__ info)
{
    int b = blockIdx.x;
    int t = threadIdx.x;
    int v = (ids[b * Ss + t] == SEP_ID) ? t : 0x7FFFFFFF;
    #pragma unroll
    for (int off = 32; off; off >>= 1) {
        int o = __shfl_xor(v, off);
        v = min(v, o);
    }
    __shared__ int wmin[8];
    int lane = t & 63, wid = t >> 6;
    if (lane == 0) wmin[wid] = v;
    __syncthreads();
    if (t == 0) {
        int first = wmin[0];
        #pragma unroll
        for (int w = 1; w < 8; w++) first = min(first, wmin[w]);
        int has = (first != 0x7FFFFFFF) ? 1 : 0;
        info[b * 4 + 0] = first;
        info[b * 4 + 1] = has;
        info[b * 4 + 2] = has ? min(first, Ss - 2) : (Ss + 1);
    }
}

// ---------------------------------------------------------------------------
// 2. Embedding + LayerNorm -> fp32 x and bf16 xb
// ---------------------------------------------------------------------------
__global__ __launch_bounds__(256) void embed_ln_kernel(
    const int* __restrict__ ids, const float* __restrict__ we,
    const float* __restrict__ pe, const float* __restrict__ te,
    const float* __restrict__ g, const float* __restrict__ bp,
    float* __restrict__ x, ushort* __restrict__ xb)
{
    int tok = blockIdx.x;
    int s = tok & (Ss - 1);
    int tid = threadIdx.x;
    int id = ids[tok];
    float e[3];
    #pragma unroll
    for (int r = 0; r < 3; r++) {
        int h = tid + (r << 8);
        e[r] = we[(size_t)id * Hh + h] + pe[(size_t)s * Hh + h] + te[h];
    }
    float sum = e[0] + e[1] + e[2];
    float sq  = fmaf(e[0], e[0], fmaf(e[1], e[1], e[2] * e[2]));
    #pragma unroll
    for (int off = 32; off; off >>= 1) {
        sum += __shfl_xor(sum, off);
        sq  += __shfl_xor(sq, off);
    }
    __shared__ float red[8];
    int lane = tid & 63, wid = tid >> 6;
    if (lane == 0) { red[wid] = sum; red[4 + wid] = sq; }
    __syncthreads();
    sum = red[0] + red[1] + red[2] + red[3];
    sq  = red[4] + red[5] + red[6] + red[7];
    float mean = sum * (1.0f / Hh);
    float var  = sq * (1.0f / Hh) - mean * mean;
    float rstd = rsqrtf(var + 1e-12f);
    #pragma unroll
    for (int r = 0; r < 3; r++) {
        int h = tid + (r << 8);
        float v = (e[r] - mean) * rstd * g[h] + bp[h];
        x[(size_t)tok * Hh + h] = v;
        xb[(size_t)tok * Hh + h] = f2bf(v);
    }
}

// ---------------------------------------------------------------------------
// 3a. Residual + LayerNorm (single y)
// ---------------------------------------------------------------------------
__global__ __launch_bounds__(256) void resid_ln_kernel(
    const float* __restrict__ resid, const float* __restrict__ y,
    const float* __restrict__ g, const float* __restrict__ bp,
    float* __restrict__ out, ushort* __restrict__ outb)
{
    int tok = blockIdx.x;
    int tid = threadIdx.x;
    float e[3];
    #pragma unroll
    for (int r = 0; r < 3; r++) {
        int h = tid + (r << 8);
        size_t idx = (size_t)tok * Hh + h;
        e[r] = resid[idx] + y[idx];
    }
    float sum = e[0] + e[1] + e[2];
    float sq  = fmaf(e[0], e[0], fmaf(e[1], e[1], e[2] * e[2]));
    #pragma unroll
    for (int off = 32; off; off >>= 1) {
        sum += __shfl_xor(sum, off);
        sq  += __shfl_xor(sq, off);
    }
    __shared__ float red[8];
    int lane = tid & 63, wid = tid >> 6;
    if (lane == 0) { red[wid] = sum; red[4 + wid] = sq; }
    __syncthreads();
    sum = red[0] + red[1] + red[2] + red[3];
    sq  = red[4] + red[5] + red[6] + red[7];
    float mean = sum * (1.0f / Hh);
    float var  = sq * (1.0f / Hh) - mean * mean;
    float rstd = rsqrtf(var + 1e-12f);
    #pragma unroll
    for (int r = 0; r < 3; r++) {
        int h = tid + (r << 8);
        float v = (e[r] - mean) * rstd * g[h] + bp[h];
        out[(size_t)tok * Hh + h] = v;
        outb[(size_t)tok * Hh + h] = f2bf(v);
    }
}

// 3b. Residual + 4 split-K partials + bias + LayerNorm
__global__ __launch_bounds__(256) void resid_ln4_kernel(
    const float* __restrict__ resid, const float* __restrict__ p,  // [4][Mm][Hh]
    const float* __restrict__ bias, const float* __restrict__ g,
    const float* __restrict__ bp,
    float* __restrict__ out, ushort* __restrict__ outb)
{
    const size_t MHl = (size_t)Mm * Hh;
    int tok = blockIdx.x;
    int tid = threadIdx.x;
    float e[3];
    #pragma unroll
    for (int r = 0; r < 3; r++) {
        int h = tid + (r << 8);
        size_t idx = (size_t)tok * Hh + h;
        float acc = resid[idx] + bias[h];
        acc += p[idx];
        acc += p[MHl + idx];
        acc += p[2 * MHl + idx];
        acc += p[3 * MHl + idx];
        e[r] = acc;
    }
    float sum = e[0] + e[1] + e[2];
    float sq  = fmaf(e[0], e[0], fmaf(e[1], e[1], e[2] * e[2]));
    #pragma unroll
    for (int off = 32; off; off >>= 1) {
        sum += __shfl_xor(sum, off);
        sq  += __shfl_xor(sq, off);
    }
    __shared__ float red[8];
    int lane = tid & 63, wid = tid >> 6;
    if (lane == 0) { red[wid] = sum; red[4 + wid] = sq; }
    __syncthreads();
    sum = red[0] + red[1] + red[2] + red[3];
    sq  = red[4] + red[5] + red[6] + red[7];
    float mean = sum * (1.0f / Hh);
    float var  = sq * (1.0f / Hh) - mean * mean;
    float rstd = rsqrtf(var + 1e-12f);
    #pragma unroll
    for (int r = 0; r < 3; r++) {
        int h = tid + (r << 8);
        float v = (e[r] - mean) * rstd * g[h] + bp[h];
        out[(size_t)tok * Hh + h] = v;
        outb[(size_t)tok * Hh + h] = f2bf(v);
    }
}

// ---------------------------------------------------------------------------
// 4. Weight transposes
// ---------------------------------------------------------------------------
__global__ __launch_bounds__(256) void transpose_kernel(
    const float* __restrict__ W, ushort* __restrict__ Wt, int K, int N)
{
    __shared__ float ts[32][33];
    int n0 = blockIdx.x * 32, k0 = blockIdx.y * 32;
    int tx = threadIdx.x & 31, ty = threadIdx.x >> 5;
    #pragma unroll
    for (int i = 0; i < 32; i += 8)
        ts[ty + i][tx] = W[(size_t)(k0 + ty + i) * N + n0 + tx];
    __syncthreads();
    #pragma unroll
    for (int i = 0; i < 32; i += 8)
        Wt[(size_t)(n0 + ty + i) * K + k0 + tx] = f2bf(ts[tx][ty + i]);
}

// 4a. Four HxH transposes in one launch (z selects source)
__global__ __launch_bounds__(256) void transpose4_kernel(
    const float* __restrict__ s0, const float* __restrict__ s1,
    const float* __restrict__ s2, const float* __restrict__ s3,
    ushort* __restrict__ dst)
{
    const float* srcs[4] = { s0, s1, s2, s3 };
    const float* W = srcs[blockIdx.z];
    ushort* Wt = dst + (size_t)blockIdx.z * Hh * Hh;
    __shared__ float ts[32][33];
    int n0 = blockIdx.x * 32, k0 = blockIdx.y * 32;
    int tx = threadIdx.x & 31, ty = threadIdx.x >> 5;
    #pragma unroll
    for (int i = 0; i < 32; i += 8)
        ts[ty + i][tx] = W[(size_t)(k0 + ty + i) * Hh + n0 + tx];
    __syncthreads();
    #pragma unroll
    for (int i = 0; i < 32; i += 8)
        Wt[(size_t)(n0 + ty + i) * Hh + k0 + tx] = f2bf(ts[tx][ty + i]);
}

__global__ __launch_bounds__(256) void pad_transpose_kernel(
    const float* __restrict__ W, ushort* __restrict__ Wt, int K, int N)
{
    __shared__ float ts[32][33];
    int n0 = blockIdx.x * 32, k0 = blockIdx.y * 32;
    int tx = threadIdx.x & 31, ty = threadIdx.x >> 5;
    #pragma unroll
    for (int i = 0; i < 32; i += 8) {
        int n = n0 + tx;
        ts[ty + i][tx] = (n < N) ? W[(size_t)(k0 + ty + i) * N + n] : 0.f;
    }
    __syncthreads();
    #pragma unroll
    for (int i = 0; i < 32; i += 8)
        Wt[(size_t)(n0 + ty + i) * K + k0 + tx] = f2bf(ts[tx][ty + i]);
}

__global__ __launch_bounds__(256) void bias_pad_kernel(
    const float* __restrict__ cb, float* __restrict__ cbp)
{
    int i = blockIdx.x * 256 + threadIdx.x;
    if (i < VP) cbp[i] = (i < Vv) ? cb[i] : -1.0e9f;
}

__global__ __launch_bounds__(256) void bias_concat_kernel(
    const float* __restrict__ a, const float* __restrict__ b,
    const float* __restrict__ c, float* __restrict__ out)
{
    int i = blockIdx.x * 256 + threadIdx.x;
    if (i < Hh) {
        out[i] = a[i];
        out[Hh + i] = b[i];
        out[2 * Hh + i] = c[i];
    }
}

// ---------------------------------------------------------------------------
// 5. bf16 MFMA GEMM (m97-pattern).
//    C[M,N] = A[M, lda-chunk] @ Bt[N, ldb-chunk]^T (+ bias, + GELU)
//    gridDim.z = split-K chunks; K = per-chunk length; A/Bt row strides lda/ldb.
//    z>0 writes partials C + z*Mm*N (f32 path only).
// ---------------------------------------------------------------------------
template <int ACT, int OUT_BF, int BIAS>
__global__ __launch_bounds__(256) void mfma_gemm(
    const ushort* __restrict__ A,
    const ushort* __restrict__ Bt,
    const float* __restrict__ bias,
    void* __restrict__ C,
    int N, int K, int lda, int ldb)
{
    __shared__ __align__(16) ushort As[128 * 32];
    __shared__ __align__(16) ushort Bs[128 * 32];
    const int tid = threadIdx.x;
    const int lane = tid & 63, wid = tid >> 6;
    const int m0 = blockIdx.y * 128, n0 = blockIdx.x * 128;
    const int kbase = blockIdx.z * K;
    const size_t zoff = (size_t)blockIdx.z * Mm * N;
    A += kbase;
    Bt += kbase;
    const int wr = (wid >> 1) * 64, wc = (wid & 1) * 64;
    const int lr = lane & 15;
    const int kg = (lane >> 4) << 3;

    f32x4 acc[4][4];
    #pragma unroll
    for (int mi = 0; mi < 4; ++mi)
        #pragma unroll
        for (int ni = 0; ni < 4; ++ni)
            acc[mi][ni] = (f32x4){0.f, 0.f, 0.f, 0.f};

    for (int k0 = 0; k0 < K; k0 += 32) {
        #pragma unroll
        for (int i = 0; i < 2; ++i) {
            int idx = i * 256 + tid;
            int r = idx >> 2, c = (idx & 3) << 3;
            __builtin_amdgcn_global_load_lds(
                (const __attribute__((address_space(1))) void*)(A + (size_t)(m0 + r) * lda + k0 + c),
                (__attribute__((address_space(3))) void*)(As + (size_t)(i * 256 + (wid << 6)) * 8),
                16, 0, 0);
        }
        #pragma unroll
        for (int i = 0; i < 2; ++i) {
            int idx = i * 256 + tid;
            int r = idx >> 2, c = (idx & 3) << 3;
            __builtin_amdgcn_global_load_lds(
                (const __attribute__((address_space(1))) void*)(Bt + (size_t)(n0 + r) * ldb + k0 + c),
                (__attribute__((address_space(3))) void*)(Bs + (size_t)(i * 256 + (wid << 6)) * 8),
                16, 0, 0);
        }
        __syncthreads();

        bf16x8 af[4], bfr[4];
        #pragma unroll
        for (int mi = 0; mi < 4; ++mi)
            af[mi] = *(const bf16x8*)(As + (size_t)(wr + mi * 16 + lr) * 32 + kg);
        #pragma unroll
        for (int ni = 0; ni < 4; ++ni)
            bfr[ni] = *(const bf16x8*)(Bs + (size_t)(wc + ni * 16 + lr) * 32 + kg);

        #pragma unroll
        for (int mi = 0; mi < 4; ++mi)
            #pragma unroll
            for (int ni = 0; ni < 4; ++ni)
                acc[mi][ni] = __builtin_amdgcn_mfma_f32_16x16x32_bf16(
                    af[mi], bfr[ni], acc[mi][ni], 0, 0, 0);
        __syncthreads();
    }

    #pragma unroll
    for (int ni = 0; ni < 4; ++ni) {
        int col = n0 + wc + ni * 16 + lr;
        float bsv = 0.f;
        if (BIAS) bsv = bias[col];
        #pragma unroll
        for (int mi = 0; mi < 4; ++mi) {
            f32x4 v = acc[mi][ni];
            #pragma unroll
            for (int q = 0; q < 4; ++q) {
                int row = m0 + wr + mi * 16 + ((lane >> 4) << 2) + q;
                float val = v[q] + bsv;
                if (ACT == 1) val = 0.5f * val * (1.0f + erff(val * 0.70710678118654752f));
                if (OUT_BF)
                    ((ushort*)C)[(size_t)row * N + col] = f2bf(val);
                else
                    ((float*)C)[zoff + (size_t)row * N + col] = val;
            }
        }
    }
}

// ---------------------------------------------------------------------------
// 6. Fused MFMA flash attention (unchanged from round 6)
// ---------------------------------------------------------------------------
constexpr int SP = 65;
constexpr int PS = 72;
constexpr int VS = 72;

__global__ __launch_bounds__(256) void flash_attn_kernel(
    const ushort* __restrict__ qkv, const int* __restrict__ info,
    ushort* __restrict__ ctx)
{
    __shared__ __align__(16) ushort K_lds[64 * 64];
    __shared__ __align__(16) ushort Vt_lds[64 * VS];
    __shared__ __align__(16) ushort P_lds[64 * PS];
    __shared__ float S_lds[64 * SP];
    __shared__ float m_s[64], l_s[64], rf_s[64];

    const int tid = threadIdx.x;
    const int lane = tid & 63, wid = tid >> 6;
    const int bh = blockIdx.y, b = bh / NHh, h = bh % NHh;
    const int i0 = blockIdx.x * 64;
    const int lr = lane & 15, hi = lane >> 4;
    const int kg = hi << 3;
    const int wr = (wid >> 1) * 32;
    const int wc = (wid & 1) * 32;
    const int has = info[b * 4 + 1], sep = info[b * 4 + 2];
    const size_t tok0 = (size_t)b * Ss;

    bf16x8 qf[2][2];
    #pragma unroll
    for (int mi = 0; mi < 2; ++mi)
        #pragma unroll
        for (int kk = 0; kk < 2; ++kk)
            qf[mi][kk] = *(const bf16x8*)&qkv[(tok0 + i0 + wr + mi * 16 + lr) * QKVN
                                             + h * DHh + kk * 32 + kg];

    f32x4 o[2][2];
    #pragma unroll
    for (int mi = 0; mi < 2; ++mi)
        #pragma unroll
        for (int ni = 0; ni < 2; ++ni)
            o[mi][ni] = (f32x4){0.f, 0.f, 0.f, 0.f};

    if (tid < 64) { m_s[tid] = -3.0e38f; l_s[tid] = 0.f; }
    __syncthreads();

    for (int j0 = 0; j0 < Ss; j0 += 64) {
        #pragma unroll
        for (int i = 0; i < 2; ++i) {
            int idx = i * 256 + tid;
            int r = idx >> 3, c = (idx & 7) << 3;
            __builtin_amdgcn_global_load_lds(
                (const __attribute__((address_space(1))) void*)
                    (qkv + (tok0 + j0 + r) * QKVN + Hh + h * DHh + c),
                (__attribute__((address_space(3))) void*)(K_lds + (size_t)idx * 8),
                16, 0, 0);
        }
        {
            int kv0 = (tid & 15) * 4;
            int d0 = (tid >> 4) * 4;
            uint2 rv[4];
            #pragma unroll
            for (int r = 0; r < 4; ++r)
                rv[r] = *(const uint2*)&qkv[(tok0 + j0 + kv0 + r) * QKVN
                                            + 2 * Hh + h * DHh + d0];
            #pragma unroll
            for (int c = 0; c < 4; ++c) {
                unsigned e0 = (c < 2) ? (rv[0].x >> (16 * c)) : (rv[0].y >> (16 * (c - 2)));
                unsigned e1 = (c < 2) ? (rv[1].x >> (16 * c)) : (rv[1].y >> (16 * (c - 2)));
                unsigned e2 = (c < 2) ? (rv[2].x >> (16 * c)) : (rv[2].y >> (16 * (c - 2)));
                unsigned e3 = (c < 2) ? (rv[3].x >> (16 * c)) : (rv[3].y >> (16 * (c - 2)));
                uint2 packed;
                packed.x = (e0 & 0xffffu) | (e1 << 16);
                packed.y = (e2 & 0xffffu) | (e3 << 16);
                *(uint2*)&Vt_lds[(size_t)(d0 + c) * VS + kv0] = packed;
            }
        }
        __syncthreads();

        f32x4 s[2][2];
        #pragma unroll
        for (int mi = 0; mi < 2; ++mi)
            #pragma unroll
            for (int ni = 0; ni < 2; ++ni)
                s[mi][ni] = (f32x4){0.f, 0.f, 0.f, 0.f};
        #pragma unroll
        for (int ni = 0; ni < 2; ++ni)
            #pragma unroll
            for (int kk = 0; kk < 2; ++kk) {
                bf16x8 kf = *(const bf16x8*)&K_lds[(size_t)(wc + ni * 16 + lr) * 64
                                                   + kk * 32 + kg];
                #pragma unroll
                for (int mi = 0; mi < 2; ++mi)
                    s[mi][ni] = __builtin_amdgcn_mfma_f32_16x16x32_bf16(
                        qf[mi][kk], kf, s[mi][ni], 0, 0, 0);
            }
        #pragma unroll
        for (int mi = 0; mi < 2; ++mi)
            #pragma unroll
            for (int ni = 0; ni < 2; ++ni)
                #pragma unroll
                for (int q = 0; q < 4; ++q) {
                    int rl = wr + mi * 16 + hi * 4 + q;
                    int cl = wc + ni * 16 + lr;
                    int gi = i0 + rl, gj = j0 + cl;
                    bool vis = (!has) || (gj <= sep) || ((gi > sep) && (gj <= gi));
                    S_lds[rl * SP + cl] = s[mi][ni][q] * 0.125f
                                          + (vis ? 0.0f : -1000000000.0f);
                }
        __syncthreads();

        {
            int r = tid >> 2, c0 = (tid & 3) * 16;
            float mold = m_s[r];
            float sv[16];
            float tmax = -3.0e38f;
            #pragma unroll
            for (int c = 0; c < 16; ++c) {
                sv[c] = S_lds[r * SP + c0 + c];
                tmax = fmaxf(tmax, sv[c]);
            }
            tmax = fmaxf(tmax, __shfl_xor(tmax, 1));
            tmax = fmaxf(tmax, __shfl_xor(tmax, 2));
            float mnew = fmaxf(mold, tmax);
            float sum = 0.f;
            #pragma unroll
            for (int c = 0; c < 16; ++c) {
                float p = __expf(sv[c] - mnew);
                P_lds[r * PS + c0 + c] = f2bf(p);
                sum += p;
            }
            sum += __shfl_xor(sum, 1);
            sum += __shfl_xor(sum, 2);
            if ((tid & 3) == 0) {
                float rf = __expf(mold - mnew);
                rf_s[r] = rf;
                l_s[r] = l_s[r] * rf + sum;
                m_s[r] = mnew;
            }
        }
        __syncthreads();

        #pragma unroll
        for (int mi = 0; mi < 2; ++mi)
            #pragma unroll
            for (int q = 0; q < 4; ++q) {
                float rf = rf_s[wr + mi * 16 + hi * 4 + q];
                #pragma unroll
                for (int ni = 0; ni < 2; ++ni)
                    o[mi][ni][q] *= rf;
            }
        #pragma unroll
        for (int kk = 0; kk < 2; ++kk) {
            bf16x8 pf[2];
            #pragma unroll
            for (int mi = 0; mi < 2; ++mi)
                pf[mi] = *(const bf16x8*)&P_lds[(size_t)(wr + mi * 16 + lr) * PS
                                                + kk * 32 + kg];
            #pragma unroll
            for (int ni = 0; ni < 2; ++ni) {
                bf16x8 vf = *(const bf16x8*)&Vt_lds[(size_t)(wc + ni * 16 + lr) * VS
                                                    + kk * 32 + kg];
                #pragma unroll
                for (int mi = 0; mi < 2; ++mi)
                    o[mi][ni] = __builtin_amdgcn_mfma_f32_16x16x32_bf16(
                        pf[mi], vf, o[mi][ni], 0, 0, 0);
            }
        }
        __syncthreads();
    }

    #pragma unroll
    for (int mi = 0; mi < 2; ++mi)
        #pragma unroll
        for (int q = 0; q < 4; ++q) {
            int rl = wr + mi * 16 + hi * 4 + q;
            float inv = 1.0f / l_s[rl];
            #pragma unroll
            for (int ni = 0; ni < 2; ++ni)
                ctx[(tok0 + i0 + rl) * Hh + h * DHh + wc + ni * 16 + lr]
                    = f2bf(o[mi][ni][q] * inv);
        }
}

// ---------------------------------------------------------------------------
// 7. Fused MFMA classifier, fixed-shift LSE (no max tracking).
//    Per-lane register accumulation of sum(exp(v - SHIFT)); one reduce/block.
// ---------------------------------------------------------------------------
__global__ __launch_bounds__(256) void cls_lse_kernel(
    const ushort* __restrict__ A,    // xb [Mm][Hh] bf16
    const ushort* __restrict__ WT,   // [VP][Hh] bf16
    const float* __restrict__ cbp,   // [VP] padded bias (-1e9 pads)
    const int* __restrict__ labels,
    float* __restrict__ psv, float* __restrict__ pll)
{
    __shared__ __align__(16) ushort As[128 * 32];
    __shared__ __align__(16) ushort Bs[128 * 32];
    __shared__ float ssum[2][128];
    __shared__ float sll[128];
    __shared__ int lab[128];
    const int tid = threadIdx.x;
    const int lane = tid & 63, wid = tid >> 6;
    const int m0 = blockIdx.y * 128;
    const int chunk = blockIdx.x;
    if (tid < 128) {
        sll[tid] = 0.f;
        lab[tid] = labels[m0 + tid];
    }
    const int wr = (wid >> 1) * 64, wcid = wid & 1, wc = wcid * 64;
    const int lr = lane & 15;
    const int hi = lane >> 4;
    const int kg = hi << 3;

    float sacc[16];
    #pragma unroll
    for (int i = 0; i < 16; ++i) sacc[i] = 0.f;

    for (int t = 0; t < TPC; ++t) {
        const int n0 = (chunk * TPC + t) * 128;
        f32x4 acc[4][4];
        #pragma unroll
        for (int mi = 0; mi < 4; ++mi)
            #pragma unroll
            for (int ni = 0; ni < 4; ++ni)
                acc[mi][ni] = (f32x4){0.f, 0.f, 0.f, 0.f};

        for (int k0 = 0; k0 < Hh; k0 += 32) {
            #pragma unroll
            for (int i = 0; i < 2; ++i) {
                int idx = i * 256 + tid;
                int r = idx >> 2, c = (idx & 3) << 3;
                __builtin_amdgcn_global_load_lds(
                    (const __attribute__((address_space(1))) void*)(A + (size_t)(m0 + r) * Hh + k0 + c),
                    (__attribute__((address_space(3))) void*)(As + (size_t)(i * 256 + (wid << 6)) * 8),
                    16, 0, 0);
            }
            #pragma unroll
            for (int i = 0; i < 2; ++i) {
                int idx = i * 256 + tid;
                int r = idx >> 2, c = (idx & 3) << 3;
                __builtin_amdgcn_global_load_lds(
                    (const __attribute__((address_space(1))) void*)(WT + (size_t)(n0 + r) * Hh + k0 + c),
                    (__attribute__((address_space(3))) void*)(Bs + (size_t)(i * 256 + (wid << 6)) * 8),
                    16, 0, 0);
            }
            __syncthreads();

            bf16x8 af[4], bfr[4];
            #pragma unroll
            for (int mi = 0; mi < 4; ++mi)
                af[mi] = *(const bf16x8*)(As + (size_t)(wr + mi * 16 + lr) * 32 + kg);
            #pragma unroll
            for (int ni = 0; ni < 4; ++ni)
                bfr[ni] = *(const bf16x8*)(Bs + (size_t)(wc + ni * 16 + lr) * 32 + kg);

            #pragma unroll
            for (int mi = 0; mi < 4; ++mi)
                #pragma unroll
                for (int ni = 0; ni < 4; ++ni)
                    acc[mi][ni] = __builtin_amdgcn_mfma_f32_16x16x32_bf16(
                        af[mi], bfr[ni], acc[mi][ni], 0, 0, 0);
            __syncthreads();
        }

        // Register-local epilogue: sum exp(v - SHIFT), label-logit catch.
        float bvs[4];
        int cols[4];
        #pragma unroll
        for (int ni = 0; ni < 4; ++ni) {
            cols[ni] = n0 + wc + ni * 16 + lr;
            bvs[ni] = cbp[cols[ni]];
        }
        #pragma unroll
        for (int mi = 0; mi < 4; ++mi) {
            #pragma unroll
            for (int q = 0; q < 4; ++q) {
                int rl = wr + mi * 16 + hi * 4 + q;
                float v0 = acc[mi][0][q] + bvs[0];
                float v1 = acc[mi][1][q] + bvs[1];
                float v2 = acc[mi][2][q] + bvs[2];
                float v3 = acc[mi][3][q] + bvs[3];
                int lb = lab[rl];
                if (lb == cols[0]) sll[rl] = v0;
                if (lb == cols[1]) sll[rl] = v1;
                if (lb == cols[2]) sll[rl] = v2;
                if (lb == cols[3]) sll[rl] = v3;
                sacc[mi * 4 + q] += __expf(v0 - LSE_SHIFT) + __expf(v1 - LSE_SHIFT)
                                  + __expf(v2 - LSE_SHIFT) + __expf(v3 - LSE_SHIFT);
            }
        }
    }

    // One cross-lane reduce per block (16 lanes share each row-slot)
    #pragma unroll
    for (int mi = 0; mi < 4; ++mi) {
        #pragma unroll
        for (int q = 0; q < 4; ++q) {
            float s = sacc[mi * 4 + q];
            s += __shfl_xor(s, 1);
            s += __shfl_xor(s, 2);
            s += __shfl_xor(s, 4);
            s += __shfl_xor(s, 8);
            if (lr == 0) ssum[wcid][wr + mi * 16 + hi * 4 + q] = s;
        }
    }
    __syncthreads();
    if (tid < 128) {
        psv[(size_t)chunk * Mm + m0 + tid] = ssum[0][tid] + ssum[1][tid];
        pll[(size_t)chunk * Mm + m0 + tid] = sll[tid];
    }
}

__global__ __launch_bounds__(256) void cls_merge_kernel(
    const float* __restrict__ psv, const float* __restrict__ pll,
    float* __restrict__ ce)
{
    int row = blockIdx.x * 256 + threadIdx.x;
    float s = 0.f, l = 0.f;
    #pragma unroll 1
    for (int c = 0; c < NCH; ++c) {
        s += psv[(size_t)c * Mm + row];
        l += pll[(size_t)c * Mm + row];
    }
    ce[row] = (LSE_SHIFT + logf(s)) - l;
}

// ---------------------------------------------------------------------------
// 8. Masked per-sample mean, final scalar
// ---------------------------------------------------------------------------
__global__ __launch_bounds__(256) void ce_reduce_kernel(
    const float* __restrict__ ce, const int* __restrict__ info,
    float* __restrict__ ps)
{
    int b = blockIdx.x, tid = threadIdx.x;
    int first = info[b * 4 + 0], has = info[b * 4 + 1];
    float sum = 0.0f;
    for (int s = tid; s < Ss; s += 256) {
        bool mv = has ? (s > first) : true;
        if (mv) sum += ce[b * Ss + s];
    }
    #pragma unroll
    for (int off = 32; off; off >>= 1) sum += __shfl_xor(sum, off);
    __shared__ float red[4];
    int lane = tid & 63, wid = tid >> 6;
    if (lane == 0) red[wid] = sum;
    __syncthreads();
    if (tid == 0) {
        float tot = red[0] + red[1] + red[2] + red[3];
        float cnt = has ? (float)(Ss - 1 - first) : (float)Ss;
        ps[b] = tot / cnt;
    }
}

__global__ void final_kernel(const float* __restrict__ ps, float* __restrict__ out)
{
    if (threadIdx.x == 0 && blockIdx.x == 0) {
        float t = 0.0f;
        #pragma unroll
        for (int b = 0; b < Bb; b++) t += ps[b];
        out[0] = t * (1.0f / Bb);
    }
}

// ---------------------------------------------------------------------------
// Host launcher
// ---------------------------------------------------------------------------
extern "C" void kernel_launch(void* const* d_in, const int* in_sizes, int n_in,
                              void* d_out, int out_size, void* d_ws, size_t ws_size,
                              hipStream_t stream)
{
    const int*   ids    = (const int*)d_in[0];
    const int*   labels = (const int*)d_in[1];
    const float* we     = (const float*)d_in[2];
    const float* pe     = (const float*)d_in[3];
    const float* te     = (const float*)d_in[4];
    const float* eg     = (const float*)d_in[5];
    const float* ebp    = (const float*)d_in[6];
    const float* Wq     = (const float*)d_in[7];
    const float* bq     = (const float*)d_in[8];
    const float* Wk     = (const float*)d_in[9];
    const float* bk     = (const float*)d_in[10];
    const float* Wv     = (const float*)d_in[11];
    const float* bv     = (const float*)d_in[12];
    const float* Wo     = (const float*)d_in[13];
    const float* bo     = (const float*)d_in[14];
    const float* l1g    = (const float*)d_in[15];
    const float* l1b    = (const float*)d_in[16];
    const float* W1     = (const float*)d_in[17];
    const float* b1     = (const float*)d_in[18];
    const float* W2     = (const float*)d_in[19];
    const float* b2     = (const float*)d_in[20];
    const float* l2g    = (const float*)d_in[21];
    const float* l2b    = (const float*)d_in[22];
    const float* cW     = (const float*)d_in[23];
    const float* cbias  = (const float*)d_in[24];

    const size_t MH  = (size_t)Mm * Hh;
    const size_t MF  = (size_t)Mm * Ff;
    const size_t HHe = (size_t)Hh * Hh;
    const size_t HFe = (size_t)Hh * Ff;

    // Workspace layout (~135 MB; proven >= 226.5 MB available)
    float* ws = (float*)d_ws;
    float* x      = ws;                                // MH f32
    float* tmp    = x + MH;                            // 4*MH f32 (split-K partials)
    float* ce     = tmp + 4 * MH;                      // Mm f32
    float* ps     = ce + Mm;                           // 16 f32
    int*   info   = (int*)(ps + 16);                   // 64 ints reserved
    float* bqkv   = (float*)(info + 64);               // 2304 f32
    ushort* xb    = (ushort*)(bqkv + QKVN);            // MH bf16
    ushort* qkvb  = xb + MH;                           // 3*MH bf16
    ushort* ctxb  = qkvb + 3 * MH;                     // MH
    ushort* f1b   = ctxb + MH;                         // MF
    ushort* wscr  = f1b + MF;                          // 4*HHe + 2*HFe bf16
    ushort* wqT = wscr;
    ushort* wkT = wqT + HHe;
    ushort* wvT = wkT + HHe;
    ushort* woT = wvT + HHe;
    ushort* w1T = woT + HHe;                           // [F][H]
    ushort* w2T = w1T + HFe;                           // [H][F]
    float* clsf = (float*)(w2T + HFe);
    float* cbp  = clsf;                                // VP
    float* psv  = cbp + VP;                            // NCH*Mm
    float* pll  = psv + (size_t)NCH * Mm;              // NCH*Mm
    ushort* cWT = qkvb;   // alias: qkvb..f1b (25.2M u16) dead at classifier time

    sep_kernel<<<Bb, 512, 0, stream>>>(ids, info);
    embed_ln_kernel<<<Mm, 256, 0, stream>>>(ids, we, pe, te, eg, ebp, x, xb);

    dim3 gQKV(QKVN / 128, Mm / 128);          // (18, 32)
    dim3 gH(Hh / 128, Mm / 128);              // (6, 32)
    dim3 gF(Ff / 128, Mm / 128);              // (24, 32)
    dim3 gW2(Hh / 128, Mm / 128, 4);          // (6, 32, 4) split-K
    dim3 gA(Ss / 64, Bb * NHh);               // (8, 96)
    dim3 t4(Hh / 32, Hh / 32, 4);             // (24, 24, 4)
    dim3 tHF(Ff / 32, Hh / 32);               // (96, 24)
    dim3 tFH(Hh / 32, Ff / 32);               // (24, 96)

    for (int l = 0; l < Ll; l++) {
        const float* bq_l = bq + (size_t)l * Hh;
        const float* bk_l = bk + (size_t)l * Hh;
        const float* bv_l = bv + (size_t)l * Hh;
        const float* bo_l = bo + (size_t)l * Hh;
        const float* b1_l = b1 + (size_t)l * Ff;
        const float* b2_l = b2 + (size_t)l * Hh;
        const float* g1  = l1g + (size_t)l * Hh;
        const float* be1 = l1b + (size_t)l * Hh;
        const float* g2  = l2g + (size_t)l * Hh;
        const float* be2 = l2b + (size_t)l * Hh;

        transpose4_kernel<<<t4, 256, 0, stream>>>(
            Wq + (size_t)l * HHe, Wk + (size_t)l * HHe,
            Wv + (size_t)l * HHe, Wo + (size_t)l * HHe, wscr);
        transpose_kernel<<<tHF, 256, 0, stream>>>(W1 + (size_t)l * HFe, w1T, Hh, Ff);
        transpose_kernel<<<tFH, 256, 0, stream>>>(W2 + (size_t)l * HFe, w2T, Ff, Hh);
        bias_concat_kernel<<<3, 256, 0, stream>>>(bq_l, bk_l, bv_l, bqkv);

        // Fused QKV projection
        mfma_gemm<0, 1, 1><<<gQKV, 256, 0, stream>>>(xb, wqT, bqkv, qkvb,
                                                     QKVN, Hh, Hh, Hh);

        flash_attn_kernel<<<gA, 256, 0, stream>>>(qkvb, info, ctxb);

        mfma_gemm<0, 0, 1><<<gH, 256, 0, stream>>>(ctxb, woT, bo_l, tmp,
                                                   Hh, Hh, Hh, Hh);
        resid_ln_kernel<<<Mm, 256, 0, stream>>>(x, tmp, g1, be1, x, xb);

        mfma_gemm<1, 1, 1><<<gF, 256, 0, stream>>>(xb, w1T, b1_l, f1b,
                                                   Ff, Hh, Hh, Hh);
        // FFN2 split-K x4: one dispatch, partials in tmp[0..3]
        mfma_gemm<0, 0, 0><<<gW2, 256, 0, stream>>>(f1b, w2T, nullptr, tmp,
                                                    Hh, Hh /*chunk*/, Ff, Ff);
        resid_ln4_kernel<<<Mm, 256, 0, stream>>>(x, tmp, b2_l, g2, be2, x, xb);
    }

    // Classifier
    pad_transpose_kernel<<<dim3(VP / 32, Hh / 32), 256, 0, stream>>>(cW, cWT, Hh, Vv);
    bias_pad_kernel<<<(VP + 255) / 256, 256, 0, stream>>>(cbias, cbp);
    cls_lse_kernel<<<dim3(NCH, Mm / 128), 256, 0, stream>>>(
        xb, cWT, cbp, labels, psv, pll);
    cls_merge_kernel<<<Mm / 256, 256, 0, stream>>>(psv, pll, ce);
    ce_reduce_kernel<<<Bb, 256, 0, stream>>>(ce, info, ps);
    final_kernel<<<1, 64, 0, stream>>>(ps, (float*)d_out);
}

// Round 8
// 2620.207 us; speedup vs baseline: 5.6925x; 1.0386x over previous
//
#include <hip/hip_runtime.h>
#include <math.h>

typedef unsigned short ushort;
typedef __bf16 bf16x8 __attribute__((ext_vector_type(8)));
typedef float f32x4 __attribute__((ext_vector_type(4)));

// Problem dims
constexpr int Bb  = 8;
constexpr int Ss  = 512;
constexpr int Hh  = 768;
constexpr int Ll  = 12;
constexpr int NHh = 12;
constexpr int Ff  = 3072;
constexpr int Vv  = 21128;
constexpr int DHh = 64;
constexpr int Mm  = Bb * Ss;   // 4096
constexpr int SEP_ID = 102;
constexpr int VP  = 21504;     // vocab padded to 168*128
constexpr int NCH = 24;        // vocab chunks (cls grid x)
constexpr int TPC = 7;         // 128-col tiles per chunk
constexpr int QKVN = 3 * Hh;   // 2304
constexpr float LSE_SHIFT = 20.0f;

static __device__ __forceinline__ ushort f2bf(float f) {
    unsigned u = __float_as_uint(f);
    unsigned r = (u + 0x7fffu + ((u >> 16) & 1u)) >> 16;
    return (ushort)r;
}
static __device__ __forceinline__ float bf2f(unsigned x) {
    return __uint_as_float(x << 16);
}

// ---------------------------------------------------------------------------
// 1. Find first SEP per batch
// ---------------------------------------------------------------------------
__global__ __launch_bounds__(512) void sep_kernel(const int* __restrict__ ids,
                                                  int* __restrict__ info)
{
    int b = blockIdx.x;
    int t = threadIdx.x;
    int v = (ids[b * Ss + t] == SEP_ID) ? t : 0x7FFFFFFF;
    #pragma unroll
    for (int off = 32; off; off >>= 1) {
        int o = __shfl_xor(v, off);
        v = min(v, o);
    }
    __shared__ int wmin[8];
    int lane = t & 63, wid = t >> 6;
    if (lane == 0) wmin[wid] = v;
    __syncthreads();
    if (t == 0) {
        int first = wmin[0];
        #pragma unroll
        for (int w = 1; w < 8; w++) first = min(first, wmin[w]);
        int has = (first != 0x7FFFFFFF) ? 1 : 0;
        info[b * 4 + 0] = first;
        info[b * 4 + 1] = has;
        info[b * 4 + 2] = has ? min(first, Ss - 2) : (Ss + 1);
    }
}

// ---------------------------------------------------------------------------
// 2. Embedding + LayerNorm -> fp32 x and bf16 xb
// ---------------------------------------------------------------------------
__global__ __launch_bounds__(256) void embed_ln_kernel(
    const int* __restrict__ ids, const float* __restrict__ we,
    const float* __restrict__ pe, const float* __restrict__ te,
    const float* __restrict__ g, const float* __restrict__ bp,
    float* __restrict__ x, ushort* __restrict__ xb)
{
    int tok = blockIdx.x;
    int s = tok & (Ss - 1);
    int tid = threadIdx.x;
    int id = ids[tok];
    float e[3];
    #pragma unroll
    for (int r = 0; r < 3; r++) {
        int h = tid + (r << 8);
        e[r] = we[(size_t)id * Hh + h] + pe[(size_t)s * Hh + h] + te[h];
    }
    float sum = e[0] + e[1] + e[2];
    float sq  = fmaf(e[0], e[0], fmaf(e[1], e[1], e[2] * e[2]));
    #pragma unroll
    for (int off = 32; off; off >>= 1) {
        sum += __shfl_xor(sum, off);
        sq  += __shfl_xor(sq, off);
    }
    __shared__ float red[8];
    int lane = tid & 63, wid = tid >> 6;
    if (lane == 0) { red[wid] = sum; red[4 + wid] = sq; }
    __syncthreads();
    sum = red[0] + red[1] + red[2] + red[3];
    sq  = red[4] + red[5] + red[6] + red[7];
    float mean = sum * (1.0f / Hh);
    float var  = sq * (1.0f / Hh) - mean * mean;
    float rstd = rsqrtf(var + 1e-12f);
    #pragma unroll
    for (int r = 0; r < 3; r++) {
        int h = tid + (r << 8);
        float v = (e[r] - mean) * rstd * g[h] + bp[h];
        x[(size_t)tok * Hh + h] = v;
        xb[(size_t)tok * Hh + h] = f2bf(v);
    }
}

// ---------------------------------------------------------------------------
// 3a. Residual + LayerNorm (single y)
// ---------------------------------------------------------------------------
__global__ __launch_bounds__(256) void resid_ln_kernel(
    const float* __restrict__ resid, const float* __restrict__ y,
    const float* __restrict__ g, const float* __restrict__ bp,
    float* __restrict__ out, ushort* __restrict__ outb)
{
    int tok = blockIdx.x;
    int tid = threadIdx.x;
    float e[3];
    #pragma unroll
    for (int r = 0; r < 3; r++) {
        int h = tid + (r << 8);
        size_t idx = (size_t)tok * Hh + h;
        e[r] = resid[idx] + y[idx];
    }
    float sum = e[0] + e[1] + e[2];
    float sq  = fmaf(e[0], e[0], fmaf(e[1], e[1], e[2] * e[2]));
    #pragma unroll
    for (int off = 32; off; off >>= 1) {
        sum += __shfl_xor(sum, off);
        sq  += __shfl_xor(sq, off);
    }
    __shared__ float red[8];
    int lane = tid & 63, wid = tid >> 6;
    if (lane == 0) { red[wid] = sum; red[4 + wid] = sq; }
    __syncthreads();
    sum = red[0] + red[1] + red[2] + red[3];
    sq  = red[4] + red[5] + red[6] + red[7];
    float mean = sum * (1.0f / Hh);
    float var  = sq * (1.0f / Hh) - mean * mean;
    float rstd = rsqrtf(var + 1e-12f);
    #pragma unroll
    for (int r = 0; r < 3; r++) {
        int h = tid + (r << 8);
        float v = (e[r] - mean) * rstd * g[h] + bp[h];
        out[(size_t)tok * Hh + h] = v;
        outb[(size_t)tok * Hh + h] = f2bf(v);
    }
}

// 3b. Residual + 4 split-K partials + bias + LayerNorm
__global__ __launch_bounds__(256) void resid_ln4_kernel(
    const float* __restrict__ resid, const float* __restrict__ p,  // [4][Mm][Hh]
    const float* __restrict__ bias, const float* __restrict__ g,
    const float* __restrict__ bp,
    float* __restrict__ out, ushort* __restrict__ outb)
{
    const size_t MHl = (size_t)Mm * Hh;
    int tok = blockIdx.x;
    int tid = threadIdx.x;
    float e[3];
    #pragma unroll
    for (int r = 0; r < 3; r++) {
        int h = tid + (r << 8);
        size_t idx = (size_t)tok * Hh + h;
        float acc = resid[idx] + bias[h];
        acc += p[idx];
        acc += p[MHl + idx];
        acc += p[2 * MHl + idx];
        acc += p[3 * MHl + idx];
        e[r] = acc;
    }
    float sum = e[0] + e[1] + e[2];
    float sq  = fmaf(e[0], e[0], fmaf(e[1], e[1], e[2] * e[2]));
    #pragma unroll
    for (int off = 32; off; off >>= 1) {
        sum += __shfl_xor(sum, off);
        sq  += __shfl_xor(sq, off);
    }
    __shared__ float red[8];
    int lane = tid & 63, wid = tid >> 6;
    if (lane == 0) { red[wid] = sum; red[4 + wid] = sq; }
    __syncthreads();
    sum = red[0] + red[1] + red[2] + red[3];
    sq  = red[4] + red[5] + red[6] + red[7];
    float mean = sum * (1.0f / Hh);
    float var  = sq * (1.0f / Hh) - mean * mean;
    float rstd = rsqrtf(var + 1e-12f);
    #pragma unroll
    for (int r = 0; r < 3; r++) {
        int h = tid + (r << 8);
        float v = (e[r] - mean) * rstd * g[h] + bp[h];
        out[(size_t)tok * Hh + h] = v;
        outb[(size_t)tok * Hh + h] = f2bf(v);
    }
}

// ---------------------------------------------------------------------------
// 4. Fused per-layer weight prep: 4 HxH + HxF + FxH transposes + bias concat
//    in one launch. 6913 blocks of 256.
// ---------------------------------------------------------------------------
__global__ __launch_bounds__(256) void prep_kernel(
    const float* __restrict__ Wq, const float* __restrict__ Wk,
    const float* __restrict__ Wv, const float* __restrict__ Wo,
    const float* __restrict__ W1, const float* __restrict__ W2,
    const float* __restrict__ bq, const float* __restrict__ bk,
    const float* __restrict__ bv,
    ushort* __restrict__ qkvoT, ushort* __restrict__ w1T,
    ushort* __restrict__ w2T, float* __restrict__ bqkv)
{
    int b = blockIdx.x;
    if (b >= 6912) {   // bias concat
        for (int j = threadIdx.x; j < Hh; j += 256) {
            bqkv[j]          = bq[j];
            bqkv[Hh + j]     = bk[j];
            bqkv[2 * Hh + j] = bv[j];
        }
        return;
    }
    const float* W;
    ushort* Wt;
    int K, N, n0, k0;
    if (b < 2304) {          // QKVO: 4 x 576 tiles of HxH
        int which = b / 576, t = b % 576;
        const float* srcs[4] = { Wq, Wk, Wv, Wo };
        W = srcs[which];
        Wt = qkvoT + (size_t)which * Hh * Hh;
        K = Hh; N = Hh;
        n0 = (t % 24) * 32; k0 = (t / 24) * 32;
    } else if (b < 4608) {   // W1: [Hh][Ff] -> w1T [Ff][Hh]
        int t = b - 2304;
        W = W1; Wt = w1T; K = Hh; N = Ff;
        n0 = (t % 96) * 32; k0 = (t / 96) * 32;
    } else {                 // W2: [Ff][Hh] -> w2T [Hh][Ff]
        int t = b - 4608;
        W = W2; Wt = w2T; K = Ff; N = Hh;
        n0 = (t % 24) * 32; k0 = (t / 24) * 32;
    }
    __shared__ float ts[32][33];
    int tx = threadIdx.x & 31, ty = threadIdx.x >> 5;
    #pragma unroll
    for (int i = 0; i < 32; i += 8)
        ts[ty + i][tx] = W[(size_t)(k0 + ty + i) * N + n0 + tx];
    __syncthreads();
    #pragma unroll
    for (int i = 0; i < 32; i += 8)
        Wt[(size_t)(n0 + ty + i) * K + k0 + tx] = f2bf(ts[tx][ty + i]);
}

// 4b. Padded transpose + bias pad for classifier
__global__ __launch_bounds__(256) void pad_transpose_kernel(
    const float* __restrict__ W, ushort* __restrict__ Wt, int K, int N)
{
    __shared__ float ts[32][33];
    int n0 = blockIdx.x * 32, k0 = blockIdx.y * 32;
    int tx = threadIdx.x & 31, ty = threadIdx.x >> 5;
    #pragma unroll
    for (int i = 0; i < 32; i += 8) {
        int n = n0 + tx;
        ts[ty + i][tx] = (n < N) ? W[(size_t)(k0 + ty + i) * N + n] : 0.f;
    }
    __syncthreads();
    #pragma unroll
    for (int i = 0; i < 32; i += 8)
        Wt[(size_t)(n0 + ty + i) * K + k0 + tx] = f2bf(ts[tx][ty + i]);
}

__global__ __launch_bounds__(256) void bias_pad_kernel(
    const float* __restrict__ cb, float* __restrict__ cbp)
{
    int i = blockIdx.x * 256 + threadIdx.x;
    if (i < VP) cbp[i] = (i < Vv) ? cb[i] : -1.0e9f;
}

// ---------------------------------------------------------------------------
// 5. bf16 MFMA GEMM (m97-pattern), split-K via gridDim.z.
// ---------------------------------------------------------------------------
template <int ACT, int OUT_BF, int BIAS>
__global__ __launch_bounds__(256) void mfma_gemm(
    const ushort* __restrict__ A,
    const ushort* __restrict__ Bt,
    const float* __restrict__ bias,
    void* __restrict__ C,
    int N, int K, int lda, int ldb)
{
    __shared__ __align__(16) ushort As[128 * 32];
    __shared__ __align__(16) ushort Bs[128 * 32];
    const int tid = threadIdx.x;
    const int lane = tid & 63, wid = tid >> 6;
    const int m0 = blockIdx.y * 128, n0 = blockIdx.x * 128;
    const int kbase = blockIdx.z * K;
    const size_t zoff = (size_t)blockIdx.z * Mm * N;
    A += kbase;
    Bt += kbase;
    const int wr = (wid >> 1) * 64, wc = (wid & 1) * 64;
    const int lr = lane & 15;
    const int kg = (lane >> 4) << 3;

    f32x4 acc[4][4];
    #pragma unroll
    for (int mi = 0; mi < 4; ++mi)
        #pragma unroll
        for (int ni = 0; ni < 4; ++ni)
            acc[mi][ni] = (f32x4){0.f, 0.f, 0.f, 0.f};

    for (int k0 = 0; k0 < K; k0 += 32) {
        #pragma unroll
        for (int i = 0; i < 2; ++i) {
            int idx = i * 256 + tid;
            int r = idx >> 2, c = (idx & 3) << 3;
            __builtin_amdgcn_global_load_lds(
                (const __attribute__((address_space(1))) void*)(A + (size_t)(m0 + r) * lda + k0 + c),
                (__attribute__((address_space(3))) void*)(As + (size_t)(i * 256 + (wid << 6)) * 8),
                16, 0, 0);
        }
        #pragma unroll
        for (int i = 0; i < 2; ++i) {
            int idx = i * 256 + tid;
            int r = idx >> 2, c = (idx & 3) << 3;
            __builtin_amdgcn_global_load_lds(
                (const __attribute__((address_space(1))) void*)(Bt + (size_t)(n0 + r) * ldb + k0 + c),
                (__attribute__((address_space(3))) void*)(Bs + (size_t)(i * 256 + (wid << 6)) * 8),
                16, 0, 0);
        }
        __syncthreads();

        bf16x8 af[4], bfr[4];
        #pragma unroll
        for (int mi = 0; mi < 4; ++mi)
            af[mi] = *(const bf16x8*)(As + (size_t)(wr + mi * 16 + lr) * 32 + kg);
        #pragma unroll
        for (int ni = 0; ni < 4; ++ni)
            bfr[ni] = *(const bf16x8*)(Bs + (size_t)(wc + ni * 16 + lr) * 32 + kg);

        #pragma unroll
        for (int mi = 0; mi < 4; ++mi)
            #pragma unroll
            for (int ni = 0; ni < 4; ++ni)
                acc[mi][ni] = __builtin_amdgcn_mfma_f32_16x16x32_bf16(
                    af[mi], bfr[ni], acc[mi][ni], 0, 0, 0);
        __syncthreads();
    }

    #pragma unroll
    for (int ni = 0; ni < 4; ++ni) {
        int col = n0 + wc + ni * 16 + lr;
        float bsv = 0.f;
        if (BIAS) bsv = bias[col];
        #pragma unroll
        for (int mi = 0; mi < 4; ++mi) {
            f32x4 v = acc[mi][ni];
            #pragma unroll
            for (int q = 0; q < 4; ++q) {
                int row = m0 + wr + mi * 16 + ((lane >> 4) << 2) + q;
                float val = v[q] + bsv;
                if (ACT == 1) {
                    // tanh-form GELU via HW exp (max |delta| ~3e-4 vs exact erf)
                    float y = 0.7978845608028654f
                              * (val + 0.044715f * val * val * val);
                    val = val / (1.0f + __expf(-2.0f * y));
                }
                if (OUT_BF)
                    ((ushort*)C)[(size_t)row * N + col] = f2bf(val);
                else
                    ((float*)C)[zoff + (size_t)row * N + col] = val;
            }
        }
    }
}

// ---------------------------------------------------------------------------
// 6. Fused MFMA flash attention.
//    K_lds now stride 72 (reg-staged): conflict-free ds_read_b128
//    (rows 144B apart -> quarter-wave covers all 32 banks).
// ---------------------------------------------------------------------------
constexpr int SP = 65;   // S_lds stride (f32)
constexpr int PS = 72;   // P_lds stride (u16)
constexpr int VS = 72;   // Vt_lds / K_lds stride (u16)

__global__ __launch_bounds__(256) void flash_attn_kernel(
    const ushort* __restrict__ qkv, const int* __restrict__ info,
    ushort* __restrict__ ctx)
{
    __shared__ __align__(16) ushort K_lds[64 * VS];
    __shared__ __align__(16) ushort Vt_lds[64 * VS];
    __shared__ __align__(16) ushort P_lds[64 * PS];
    __shared__ float S_lds[64 * SP];
    __shared__ float m_s[64], l_s[64], rf_s[64];

    const int tid = threadIdx.x;
    const int lane = tid & 63, wid = tid >> 6;
    const int bh = blockIdx.y, b = bh / NHh, h = bh % NHh;
    const int i0 = blockIdx.x * 64;
    const int lr = lane & 15, hi = lane >> 4;
    const int kg = hi << 3;
    const int wr = (wid >> 1) * 32;
    const int wc = (wid & 1) * 32;
    const int has = info[b * 4 + 1], sep = info[b * 4 + 2];
    const size_t tok0 = (size_t)b * Ss;

    bf16x8 qf[2][2];
    #pragma unroll
    for (int mi = 0; mi < 2; ++mi)
        #pragma unroll
        for (int kk = 0; kk < 2; ++kk)
            qf[mi][kk] = *(const bf16x8*)&qkv[(tok0 + i0 + wr + mi * 16 + lr) * QKVN
                                             + h * DHh + kk * 32 + kg];

    f32x4 o[2][2];
    #pragma unroll
    for (int mi = 0; mi < 2; ++mi)
        #pragma unroll
        for (int ni = 0; ni < 2; ++ni)
            o[mi][ni] = (f32x4){0.f, 0.f, 0.f, 0.f};

    if (tid < 64) { m_s[tid] = -3.0e38f; l_s[tid] = 0.f; }
    __syncthreads();

    for (int j0 = 0; j0 < Ss; j0 += 64) {
        // stage K tile [kv=64][d=64] reg-staged into stride-72 LDS
        #pragma unroll
        for (int i = 0; i < 2; ++i) {
            int ix = i * 256 + tid;
            int r = ix >> 3, c = (ix & 7) << 3;
            uint4 kq = *(const uint4*)&qkv[(tok0 + j0 + r) * QKVN + Hh + h * DHh + c];
            *(uint4*)&K_lds[(size_t)r * VS + c] = kq;
        }
        // stage V transposed: Vt[d][kv], stride 72
        {
            int kv0 = (tid & 15) * 4;
            int d0 = (tid >> 4) * 4;
            uint2 rv[4];
            #pragma unroll
            for (int r = 0; r < 4; ++r)
                rv[r] = *(const uint2*)&qkv[(tok0 + j0 + kv0 + r) * QKVN
                                            + 2 * Hh + h * DHh + d0];
            #pragma unroll
            for (int c = 0; c < 4; ++c) {
                unsigned e0 = (c < 2) ? (rv[0].x >> (16 * c)) : (rv[0].y >> (16 * (c - 2)));
                unsigned e1 = (c < 2) ? (rv[1].x >> (16 * c)) : (rv[1].y >> (16 * (c - 2)));
                unsigned e2 = (c < 2) ? (rv[2].x >> (16 * c)) : (rv[2].y >> (16 * (c - 2)));
                unsigned e3 = (c < 2) ? (rv[3].x >> (16 * c)) : (rv[3].y >> (16 * (c - 2)));
                uint2 packed;
                packed.x = (e0 & 0xffffu) | (e1 << 16);
                packed.y = (e2 & 0xffffu) | (e3 << 16);
                *(uint2*)&Vt_lds[(size_t)(d0 + c) * VS + kv0] = packed;
            }
        }
        __syncthreads();

        f32x4 s[2][2];
        #pragma unroll
        for (int mi = 0; mi < 2; ++mi)
            #pragma unroll
            for (int ni = 0; ni < 2; ++ni)
                s[mi][ni] = (f32x4){0.f, 0.f, 0.f, 0.f};
        #pragma unroll
        for (int ni = 0; ni < 2; ++ni)
            #pragma unroll
            for (int kk = 0; kk < 2; ++kk) {
                bf16x8 kf = *(const bf16x8*)&K_lds[(size_t)(wc + ni * 16 + lr) * VS
                                                   + kk * 32 + kg];
                #pragma unroll
                for (int mi = 0; mi < 2; ++mi)
                    s[mi][ni] = __builtin_amdgcn_mfma_f32_16x16x32_bf16(
                        qf[mi][kk], kf, s[mi][ni], 0, 0, 0);
            }
        #pragma unroll
        for (int mi = 0; mi < 2; ++mi)
            #pragma unroll
            for (int ni = 0; ni < 2; ++ni)
                #pragma unroll
                for (int q = 0; q < 4; ++q) {
                    int rl = wr + mi * 16 + hi * 4 + q;
                    int cl = wc + ni * 16 + lr;
                    int gi = i0 + rl, gj = j0 + cl;
                    bool vis = (!has) || (gj <= sep) || ((gi > sep) && (gj <= gi));
                    S_lds[rl * SP + cl] = s[mi][ni][q] * 0.125f
                                          + (vis ? 0.0f : -1000000000.0f);
                }
        __syncthreads();

        {
            int r = tid >> 2, c0 = (tid & 3) * 16;
            float mold = m_s[r];
            float sv[16];
            float tmax = -3.0e38f;
            #pragma unroll
            for (int c = 0; c < 16; ++c) {
                sv[c] = S_lds[r * SP + c0 + c];
                tmax = fmaxf(tmax, sv[c]);
            }
            tmax = fmaxf(tmax, __shfl_xor(tmax, 1));
            tmax = fmaxf(tmax, __shfl_xor(tmax, 2));
            float mnew = fmaxf(mold, tmax);
            float sum = 0.f;
            #pragma unroll
            for (int c = 0; c < 16; ++c) {
                float p = __expf(sv[c] - mnew);
                P_lds[r * PS + c0 + c] = f2bf(p);
                sum += p;
            }
            sum += __shfl_xor(sum, 1);
            sum += __shfl_xor(sum, 2);
            if ((tid & 3) == 0) {
                float rf = __expf(mold - mnew);
                rf_s[r] = rf;
                l_s[r] = l_s[r] * rf + sum;
                m_s[r] = mnew;
            }
        }
        __syncthreads();

        #pragma unroll
        for (int mi = 0; mi < 2; ++mi)
            #pragma unroll
            for (int q = 0; q < 4; ++q) {
                float rf = rf_s[wr + mi * 16 + hi * 4 + q];
                #pragma unroll
                for (int ni = 0; ni < 2; ++ni)
                    o[mi][ni][q] *= rf;
            }
        #pragma unroll
        for (int kk = 0; kk < 2; ++kk) {
            bf16x8 pf[2];
            #pragma unroll
            for (int mi = 0; mi < 2; ++mi)
                pf[mi] = *(const bf16x8*)&P_lds[(size_t)(wr + mi * 16 + lr) * PS
                                                + kk * 32 + kg];
            #pragma unroll
            for (int ni = 0; ni < 2; ++ni) {
                bf16x8 vf = *(const bf16x8*)&Vt_lds[(size_t)(wc + ni * 16 + lr) * VS
                                                    + kk * 32 + kg];
                #pragma unroll
                for (int mi = 0; mi < 2; ++mi)
                    o[mi][ni] = __builtin_amdgcn_mfma_f32_16x16x32_bf16(
                        pf[mi], vf, o[mi][ni], 0, 0, 0);
            }
        }
        __syncthreads();
    }

    #pragma unroll
    for (int mi = 0; mi < 2; ++mi)
        #pragma unroll
        for (int q = 0; q < 4; ++q) {
            int rl = wr + mi * 16 + hi * 4 + q;
            float inv = 1.0f / l_s[rl];
            #pragma unroll
            for (int ni = 0; ni < 2; ++ni)
                ctx[(tok0 + i0 + rl) * Hh + h * DHh + wc + ni * 16 + lr]
                    = f2bf(o[mi][ni][q] * inv);
        }
}

// ---------------------------------------------------------------------------
// 7. Fused MFMA classifier, fixed-shift LSE
// ---------------------------------------------------------------------------
__global__ __launch_bounds__(256) void cls_lse_kernel(
    const ushort* __restrict__ A,
    const ushort* __restrict__ WT,
    const float* __restrict__ cbp,
    const int* __restrict__ labels,
    float* __restrict__ psv, float* __restrict__ pll)
{
    __shared__ __align__(16) ushort As[128 * 32];
    __shared__ __align__(16) ushort Bs[128 * 32];
    __shared__ float ssum[2][128];
    __shared__ float sll[128];
    __shared__ int lab[128];
    const int tid = threadIdx.x;
    const int lane = tid & 63, wid = tid >> 6;
    const int m0 = blockIdx.y * 128;
    const int chunk = blockIdx.x;
    if (tid < 128) {
        sll[tid] = 0.f;
        lab[tid] = labels[m0 + tid];
    }
    const int wr = (wid >> 1) * 64, wcid = wid & 1, wc = wcid * 64;
    const int lr = lane & 15;
    const int hi = lane >> 4;
    const int kg = hi << 3;

    float sacc[16];
    #pragma unroll
    for (int i = 0; i < 16; ++i) sacc[i] = 0.f;

    for (int t = 0; t < TPC; ++t) {
        const int n0 = (chunk * TPC + t) * 128;
        f32x4 acc[4][4];
        #pragma unroll
        for (int mi = 0; mi < 4; ++mi)
            #pragma unroll
            for (int ni = 0; ni < 4; ++ni)
                acc[mi][ni] = (f32x4){0.f, 0.f, 0.f, 0.f};

        for (int k0 = 0; k0 < Hh; k0 += 32) {
            #pragma unroll
            for (int i = 0; i < 2; ++i) {
                int idx = i * 256 + tid;
                int r = idx >> 2, c = (idx & 3) << 3;
                __builtin_amdgcn_global_load_lds(
                    (const __attribute__((address_space(1))) void*)(A + (size_t)(m0 + r) * Hh + k0 + c),
                    (__attribute__((address_space(3))) void*)(As + (size_t)(i * 256 + (wid << 6)) * 8),
                    16, 0, 0);
            }
            #pragma unroll
            for (int i = 0; i < 2; ++i) {
                int idx = i * 256 + tid;
                int r = idx >> 2, c = (idx & 3) << 3;
                __builtin_amdgcn_global_load_lds(
                    (const __attribute__((address_space(1))) void*)(WT + (size_t)(n0 + r) * Hh + k0 + c),
                    (__attribute__((address_space(3))) void*)(Bs + (size_t)(i * 256 + (wid << 6)) * 8),
                    16, 0, 0);
            }
            __syncthreads();

            bf16x8 af[4], bfr[4];
            #pragma unroll
            for (int mi = 0; mi < 4; ++mi)
                af[mi] = *(const bf16x8*)(As + (size_t)(wr + mi * 16 + lr) * 32 + kg);
            #pragma unroll
            for (int ni = 0; ni < 4; ++ni)
                bfr[ni] = *(const bf16x8*)(Bs + (size_t)(wc + ni * 16 + lr) * 32 + kg);

            #pragma unroll
            for (int mi = 0; mi < 4; ++mi)
                #pragma unroll
                for (int ni = 0; ni < 4; ++ni)
                    acc[mi][ni] = __builtin_amdgcn_mfma_f32_16x16x32_bf16(
                        af[mi], bfr[ni], acc[mi][ni], 0, 0, 0);
            __syncthreads();
        }

        float bvs[4];
        int cols[4];
        #pragma unroll
        for (int ni = 0; ni < 4; ++ni) {
            cols[ni] = n0 + wc + ni * 16 + lr;
            bvs[ni] = cbp[cols[ni]];
        }
        #pragma unroll
        for (int mi = 0; mi < 4; ++mi) {
            #pragma unroll
            for (int q = 0; q < 4; ++q) {
                int rl = wr + mi * 16 + hi * 4 + q;
                float v0 = acc[mi][0][q] + bvs[0];
                float v1 = acc[mi][1][q] + bvs[1];
                float v2 = acc[mi][2][q] + bvs[2];
                float v3 = acc[mi][3][q] + bvs[3];
                int lb = lab[rl];
                if (lb == cols[0]) sll[rl] = v0;
                if (lb == cols[1]) sll[rl] = v1;
                if (lb == cols[2]) sll[rl] = v2;
                if (lb == cols[3]) sll[rl] = v3;
                sacc[mi * 4 + q] += __expf(v0 - LSE_SHIFT) + __expf(v1 - LSE_SHIFT)
                                  + __expf(v2 - LSE_SHIFT) + __expf(v3 - LSE_SHIFT);
            }
        }
    }

    #pragma unroll
    for (int mi = 0; mi < 4; ++mi) {
        #pragma unroll
        for (int q = 0; q < 4; ++q) {
            float s = sacc[mi * 4 + q];
            s += __shfl_xor(s, 1);
            s += __shfl_xor(s, 2);
            s += __shfl_xor(s, 4);
            s += __shfl_xor(s, 8);
            if (lr == 0) ssum[wcid][wr + mi * 16 + hi * 4 + q] = s;
        }
    }
    __syncthreads();
    if (tid < 128) {
        psv[(size_t)chunk * Mm + m0 + tid] = ssum[0][tid] + ssum[1][tid];
        pll[(size_t)chunk * Mm + m0 + tid] = sll[tid];
    }
}

__global__ __launch_bounds__(256) void cls_merge_kernel(
    const float* __restrict__ psv, const float* __restrict__ pll,
    float* __restrict__ ce)
{
    int row = blockIdx.x * 256 + threadIdx.x;
    float s = 0.f, l = 0.f;
    #pragma unroll 1
    for (int c = 0; c < NCH; ++c) {
        s += psv[(size_t)c * Mm + row];
        l += pll[(size_t)c * Mm + row];
    }
    ce[row] = (LSE_SHIFT + logf(s)) - l;
}

// ---------------------------------------------------------------------------
// 8. Masked per-sample mean, final scalar
// ---------------------------------------------------------------------------
__global__ __launch_bounds__(256) void ce_reduce_kernel(
    const float* __restrict__ ce, const int* __restrict__ info,
    float* __restrict__ ps)
{
    int b = blockIdx.x, tid = threadIdx.x;
    int first = info[b * 4 + 0], has = info[b * 4 + 1];
    float sum = 0.0f;
    for (int s = tid; s < Ss; s += 256) {
        bool mv = has ? (s > first) : true;
        if (mv) sum += ce[b * Ss + s];
    }
    #pragma unroll
    for (int off = 32; off; off >>= 1) sum += __shfl_xor(sum, off);
    __shared__ float red[4];
    int lane = tid & 63, wid = tid >> 6;
    if (lane == 0) red[wid] = sum;
    __syncthreads();
    if (tid == 0) {
        float tot = red[0] + red[1] + red[2] + red[3];
        float cnt = has ? (float)(Ss - 1 - first) : (float)Ss;
        ps[b] = tot / cnt;
    }
}

__global__ void final_kernel(const float* __restrict__ ps, float* __restrict__ out)
{
    if (threadIdx.x == 0 && blockIdx.x == 0) {
        float t = 0.0f;
        #pragma unroll
        for (int b = 0; b < Bb; b++) t += ps[b];
        out[0] = t * (1.0f / Bb);
    }
}

// ---------------------------------------------------------------------------
// Host launcher
// ---------------------------------------------------------------------------
extern "C" void kernel_launch(void* const* d_in, const int* in_sizes, int n_in,
                              void* d_out, int out_size, void* d_ws, size_t ws_size,
                              hipStream_t stream)
{
    const int*   ids    = (const int*)d_in[0];
    const int*   labels = (const int*)d_in[1];
    const float* we     = (const float*)d_in[2];
    const float* pe     = (const float*)d_in[3];
    const float* te     = (const float*)d_in[4];
    const float* eg     = (const float*)d_in[5];
    const float* ebp    = (const float*)d_in[6];
    const float* Wq     = (const float*)d_in[7];
    const float* bq     = (const float*)d_in[8];
    const float* Wk     = (const float*)d_in[9];
    const float* bk     = (const float*)d_in[10];
    const float* Wv     = (const float*)d_in[11];
    const float* bv     = (const float*)d_in[12];
    const float* Wo     = (const float*)d_in[13];
    const float* bo     = (const float*)d_in[14];
    const float* l1g    = (const float*)d_in[15];
    const float* l1b    = (const float*)d_in[16];
    const float* W1     = (const float*)d_in[17];
    const float* b1     = (const float*)d_in[18];
    const float* W2     = (const float*)d_in[19];
    const float* b2     = (const float*)d_in[20];
    const float* l2g    = (const float*)d_in[21];
    const float* l2b    = (const float*)d_in[22];
    const float* cW     = (const float*)d_in[23];
    const float* cbias  = (const float*)d_in[24];

    const size_t MH  = (size_t)Mm * Hh;
    const size_t MF  = (size_t)Mm * Ff;
    const size_t HHe = (size_t)Hh * Hh;
    const size_t HFe = (size_t)Hh * Ff;

    // Workspace layout (~135 MB; proven >= 226.5 MB available)
    float* ws = (float*)d_ws;
    float* x      = ws;                                // MH f32
    float* tmp    = x + MH;                            // 4*MH f32
    float* ce     = tmp + 4 * MH;                      // Mm f32
    float* ps     = ce + Mm;                           // 16 f32
    int*   info   = (int*)(ps + 16);                   // 64 ints reserved
    float* bqkv   = (float*)(info + 64);               // 2304 f32
    ushort* xb    = (ushort*)(bqkv + QKVN);            // MH bf16
    ushort* qkvb  = xb + MH;                           // 3*MH bf16
    ushort* ctxb  = qkvb + 3 * MH;                     // MH
    ushort* f1b   = ctxb + MH;                         // MF
    ushort* wscr  = f1b + MF;                          // 4*HHe + 2*HFe bf16
    ushort* wqT = wscr;
    ushort* woT = wqT + 3 * HHe;                       // qkvoT[3] = Wo slot
    ushort* w1T = wscr + 4 * HHe;                      // [F][H]
    ushort* w2T = w1T + HFe;                           // [H][F]
    float* clsf = (float*)(w2T + HFe);
    float* cbp  = clsf;                                // VP
    float* psv  = cbp + VP;                            // NCH*Mm
    float* pll  = psv + (size_t)NCH * Mm;              // NCH*Mm
    ushort* cWT = qkvb;   // alias: qkvb..f1b dead at classifier time

    sep_kernel<<<Bb, 512, 0, stream>>>(ids, info);
    embed_ln_kernel<<<Mm, 256, 0, stream>>>(ids, we, pe, te, eg, ebp, x, xb);

    dim3 gQKV(QKVN / 128, Mm / 128);          // (18, 32)
    dim3 gH(Hh / 128, Mm / 128);              // (6, 32)
    dim3 gF(Ff / 128, Mm / 128);              // (24, 32)
    dim3 gW2(Hh / 128, Mm / 128, 4);          // (6, 32, 4) split-K
    dim3 gA(Ss / 64, Bb * NHh);               // (8, 96)

    for (int l = 0; l < Ll; l++) {
        const float* bo_l = bo + (size_t)l * Hh;
        const float* b1_l = b1 + (size_t)l * Ff;
        const float* b2_l = b2 + (size_t)l * Hh;
        const float* g1  = l1g + (size_t)l * Hh;
        const float* be1 = l1b + (size_t)l * Hh;
        const float* g2  = l2g + (size_t)l * Hh;
        const float* be2 = l2b + (size_t)l * Hh;

        prep_kernel<<<6913, 256, 0, stream>>>(
            Wq + (size_t)l * HHe, Wk + (size_t)l * HHe,
            Wv + (size_t)l * HHe, Wo + (size_t)l * HHe,
            W1 + (size_t)l * HFe, W2 + (size_t)l * HFe,
            bq + (size_t)l * Hh, bk + (size_t)l * Hh, bv + (size_t)l * Hh,
            wscr, w1T, w2T, bqkv);

        // Fused QKV projection: [M][768] @ [2304][768]^T -> [M][2304]
        mfma_gemm<0, 1, 1><<<gQKV, 256, 0, stream>>>(xb, wqT, bqkv, qkvb,
                                                     QKVN, Hh, Hh, Hh);

        flash_attn_kernel<<<gA, 256, 0, stream>>>(qkvb, info, ctxb);

        mfma_gemm<0, 0, 1><<<gH, 256, 0, stream>>>(ctxb, woT, bo_l, tmp,
                                                   Hh, Hh, Hh, Hh);
        resid_ln_kernel<<<Mm, 256, 0, stream>>>(x, tmp, g1, be1, x, xb);

        mfma_gemm<1, 1, 1><<<gF, 256, 0, stream>>>(xb, w1T, b1_l, f1b,
                                                   Ff, Hh, Hh, Hh);
        mfma_gemm<0, 0, 0><<<gW2, 256, 0, stream>>>(f1b, w2T, nullptr, tmp,
                                                    Hh, Hh /*chunk*/, Ff, Ff);
        resid_ln4_kernel<<<Mm, 256, 0, stream>>>(x, tmp, b2_l, g2, be2, x, xb);
    }

    // Classifier
    pad_transpose_kernel<<<dim3(VP / 32, Hh / 32), 256, 0, stream>>>(cW, cWT, Hh, Vv);
    bias_pad_kernel<<<(VP + 255) / 256, 256, 0, stream>>>(cbias, cbp);
    cls_lse_kernel<<<dim3(NCH, Mm / 128), 256, 0, stream>>>(
        xb, cWT, cbp, labels, psv, pll);
    cls_merge_kernel<<<Mm / 256, 256, 0, stream>>>(psv, pll, ce);
    ce_reduce_kernel<<<Bb, 256, 0, stream>>>(ce, info, ps);
    final_kernel<<<1, 64, 0, stream>>>(ps, (float*)d_out);
}

// Round 9
// 2608.059 us; speedup vs baseline: 5.7190x; 1.0047x over previous
//
#include <hip/hip_runtime.h>
#include <math.h>

typedef unsigned short ushort;
typedef __bf16 bf16x8 __attribute__((ext_vector_type(8)));
typedef float f32x4 __attribute__((ext_vector_type(4)));

// Problem dims
constexpr int Bb  = 8;
constexpr int Ss  = 512;
constexpr int Hh  = 768;
constexpr int Ll  = 12;
constexpr int NHh = 12;
constexpr int Ff  = 3072;
constexpr int Vv  = 21128;
constexpr int DHh = 64;
constexpr int Mm  = Bb * Ss;   // 4096
constexpr int SEP_ID = 102;
constexpr int VP  = 21504;     // vocab padded to 168*128
constexpr int NCH = 42;        // vocab chunks (cls grid x) -- r9: 24->42
constexpr int TPC = 4;         // 128-col tiles per chunk   -- r9: 7->4
constexpr int QKVN = 3 * Hh;   // 2304
constexpr float LSE_SHIFT = 20.0f;

static __device__ __forceinline__ ushort f2bf(float f) {
    unsigned u = __float_as_uint(f);
    unsigned r = (u + 0x7fffu + ((u >> 16) & 1u)) >> 16;
    return (ushort)r;
}
static __device__ __forceinline__ float bf2f(unsigned x) {
    return __uint_as_float(x << 16);
}

// ---------------------------------------------------------------------------
// 1. Find first SEP per batch
// ---------------------------------------------------------------------------
__global__ __launch_bounds__(512) void sep_kernel(const int* __restrict__ ids,
                                                  int* __restrict__ info)
{
    int b = blockIdx.x;
    int t = threadIdx.x;
    int v = (ids[b * Ss + t] == SEP_ID) ? t : 0x7FFFFFFF;
    #pragma unroll
    for (int off = 32; off; off >>= 1) {
        int o = __shfl_xor(v, off);
        v = min(v, o);
    }
    __shared__ int wmin[8];
    int lane = t & 63, wid = t >> 6;
    if (lane == 0) wmin[wid] = v;
    __syncthreads();
    if (t == 0) {
        int first = wmin[0];
        #pragma unroll
        for (int w = 1; w < 8; w++) first = min(first, wmin[w]);
        int has = (first != 0x7FFFFFFF) ? 1 : 0;
        info[b * 4 + 0] = first;
        info[b * 4 + 1] = has;
        info[b * 4 + 2] = has ? min(first, Ss - 2) : (Ss + 1);
    }
}

// ---------------------------------------------------------------------------
// 2. Embedding + LayerNorm -> fp32 x and bf16 xb
// ---------------------------------------------------------------------------
__global__ __launch_bounds__(256) void embed_ln_kernel(
    const int* __restrict__ ids, const float* __restrict__ we,
    const float* __restrict__ pe, const float* __restrict__ te,
    const float* __restrict__ g, const float* __restrict__ bp,
    float* __restrict__ x, ushort* __restrict__ xb)
{
    int tok = blockIdx.x;
    int s = tok & (Ss - 1);
    int tid = threadIdx.x;
    int id = ids[tok];
    float e[3];
    #pragma unroll
    for (int r = 0; r < 3; r++) {
        int h = tid + (r << 8);
        e[r] = we[(size_t)id * Hh + h] + pe[(size_t)s * Hh + h] + te[h];
    }
    float sum = e[0] + e[1] + e[2];
    float sq  = fmaf(e[0], e[0], fmaf(e[1], e[1], e[2] * e[2]));
    #pragma unroll
    for (int off = 32; off; off >>= 1) {
        sum += __shfl_xor(sum, off);
        sq  += __shfl_xor(sq, off);
    }
    __shared__ float red[8];
    int lane = tid & 63, wid = tid >> 6;
    if (lane == 0) { red[wid] = sum; red[4 + wid] = sq; }
    __syncthreads();
    sum = red[0] + red[1] + red[2] + red[3];
    sq  = red[4] + red[5] + red[6] + red[7];
    float mean = sum * (1.0f / Hh);
    float var  = sq * (1.0f / Hh) - mean * mean;
    float rstd = rsqrtf(var + 1e-12f);
    #pragma unroll
    for (int r = 0; r < 3; r++) {
        int h = tid + (r << 8);
        float v = (e[r] - mean) * rstd * g[h] + bp[h];
        x[(size_t)tok * Hh + h] = v;
        xb[(size_t)tok * Hh + h] = f2bf(v);
    }
}

// ---------------------------------------------------------------------------
// 3. Residual + 4 split-K partials + bias + LayerNorm
// ---------------------------------------------------------------------------
__global__ __launch_bounds__(256) void resid_ln4_kernel(
    const float* __restrict__ resid, const float* __restrict__ p,  // [4][Mm][Hh]
    const float* __restrict__ bias, const float* __restrict__ g,
    const float* __restrict__ bp,
    float* __restrict__ out, ushort* __restrict__ outb)
{
    const size_t MHl = (size_t)Mm * Hh;
    int tok = blockIdx.x;
    int tid = threadIdx.x;
    float e[3];
    #pragma unroll
    for (int r = 0; r < 3; r++) {
        int h = tid + (r << 8);
        size_t idx = (size_t)tok * Hh + h;
        float acc = resid[idx] + bias[h];
        acc += p[idx];
        acc += p[MHl + idx];
        acc += p[2 * MHl + idx];
        acc += p[3 * MHl + idx];
        e[r] = acc;
    }
    float sum = e[0] + e[1] + e[2];
    float sq  = fmaf(e[0], e[0], fmaf(e[1], e[1], e[2] * e[2]));
    #pragma unroll
    for (int off = 32; off; off >>= 1) {
        sum += __shfl_xor(sum, off);
        sq  += __shfl_xor(sq, off);
    }
    __shared__ float red[8];
    int lane = tid & 63, wid = tid >> 6;
    if (lane == 0) { red[wid] = sum; red[4 + wid] = sq; }
    __syncthreads();
    sum = red[0] + red[1] + red[2] + red[3];
    sq  = red[4] + red[5] + red[6] + red[7];
    float mean = sum * (1.0f / Hh);
    float var  = sq * (1.0f / Hh) - mean * mean;
    float rstd = rsqrtf(var + 1e-12f);
    #pragma unroll
    for (int r = 0; r < 3; r++) {
        int h = tid + (r << 8);
        float v = (e[r] - mean) * rstd * g[h] + bp[h];
        out[(size_t)tok * Hh + h] = v;
        outb[(size_t)tok * Hh + h] = f2bf(v);
    }
}

// ---------------------------------------------------------------------------
// 4. Fused per-layer weight prep: 4 HxH + HxF + FxH transposes + bias concat
// ---------------------------------------------------------------------------
__global__ __launch_bounds__(256) void prep_kernel(
    const float* __restrict__ Wq, const float* __restrict__ Wk,
    const float* __restrict__ Wv, const float* __restrict__ Wo,
    const float* __restrict__ W1, const float* __restrict__ W2,
    const float* __restrict__ bq, const float* __restrict__ bk,
    const float* __restrict__ bv,
    ushort* __restrict__ qkvoT, ushort* __restrict__ w1T,
    ushort* __restrict__ w2T, float* __restrict__ bqkv)
{
    int b = blockIdx.x;
    if (b >= 6912) {   // bias concat
        for (int j = threadIdx.x; j < Hh; j += 256) {
            bqkv[j]          = bq[j];
            bqkv[Hh + j]     = bk[j];
            bqkv[2 * Hh + j] = bv[j];
        }
        return;
    }
    const float* W;
    ushort* Wt;
    int K, N, n0, k0;
    if (b < 2304) {          // QKVO: 4 x 576 tiles of HxH
        int which = b / 576, t = b % 576;
        const float* srcs[4] = { Wq, Wk, Wv, Wo };
        W = srcs[which];
        Wt = qkvoT + (size_t)which * Hh * Hh;
        K = Hh; N = Hh;
        n0 = (t % 24) * 32; k0 = (t / 24) * 32;
    } else if (b < 4608) {   // W1: [Hh][Ff] -> w1T [Ff][Hh]
        int t = b - 2304;
        W = W1; Wt = w1T; K = Hh; N = Ff;
        n0 = (t % 96) * 32; k0 = (t / 96) * 32;
    } else {                 // W2: [Ff][Hh] -> w2T [Hh][Ff]
        int t = b - 4608;
        W = W2; Wt = w2T; K = Ff; N = Hh;
        n0 = (t % 24) * 32; k0 = (t / 24) * 32;
    }
    __shared__ float ts[32][33];
    int tx = threadIdx.x & 31, ty = threadIdx.x >> 5;
    #pragma unroll
    for (int i = 0; i < 32; i += 8)
        ts[ty + i][tx] = W[(size_t)(k0 + ty + i) * N + n0 + tx];
    __syncthreads();
    #pragma unroll
    for (int i = 0; i < 32; i += 8)
        Wt[(size_t)(n0 + ty + i) * K + k0 + tx] = f2bf(ts[tx][ty + i]);
}

// 4b. Padded transpose + bias pad for classifier
__global__ __launch_bounds__(256) void pad_transpose_kernel(
    const float* __restrict__ W, ushort* __restrict__ Wt, int K, int N)
{
    __shared__ float ts[32][33];
    int n0 = blockIdx.x * 32, k0 = blockIdx.y * 32;
    int tx = threadIdx.x & 31, ty = threadIdx.x >> 5;
    #pragma unroll
    for (int i = 0; i < 32; i += 8) {
        int n = n0 + tx;
        ts[ty + i][tx] = (n < N) ? W[(size_t)(k0 + ty + i) * N + n] : 0.f;
    }
    __syncthreads();
    #pragma unroll
    for (int i = 0; i < 32; i += 8)
        Wt[(size_t)(n0 + ty + i) * K + k0 + tx] = f2bf(ts[tx][ty + i]);
}

__global__ __launch_bounds__(256) void bias_pad_kernel(
    const float* __restrict__ cb, float* __restrict__ cbp)
{
    int i = blockIdx.x * 256 + threadIdx.x;
    if (i < VP) cbp[i] = (i < Vv) ? cb[i] : -1.0e9f;
}

// ---------------------------------------------------------------------------
// 5. bf16 MFMA GEMM (m97-pattern), split-K via gridDim.z.
// ---------------------------------------------------------------------------
template <int ACT, int OUT_BF, int BIAS>
__global__ __launch_bounds__(256) void mfma_gemm(
    const ushort* __restrict__ A,
    const ushort* __restrict__ Bt,
    const float* __restrict__ bias,
    void* __restrict__ C,
    int N, int K, int lda, int ldb)
{
    __shared__ __align__(16) ushort As[128 * 32];
    __shared__ __align__(16) ushort Bs[128 * 32];
    const int tid = threadIdx.x;
    const int lane = tid & 63, wid = tid >> 6;
    const int m0 = blockIdx.y * 128, n0 = blockIdx.x * 128;
    const int kbase = blockIdx.z * K;
    const size_t zoff = (size_t)blockIdx.z * Mm * N;
    A += kbase;
    Bt += kbase;
    const int wr = (wid >> 1) * 64, wc = (wid & 1) * 64;
    const int lr = lane & 15;
    const int kg = (lane >> 4) << 3;

    f32x4 acc[4][4];
    #pragma unroll
    for (int mi = 0; mi < 4; ++mi)
        #pragma unroll
        for (int ni = 0; ni < 4; ++ni)
            acc[mi][ni] = (f32x4){0.f, 0.f, 0.f, 0.f};

    for (int k0 = 0; k0 < K; k0 += 32) {
        #pragma unroll
        for (int i = 0; i < 2; ++i) {
            int idx = i * 256 + tid;
            int r = idx >> 2, c = (idx & 3) << 3;
            __builtin_amdgcn_global_load_lds(
                (const __attribute__((address_space(1))) void*)(A + (size_t)(m0 + r) * lda + k0 + c),
                (__attribute__((address_space(3))) void*)(As + (size_t)(i * 256 + (wid << 6)) * 8),
                16, 0, 0);
        }
        #pragma unroll
        for (int i = 0; i < 2; ++i) {
            int idx = i * 256 + tid;
            int r = idx >> 2, c = (idx & 3) << 3;
            __builtin_amdgcn_global_load_lds(
                (const __attribute__((address_space(1))) void*)(Bt + (size_t)(n0 + r) * ldb + k0 + c),
                (__attribute__((address_space(3))) void*)(Bs + (size_t)(i * 256 + (wid << 6)) * 8),
                16, 0, 0);
        }
        __syncthreads();

        bf16x8 af[4], bfr[4];
        #pragma unroll
        for (int mi = 0; mi < 4; ++mi)
            af[mi] = *(const bf16x8*)(As + (size_t)(wr + mi * 16 + lr) * 32 + kg);
        #pragma unroll
        for (int ni = 0; ni < 4; ++ni)
            bfr[ni] = *(const bf16x8*)(Bs + (size_t)(wc + ni * 16 + lr) * 32 + kg);

        #pragma unroll
        for (int mi = 0; mi < 4; ++mi)
            #pragma unroll
            for (int ni = 0; ni < 4; ++ni)
                acc[mi][ni] = __builtin_amdgcn_mfma_f32_16x16x32_bf16(
                    af[mi], bfr[ni], acc[mi][ni], 0, 0, 0);
        __syncthreads();
    }

    #pragma unroll
    for (int ni = 0; ni < 4; ++ni) {
        int col = n0 + wc + ni * 16 + lr;
        float bsv = 0.f;
        if (BIAS) bsv = bias[col];
        #pragma unroll
        for (int mi = 0; mi < 4; ++mi) {
            f32x4 v = acc[mi][ni];
            #pragma unroll
            for (int q = 0; q < 4; ++q) {
                int row = m0 + wr + mi * 16 + ((lane >> 4) << 2) + q;
                float val = v[q] + bsv;
                if (ACT == 1) {
                    float y = 0.7978845608028654f
                              * (val + 0.044715f * val * val * val);
                    val = val / (1.0f + __expf(-2.0f * y));
                }
                if (OUT_BF)
                    ((ushort*)C)[(size_t)row * N + col] = f2bf(val);
                else
                    ((float*)C)[zoff + (size_t)row * N + col] = val;
            }
        }
    }
}

// ---------------------------------------------------------------------------
// 6. Fused MFMA flash attention (stride-72 conflict-free LDS)
// ---------------------------------------------------------------------------
constexpr int SP = 65;   // S_lds stride (f32)
constexpr int PS = 72;   // P_lds stride (u16)
constexpr int VS = 72;   // Vt_lds / K_lds stride (u16)

__global__ __launch_bounds__(256) void flash_attn_kernel(
    const ushort* __restrict__ qkv, const int* __restrict__ info,
    ushort* __restrict__ ctx)
{
    __shared__ __align__(16) ushort K_lds[64 * VS];
    __shared__ __align__(16) ushort Vt_lds[64 * VS];
    __shared__ __align__(16) ushort P_lds[64 * PS];
    __shared__ float S_lds[64 * SP];
    __shared__ float m_s[64], l_s[64], rf_s[64];

    const int tid = threadIdx.x;
    const int lane = tid & 63, wid = tid >> 6;
    const int bh = blockIdx.y, b = bh / NHh, h = bh % NHh;
    const int i0 = blockIdx.x * 64;
    const int lr = lane & 15, hi = lane >> 4;
    const int kg = hi << 3;
    const int wr = (wid >> 1) * 32;
    const int wc = (wid & 1) * 32;
    const int has = info[b * 4 + 1], sep = info[b * 4 + 2];
    const size_t tok0 = (size_t)b * Ss;

    bf16x8 qf[2][2];
    #pragma unroll
    for (int mi = 0; mi < 2; ++mi)
        #pragma unroll
        for (int kk = 0; kk < 2; ++kk)
            qf[mi][kk] = *(const bf16x8*)&qkv[(tok0 + i0 + wr + mi * 16 + lr) * QKVN
                                             + h * DHh + kk * 32 + kg];

    f32x4 o[2][2];
    #pragma unroll
    for (int mi = 0; mi < 2; ++mi)
        #pragma unroll
        for (int ni = 0; ni < 2; ++ni)
            o[mi][ni] = (f32x4){0.f, 0.f, 0.f, 0.f};

    if (tid < 64) { m_s[tid] = -3.0e38f; l_s[tid] = 0.f; }
    __syncthreads();

    for (int j0 = 0; j0 < Ss; j0 += 64) {
        #pragma unroll
        for (int i = 0; i < 2; ++i) {
            int ix = i * 256 + tid;
            int r = ix >> 3, c = (ix & 7) << 3;
            uint4 kq = *(const uint4*)&qkv[(tok0 + j0 + r) * QKVN + Hh + h * DHh + c];
            *(uint4*)&K_lds[(size_t)r * VS + c] = kq;
        }
        {
            int kv0 = (tid & 15) * 4;
            int d0 = (tid >> 4) * 4;
            uint2 rv[4];
            #pragma unroll
            for (int r = 0; r < 4; ++r)
                rv[r] = *(const uint2*)&qkv[(tok0 + j0 + kv0 + r) * QKVN
                                            + 2 * Hh + h * DHh + d0];
            #pragma unroll
            for (int c = 0; c < 4; ++c) {
                unsigned e0 = (c < 2) ? (rv[0].x >> (16 * c)) : (rv[0].y >> (16 * (c - 2)));
                unsigned e1 = (c < 2) ? (rv[1].x >> (16 * c)) : (rv[1].y >> (16 * (c - 2)));
                unsigned e2 = (c < 2) ? (rv[2].x >> (16 * c)) : (rv[2].y >> (16 * (c - 2)));
                unsigned e3 = (c < 2) ? (rv[3].x >> (16 * c)) : (rv[3].y >> (16 * (c - 2)));
                uint2 packed;
                packed.x = (e0 & 0xffffu) | (e1 << 16);
                packed.y = (e2 & 0xffffu) | (e3 << 16);
                *(uint2*)&Vt_lds[(size_t)(d0 + c) * VS + kv0] = packed;
            }
        }
        __syncthreads();

        f32x4 s[2][2];
        #pragma unroll
        for (int mi = 0; mi < 2; ++mi)
            #pragma unroll
            for (int ni = 0; ni < 2; ++ni)
                s[mi][ni] = (f32x4){0.f, 0.f, 0.f, 0.f};
        #pragma unroll
        for (int ni = 0; ni < 2; ++ni)
            #pragma unroll
            for (int kk = 0; kk < 2; ++kk) {
                bf16x8 kf = *(const bf16x8*)&K_lds[(size_t)(wc + ni * 16 + lr) * VS
                                                   + kk * 32 + kg];
                #pragma unroll
                for (int mi = 0; mi < 2; ++mi)
                    s[mi][ni] = __builtin_amdgcn_mfma_f32_16x16x32_bf16(
                        qf[mi][kk], kf, s[mi][ni], 0, 0, 0);
            }
        #pragma unroll
        for (int mi = 0; mi < 2; ++mi)
            #pragma unroll
            for (int ni = 0; ni < 2; ++ni)
                #pragma unroll
                for (int q = 0; q < 4; ++q) {
                    int rl = wr + mi * 16 + hi * 4 + q;
                    int cl = wc + ni * 16 + lr;
                    int gi = i0 + rl, gj = j0 + cl;
                    bool vis = (!has) || (gj <= sep) || ((gi > sep) && (gj <= gi));
                    S_lds[rl * SP + cl] = s[mi][ni][q] * 0.125f
                                          + (vis ? 0.0f : -1000000000.0f);
                }
        __syncthreads();

        {
            int r = tid >> 2, c0 = (tid & 3) * 16;
            float mold = m_s[r];
            float sv[16];
            float tmax = -3.0e38f;
            #pragma unroll
            for (int c = 0; c < 16; ++c) {
                sv[c] = S_lds[r * SP + c0 + c];
                tmax = fmaxf(tmax, sv[c]);
            }
            tmax = fmaxf(tmax, __shfl_xor(tmax, 1));
            tmax = fmaxf(tmax, __shfl_xor(tmax, 2));
            float mnew = fmaxf(mold, tmax);
            float sum = 0.f;
            #pragma unroll
            for (int c = 0; c < 16; ++c) {
                float p = __expf(sv[c] - mnew);
                P_lds[r * PS + c0 + c] = f2bf(p);
                sum += p;
            }
            sum += __shfl_xor(sum, 1);
            sum += __shfl_xor(sum, 2);
            if ((tid & 3) == 0) {
                float rf = __expf(mold - mnew);
                rf_s[r] = rf;
                l_s[r] = l_s[r] * rf + sum;
                m_s[r] = mnew;
            }
        }
        __syncthreads();

        #pragma unroll
        for (int mi = 0; mi < 2; ++mi)
            #pragma unroll
            for (int q = 0; q < 4; ++q) {
                float rf = rf_s[wr + mi * 16 + hi * 4 + q];
                #pragma unroll
                for (int ni = 0; ni < 2; ++ni)
                    o[mi][ni][q] *= rf;
            }
        #pragma unroll
        for (int kk = 0; kk < 2; ++kk) {
            bf16x8 pf[2];
            #pragma unroll
            for (int mi = 0; mi < 2; ++mi)
                pf[mi] = *(const bf16x8*)&P_lds[(size_t)(wr + mi * 16 + lr) * PS
                                                + kk * 32 + kg];
            #pragma unroll
            for (int ni = 0; ni < 2; ++ni) {
                bf16x8 vf = *(const bf16x8*)&Vt_lds[(size_t)(wc + ni * 16 + lr) * VS
                                                    + kk * 32 + kg];
                #pragma unroll
                for (int mi = 0; mi < 2; ++mi)
                    o[mi][ni] = __builtin_amdgcn_mfma_f32_16x16x32_bf16(
                        pf[mi], vf, o[mi][ni], 0, 0, 0);
            }
        }
        __syncthreads();
    }

    #pragma unroll
    for (int mi = 0; mi < 2; ++mi)
        #pragma unroll
        for (int q = 0; q < 4; ++q) {
            int rl = wr + mi * 16 + hi * 4 + q;
            float inv = 1.0f / l_s[rl];
            #pragma unroll
            for (int ni = 0; ni < 2; ++ni)
                ctx[(tok0 + i0 + rl) * Hh + h * DHh + wc + ni * 16 + lr]
                    = f2bf(o[mi][ni][q] * inv);
        }
}

// ---------------------------------------------------------------------------
// 7. Fused MFMA classifier, fixed-shift LSE. Grid (NCH=42, 32).
// ---------------------------------------------------------------------------
__global__ __launch_bounds__(256) void cls_lse_kernel(
    const ushort* __restrict__ A,
    const ushort* __restrict__ WT,
    const float* __restrict__ cbp,
    const int* __restrict__ labels,
    float* __restrict__ psv, float* __restrict__ pll)
{
    __shared__ __align__(16) ushort As[128 * 32];
    __shared__ __align__(16) ushort Bs[128 * 32];
    __shared__ float ssum[2][128];
    __shared__ float sll[128];
    __shared__ int lab[128];
    const int tid = threadIdx.x;
    const int lane = tid & 63, wid = tid >> 6;
    const int m0 = blockIdx.y * 128;
    const int chunk = blockIdx.x;
    if (tid < 128) {
        sll[tid] = 0.f;
        lab[tid] = labels[m0 + tid];
    }
    const int wr = (wid >> 1) * 64, wcid = wid & 1, wc = wcid * 64;
    const int lr = lane & 15;
    const int hi = lane >> 4;
    const int kg = hi << 3;

    float sacc[16];
    #pragma unroll
    for (int i = 0; i < 16; ++i) sacc[i] = 0.f;

    for (int t = 0; t < TPC; ++t) {
        const int n0 = (chunk * TPC + t) * 128;
        f32x4 acc[4][4];
        #pragma unroll
        for (int mi = 0; mi < 4; ++mi)
            #pragma unroll
            for (int ni = 0; ni < 4; ++ni)
                acc[mi][ni] = (f32x4){0.f, 0.f, 0.f, 0.f};

        for (int k0 = 0; k0 < Hh; k0 += 32) {
            #pragma unroll
            for (int i = 0; i < 2; ++i) {
                int idx = i * 256 + tid;
                int r = idx >> 2, c = (idx & 3) << 3;
                __builtin_amdgcn_global_load_lds(
                    (const __attribute__((address_space(1))) void*)(A + (size_t)(m0 + r) * Hh + k0 + c),
                    (__attribute__((address_space(3))) void*)(As + (size_t)(i * 256 + (wid << 6)) * 8),
                    16, 0, 0);
            }
            #pragma unroll
            for (int i = 0; i < 2; ++i) {
                int idx = i * 256 + tid;
                int r = idx >> 2, c = (idx & 3) << 3;
                __builtin_amdgcn_global_load_lds(
                    (const __attribute__((address_space(1))) void*)(WT + (size_t)(n0 + r) * Hh + k0 + c),
                    (__attribute__((address_space(3))) void*)(Bs + (size_t)(i * 256 + (wid << 6)) * 8),
                    16, 0, 0);
            }
            __syncthreads();

            bf16x8 af[4], bfr[4];
            #pragma unroll
            for (int mi = 0; mi < 4; ++mi)
                af[mi] = *(const bf16x8*)(As + (size_t)(wr + mi * 16 + lr) * 32 + kg);
            #pragma unroll
            for (int ni = 0; ni < 4; ++ni)
                bfr[ni] = *(const bf16x8*)(Bs + (size_t)(wc + ni * 16 + lr) * 32 + kg);

            #pragma unroll
            for (int mi = 0; mi < 4; ++mi)
                #pragma unroll
                for (int ni = 0; ni < 4; ++ni)
                    acc[mi][ni] = __builtin_amdgcn_mfma_f32_16x16x32_bf16(
                        af[mi], bfr[ni], acc[mi][ni], 0, 0, 0);
            __syncthreads();
        }

        float bvs[4];
        int cols[4];
        #pragma unroll
        for (int ni = 0; ni < 4; ++ni) {
            cols[ni] = n0 + wc + ni * 16 + lr;
            bvs[ni] = cbp[cols[ni]];
        }
        #pragma unroll
        for (int mi = 0; mi < 4; ++mi) {
            #pragma unroll
            for (int q = 0; q < 4; ++q) {
                int rl = wr + mi * 16 + hi * 4 + q;
                float v0 = acc[mi][0][q] + bvs[0];
                float v1 = acc[mi][1][q] + bvs[1];
                float v2 = acc[mi][2][q] + bvs[2];
                float v3 = acc[mi][3][q] + bvs[3];
                int lb = lab[rl];
                if (lb == cols[0]) sll[rl] = v0;
                if (lb == cols[1]) sll[rl] = v1;
                if (lb == cols[2]) sll[rl] = v2;
                if (lb == cols[3]) sll[rl] = v3;
                sacc[mi * 4 + q] += __expf(v0 - LSE_SHIFT) + __expf(v1 - LSE_SHIFT)
                                  + __expf(v2 - LSE_SHIFT) + __expf(v3 - LSE_SHIFT);
            }
        }
    }

    #pragma unroll
    for (int mi = 0; mi < 4; ++mi) {
        #pragma unroll
        for (int q = 0; q < 4; ++q) {
            float s = sacc[mi * 4 + q];
            s += __shfl_xor(s, 1);
            s += __shfl_xor(s, 2);
            s += __shfl_xor(s, 4);
            s += __shfl_xor(s, 8);
            if (lr == 0) ssum[wcid][wr + mi * 16 + hi * 4 + q] = s;
        }
    }
    __syncthreads();
    if (tid < 128) {
        psv[(size_t)chunk * Mm + m0 + tid] = ssum[0][tid] + ssum[1][tid];
        pll[(size_t)chunk * Mm + m0 + tid] = sll[tid];
    }
}

// 7b. Merge chunk partials + masked per-sample mean (one block per batch)
__global__ __launch_bounds__(256) void cls_finish_kernel(
    const float* __restrict__ psv, const float* __restrict__ pll,
    const int* __restrict__ info, float* __restrict__ ps)
{
    int b = blockIdx.x, tid = threadIdx.x;
    int first = info[b * 4 + 0], has = info[b * 4 + 1];
    float sum = 0.f;
    #pragma unroll
    for (int rr = 0; rr < 2; ++rr) {
        int s = tid + rr * 256;
        int row = b * Ss + s;
        float sv = 0.f, l = 0.f;
        #pragma unroll 1
        for (int c = 0; c < NCH; ++c) {
            sv += psv[(size_t)c * Mm + row];
            l  += pll[(size_t)c * Mm + row];
        }
        float cev = (LSE_SHIFT + logf(sv)) - l;
        bool mv = has ? (s > first) : true;
        if (mv) sum += cev;
    }
    #pragma unroll
    for (int off = 32; off; off >>= 1) sum += __shfl_xor(sum, off);
    __shared__ float red[4];
    int lane = tid & 63, wid = tid >> 6;
    if (lane == 0) red[wid] = sum;
    __syncthreads();
    if (tid == 0) {
        float tot = red[0] + red[1] + red[2] + red[3];
        float cnt = has ? (float)(Ss - 1 - first) : (float)Ss;
        ps[b] = tot / cnt;
    }
}

__global__ void final_kernel(const float* __restrict__ ps, float* __restrict__ out)
{
    if (threadIdx.x == 0 && blockIdx.x == 0) {
        float t = 0.0f;
        #pragma unroll
        for (int b = 0; b < Bb; b++) t += ps[b];
        out[0] = t * (1.0f / Bb);
    }
}

// ---------------------------------------------------------------------------
// Host launcher
// ---------------------------------------------------------------------------
extern "C" void kernel_launch(void* const* d_in, const int* in_sizes, int n_in,
                              void* d_out, int out_size, void* d_ws, size_t ws_size,
                              hipStream_t stream)
{
    const int*   ids    = (const int*)d_in[0];
    const int*   labels = (const int*)d_in[1];
    const float* we     = (const float*)d_in[2];
    const float* pe     = (const float*)d_in[3];
    const float* te     = (const float*)d_in[4];
    const float* eg     = (const float*)d_in[5];
    const float* ebp    = (const float*)d_in[6];
    const float* Wq     = (const float*)d_in[7];
    const float* bq     = (const float*)d_in[8];
    const float* Wk     = (const float*)d_in[9];
    const float* bk     = (const float*)d_in[10];
    const float* Wv     = (const float*)d_in[11];
    const float* bv     = (const float*)d_in[12];
    const float* Wo     = (const float*)d_in[13];
    const float* bo     = (const float*)d_in[14];
    const float* l1g    = (const float*)d_in[15];
    const float* l1b    = (const float*)d_in[16];
    const float* W1     = (const float*)d_in[17];
    const float* b1     = (const float*)d_in[18];
    const float* W2     = (const float*)d_in[19];
    const float* b2     = (const float*)d_in[20];
    const float* l2g    = (const float*)d_in[21];
    const float* l2b    = (const float*)d_in[22];
    const float* cW     = (const float*)d_in[23];
    const float* cbias  = (const float*)d_in[24];

    const size_t MH  = (size_t)Mm * Hh;
    const size_t MF  = (size_t)Mm * Ff;
    const size_t HHe = (size_t)Hh * Hh;
    const size_t HFe = (size_t)Hh * Ff;

    // Workspace layout (~137 MB; proven >= 226.5 MB available)
    float* ws = (float*)d_ws;
    float* x      = ws;                                // MH f32
    float* tmp    = x + MH;                            // 4*MH f32 (split-K partials)
    float* ps     = tmp + 4 * MH;                      // 16 f32
    int*   info   = (int*)(ps + 16);                   // 64 ints reserved
    float* bqkv   = (float*)(info + 64);               // 2304 f32
    ushort* xb    = (ushort*)(bqkv + QKVN);            // MH bf16
    ushort* qkvb  = xb + MH;                           // 3*MH bf16
    ushort* ctxb  = qkvb + 3 * MH;                     // MH
    ushort* f1b   = ctxb + MH;                         // MF
    ushort* wscr  = f1b + MF;                          // 4*HHe + 2*HFe bf16
    ushort* wqT = wscr;
    ushort* woT = wqT + 3 * HHe;                       // qkvoT[3] = Wo slot
    ushort* w1T = wscr + 4 * HHe;                      // [F][H]
    ushort* w2T = w1T + HFe;                           // [H][F]
    float* clsf = (float*)(w2T + HFe);
    float* cbp  = clsf;                                // VP
    float* psv  = cbp + VP;                            // NCH*Mm
    float* pll  = psv + (size_t)NCH * Mm;              // NCH*Mm
    ushort* cWT = qkvb;   // alias: qkvb..f1b dead at classifier time

    sep_kernel<<<Bb, 512, 0, stream>>>(ids, info);
    embed_ln_kernel<<<Mm, 256, 0, stream>>>(ids, we, pe, te, eg, ebp, x, xb);

    dim3 gQKV(QKVN / 128, Mm / 128);          // (18, 32)
    dim3 gWo(Hh / 128, Mm / 128, 4);          // (6, 32, 4) split-K
    dim3 gF(Ff / 128, Mm / 128);              // (24, 32)
    dim3 gW2(Hh / 128, Mm / 128, 4);          // (6, 32, 4) split-K
    dim3 gA(Ss / 64, Bb * NHh);               // (8, 96)

    for (int l = 0; l < Ll; l++) {
        const float* bo_l = bo + (size_t)l * Hh;
        const float* b1_l = b1 + (size_t)l * Ff;
        const float* b2_l = b2 + (size_t)l * Hh;
        const float* g1  = l1g + (size_t)l * Hh;
        const float* be1 = l1b + (size_t)l * Hh;
        const float* g2  = l2g + (size_t)l * Hh;
        const float* be2 = l2b + (size_t)l * Hh;

        prep_kernel<<<6913, 256, 0, stream>>>(
            Wq + (size_t)l * HHe, Wk + (size_t)l * HHe,
            Wv + (size_t)l * HHe, Wo + (size_t)l * HHe,
            W1 + (size_t)l * HFe, W2 + (size_t)l * HFe,
            bq + (size_t)l * Hh, bk + (size_t)l * Hh, bv + (size_t)l * Hh,
            wscr, w1T, w2T, bqkv);

        // Fused QKV projection: [M][768] @ [2304][768]^T -> [M][2304]
        mfma_gemm<0, 1, 1><<<gQKV, 256, 0, stream>>>(xb, wqT, bqkv, qkvb,
                                                     QKVN, Hh, Hh, Hh);

        flash_attn_kernel<<<gA, 256, 0, stream>>>(qkvb, info, ctxb);

        // Wo projection split-K x4 (r9): partials in tmp, bias folded into LN
        mfma_gemm<0, 0, 0><<<gWo, 256, 0, stream>>>(ctxb, woT, nullptr, tmp,
                                                    Hh, Hh / 4, Hh, Hh);
        resid_ln4_kernel<<<Mm, 256, 0, stream>>>(x, tmp, bo_l, g1, be1, x, xb);

        mfma_gemm<1, 1, 1><<<gF, 256, 0, stream>>>(xb, w1T, b1_l, f1b,
                                                   Ff, Hh, Hh, Hh);
        mfma_gemm<0, 0, 0><<<gW2, 256, 0, stream>>>(f1b, w2T, nullptr, tmp,
                                                    Hh, Hh /*chunk*/, Ff, Ff);
        resid_ln4_kernel<<<Mm, 256, 0, stream>>>(x, tmp, b2_l, g2, be2, x, xb);
    }

    // Classifier
    pad_transpose_kernel<<<dim3(VP / 32, Hh / 32), 256, 0, stream>>>(cW, cWT, Hh, Vv);
    bias_pad_kernel<<<(VP + 255) / 256, 256, 0, stream>>>(cbias, cbp);
    cls_lse_kernel<<<dim3(NCH, Mm / 128), 256, 0, stream>>>(
        xb, cWT, cbp, labels, psv, pll);
    cls_finish_kernel<<<Bb, 256, 0, stream>>>(psv, pll, info, ps);
    final_kernel<<<1, 64, 0, stream>>>(ps, (float*)d_out);
}

// Round 10
// 2492.820 us; speedup vs baseline: 5.9834x; 1.0462x over previous
//
#include <hip/hip_runtime.h>
#include <math.h>

typedef unsigned short ushort;
typedef __bf16 bf16x8 __attribute__((ext_vector_type(8)));
typedef float f32x4 __attribute__((ext_vector_type(4)));

// Problem dims
constexpr int Bb  = 8;
constexpr int Ss  = 512;
constexpr int Hh  = 768;
constexpr int Ll  = 12;
constexpr int NHh = 12;
constexpr int Ff  = 3072;
constexpr int Vv  = 21128;
constexpr int DHh = 64;
constexpr int Mm  = Bb * Ss;   // 4096
constexpr int SEP_ID = 102;
constexpr int VP  = 21504;     // vocab padded to 168*128
constexpr int NCH = 42;        // vocab chunks (cls grid x)
constexpr int TPC = 4;         // 128-col tiles per chunk
constexpr int QKVN = 3 * Hh;   // 2304
constexpr float LSE_SHIFT = 20.0f;

static __device__ __forceinline__ ushort f2bf(float f) {
    unsigned u = __float_as_uint(f);
    unsigned r = (u + 0x7fffu + ((u >> 16) & 1u)) >> 16;
    return (ushort)r;
}
static __device__ __forceinline__ float bf2f(unsigned x) {
    return __uint_as_float(x << 16);
}

// ---------------------------------------------------------------------------
// 1. Find first SEP per batch
// ---------------------------------------------------------------------------
__global__ __launch_bounds__(512) void sep_kernel(const int* __restrict__ ids,
                                                  int* __restrict__ info)
{
    int b = blockIdx.x;
    int t = threadIdx.x;
    int v = (ids[b * Ss + t] == SEP_ID) ? t : 0x7FFFFFFF;
    #pragma unroll
    for (int off = 32; off; off >>= 1) {
        int o = __shfl_xor(v, off);
        v = min(v, o);
    }
    __shared__ int wmin[8];
    int lane = t & 63, wid = t >> 6;
    if (lane == 0) wmin[wid] = v;
    __syncthreads();
    if (t == 0) {
        int first = wmin[0];
        #pragma unroll
        for (int w = 1; w < 8; w++) first = min(first, wmin[w]);
        int has = (first != 0x7FFFFFFF) ? 1 : 0;
        info[b * 4 + 0] = first;
        info[b * 4 + 1] = has;
        info[b * 4 + 2] = has ? min(first, Ss - 2) : (Ss + 1);
    }
}

// ---------------------------------------------------------------------------
// 2. Embedding + LayerNorm -> fp32 x and bf16 xb
// ---------------------------------------------------------------------------
__global__ __launch_bounds__(256) void embed_ln_kernel(
    const int* __restrict__ ids, const float* __restrict__ we,
    const float* __restrict__ pe, const float* __restrict__ te,
    const float* __restrict__ g, const float* __restrict__ bp,
    float* __restrict__ x, ushort* __restrict__ xb)
{
    int tok = blockIdx.x;
    int s = tok & (Ss - 1);
    int tid = threadIdx.x;
    int id = ids[tok];
    float e[3];
    #pragma unroll
    for (int r = 0; r < 3; r++) {
        int h = tid + (r << 8);
        e[r] = we[(size_t)id * Hh + h] + pe[(size_t)s * Hh + h] + te[h];
    }
    float sum = e[0] + e[1] + e[2];
    float sq  = fmaf(e[0], e[0], fmaf(e[1], e[1], e[2] * e[2]));
    #pragma unroll
    for (int off = 32; off; off >>= 1) {
        sum += __shfl_xor(sum, off);
        sq  += __shfl_xor(sq, off);
    }
    __shared__ float red[8];
    int lane = tid & 63, wid = tid >> 6;
    if (lane == 0) { red[wid] = sum; red[4 + wid] = sq; }
    __syncthreads();
    sum = red[0] + red[1] + red[2] + red[3];
    sq  = red[4] + red[5] + red[6] + red[7];
    float mean = sum * (1.0f / Hh);
    float var  = sq * (1.0f / Hh) - mean * mean;
    float rstd = rsqrtf(var + 1e-12f);
    #pragma unroll
    for (int r = 0; r < 3; r++) {
        int h = tid + (r << 8);
        float v = (e[r] - mean) * rstd * g[h] + bp[h];
        x[(size_t)tok * Hh + h] = v;
        xb[(size_t)tok * Hh + h] = f2bf(v);
    }
}

// ---------------------------------------------------------------------------
// 3. Residual + 4 split-K bf16 partials + bias + LayerNorm
// ---------------------------------------------------------------------------
__global__ __launch_bounds__(256) void resid_ln4_kernel(
    const float* __restrict__ resid, const ushort* __restrict__ p,  // [4][Mm][Hh] bf16
    const float* __restrict__ bias, const float* __restrict__ g,
    const float* __restrict__ bp,
    float* __restrict__ out, ushort* __restrict__ outb)
{
    const size_t MHl = (size_t)Mm * Hh;
    int tok = blockIdx.x;
    int tid = threadIdx.x;
    float e[3];
    #pragma unroll
    for (int r = 0; r < 3; r++) {
        int h = tid + (r << 8);
        size_t idx = (size_t)tok * Hh + h;
        float acc = resid[idx] + bias[h];
        acc += bf2f(p[idx]);
        acc += bf2f(p[MHl + idx]);
        acc += bf2f(p[2 * MHl + idx]);
        acc += bf2f(p[3 * MHl + idx]);
        e[r] = acc;
    }
    float sum = e[0] + e[1] + e[2];
    float sq  = fmaf(e[0], e[0], fmaf(e[1], e[1], e[2] * e[2]));
    #pragma unroll
    for (int off = 32; off; off >>= 1) {
        sum += __shfl_xor(sum, off);
        sq  += __shfl_xor(sq, off);
    }
    __shared__ float red[8];
    int lane = tid & 63, wid = tid >> 6;
    if (lane == 0) { red[wid] = sum; red[4 + wid] = sq; }
    __syncthreads();
    sum = red[0] + red[1] + red[2] + red[3];
    sq  = red[4] + red[5] + red[6] + red[7];
    float mean = sum * (1.0f / Hh);
    float var  = sq * (1.0f / Hh) - mean * mean;
    float rstd = rsqrtf(var + 1e-12f);
    #pragma unroll
    for (int r = 0; r < 3; r++) {
        int h = tid + (r << 8);
        float v = (e[r] - mean) * rstd * g[h] + bp[h];
        out[(size_t)tok * Hh + h] = v;
        outb[(size_t)tok * Hh + h] = f2bf(v);
    }
}

// ---------------------------------------------------------------------------
// 4. Fused per-layer weight prep: 4 HxH + HxF + FxH transposes + bias concat
// ---------------------------------------------------------------------------
__global__ __launch_bounds__(256) void prep_kernel(
    const float* __restrict__ Wq, const float* __restrict__ Wk,
    const float* __restrict__ Wv, const float* __restrict__ Wo,
    const float* __restrict__ W1, const float* __restrict__ W2,
    const float* __restrict__ bq, const float* __restrict__ bk,
    const float* __restrict__ bv,
    ushort* __restrict__ qkvoT, ushort* __restrict__ w1T,
    ushort* __restrict__ w2T, float* __restrict__ bqkv)
{
    int b = blockIdx.x;
    if (b >= 6912) {   // bias concat
        for (int j = threadIdx.x; j < Hh; j += 256) {
            bqkv[j]          = bq[j];
            bqkv[Hh + j]     = bk[j];
            bqkv[2 * Hh + j] = bv[j];
        }
        return;
    }
    const float* W;
    ushort* Wt;
    int K, N, n0, k0;
    if (b < 2304) {          // QKVO: 4 x 576 tiles of HxH
        int which = b / 576, t = b % 576;
        const float* srcs[4] = { Wq, Wk, Wv, Wo };
        W = srcs[which];
        Wt = qkvoT + (size_t)which * Hh * Hh;
        K = Hh; N = Hh;
        n0 = (t % 24) * 32; k0 = (t / 24) * 32;
    } else if (b < 4608) {   // W1: [Hh][Ff] -> w1T [Ff][Hh]
        int t = b - 2304;
        W = W1; Wt = w1T; K = Hh; N = Ff;
        n0 = (t % 96) * 32; k0 = (t / 96) * 32;
    } else {                 // W2: [Ff][Hh] -> w2T [Hh][Ff]
        int t = b - 4608;
        W = W2; Wt = w2T; K = Ff; N = Hh;
        n0 = (t % 24) * 32; k0 = (t / 24) * 32;
    }
    __shared__ float ts[32][33];
    int tx = threadIdx.x & 31, ty = threadIdx.x >> 5;
    #pragma unroll
    for (int i = 0; i < 32; i += 8)
        ts[ty + i][tx] = W[(size_t)(k0 + ty + i) * N + n0 + tx];
    __syncthreads();
    #pragma unroll
    for (int i = 0; i < 32; i += 8)
        Wt[(size_t)(n0 + ty + i) * K + k0 + tx] = f2bf(ts[tx][ty + i]);
}

// 4b. Padded transpose + bias pad for classifier
__global__ __launch_bounds__(256) void pad_transpose_kernel(
    const float* __restrict__ W, ushort* __restrict__ Wt, int K, int N)
{
    __shared__ float ts[32][33];
    int n0 = blockIdx.x * 32, k0 = blockIdx.y * 32;
    int tx = threadIdx.x & 31, ty = threadIdx.x >> 5;
    #pragma unroll
    for (int i = 0; i < 32; i += 8) {
        int n = n0 + tx;
        ts[ty + i][tx] = (n < N) ? W[(size_t)(k0 + ty + i) * N + n] : 0.f;
    }
    __syncthreads();
    #pragma unroll
    for (int i = 0; i < 32; i += 8)
        Wt[(size_t)(n0 + ty + i) * K + k0 + tx] = f2bf(ts[tx][ty + i]);
}

__global__ __launch_bounds__(256) void bias_pad_kernel(
    const float* __restrict__ cb, float* __restrict__ cbp)
{
    int i = blockIdx.x * 256 + threadIdx.x;
    if (i < VP) cbp[i] = (i < Vv) ? cb[i] : -1.0e9f;
}

// ---------------------------------------------------------------------------
// 5. bf16 MFMA GEMM (m97-pattern), split-K via gridDim.z.
//    OUT_BF=1 writes bf16 (z-offset partials when gridDim.z>1);
//    OUT_BF=0 writes f32 with z-offset.
// ---------------------------------------------------------------------------
template <int ACT, int OUT_BF, int BIAS>
__global__ __launch_bounds__(256) void mfma_gemm(
    const ushort* __restrict__ A,
    const ushort* __restrict__ Bt,
    const float* __restrict__ bias,
    void* __restrict__ C,
    int N, int K, int lda, int ldb)
{
    __shared__ __align__(16) ushort As[128 * 32];
    __shared__ __align__(16) ushort Bs[128 * 32];
    const int tid = threadIdx.x;
    const int lane = tid & 63, wid = tid >> 6;
    const int m0 = blockIdx.y * 128, n0 = blockIdx.x * 128;
    const int kbase = blockIdx.z * K;
    const size_t zoff = (size_t)blockIdx.z * Mm * N;
    A += kbase;
    Bt += kbase;
    const int wr = (wid >> 1) * 64, wc = (wid & 1) * 64;
    const int lr = lane & 15;
    const int kg = (lane >> 4) << 3;

    f32x4 acc[4][4];
    #pragma unroll
    for (int mi = 0; mi < 4; ++mi)
        #pragma unroll
        for (int ni = 0; ni < 4; ++ni)
            acc[mi][ni] = (f32x4){0.f, 0.f, 0.f, 0.f};

    for (int k0 = 0; k0 < K; k0 += 32) {
        #pragma unroll
        for (int i = 0; i < 2; ++i) {
            int idx = i * 256 + tid;
            int r = idx >> 2, c = (idx & 3) << 3;
            __builtin_amdgcn_global_load_lds(
                (const __attribute__((address_space(1))) void*)(A + (size_t)(m0 + r) * lda + k0 + c),
                (__attribute__((address_space(3))) void*)(As + (size_t)(i * 256 + (wid << 6)) * 8),
                16, 0, 0);
        }
        #pragma unroll
        for (int i = 0; i < 2; ++i) {
            int idx = i * 256 + tid;
            int r = idx >> 2, c = (idx & 3) << 3;
            __builtin_amdgcn_global_load_lds(
                (const __attribute__((address_space(1))) void*)(Bt + (size_t)(n0 + r) * ldb + k0 + c),
                (__attribute__((address_space(3))) void*)(Bs + (size_t)(i * 256 + (wid << 6)) * 8),
                16, 0, 0);
        }
        __syncthreads();

        bf16x8 af[4], bfr[4];
        #pragma unroll
        for (int mi = 0; mi < 4; ++mi)
            af[mi] = *(const bf16x8*)(As + (size_t)(wr + mi * 16 + lr) * 32 + kg);
        #pragma unroll
        for (int ni = 0; ni < 4; ++ni)
            bfr[ni] = *(const bf16x8*)(Bs + (size_t)(wc + ni * 16 + lr) * 32 + kg);

        #pragma unroll
        for (int mi = 0; mi < 4; ++mi)
            #pragma unroll
            for (int ni = 0; ni < 4; ++ni)
                acc[mi][ni] = __builtin_amdgcn_mfma_f32_16x16x32_bf16(
                    af[mi], bfr[ni], acc[mi][ni], 0, 0, 0);
        __syncthreads();
    }

    #pragma unroll
    for (int ni = 0; ni < 4; ++ni) {
        int col = n0 + wc + ni * 16 + lr;
        float bsv = 0.f;
        if (BIAS) bsv = bias[col];
        #pragma unroll
        for (int mi = 0; mi < 4; ++mi) {
            f32x4 v = acc[mi][ni];
            #pragma unroll
            for (int q = 0; q < 4; ++q) {
                int row = m0 + wr + mi * 16 + ((lane >> 4) << 2) + q;
                float val = v[q] + bsv;
                if (ACT == 1) {
                    float y = 0.7978845608028654f
                              * (val + 0.044715f * val * val * val);
                    val = val / (1.0f + __expf(-2.0f * y));
                }
                if (OUT_BF)
                    ((ushort*)C)[zoff + (size_t)row * N + col] = f2bf(val);
                else
                    ((float*)C)[zoff + (size_t)row * N + col] = val;
            }
        }
    }
}

// ---------------------------------------------------------------------------
// 6. Fused MFMA flash attention (stride-72 conflict-free LDS)
// ---------------------------------------------------------------------------
constexpr int SP = 65;   // S_lds stride (f32)
constexpr int PS = 72;   // P_lds stride (u16)
constexpr int VS = 72;   // Vt_lds / K_lds stride (u16)

__global__ __launch_bounds__(256) void flash_attn_kernel(
    const ushort* __restrict__ qkv, const int* __restrict__ info,
    ushort* __restrict__ ctx)
{
    __shared__ __align__(16) ushort K_lds[64 * VS];
    __shared__ __align__(16) ushort Vt_lds[64 * VS];
    __shared__ __align__(16) ushort P_lds[64 * PS];
    __shared__ float S_lds[64 * SP];
    __shared__ float m_s[64], l_s[64], rf_s[64];

    const int tid = threadIdx.x;
    const int lane = tid & 63, wid = tid >> 6;
    const int bh = blockIdx.y, b = bh / NHh, h = bh % NHh;
    const int i0 = blockIdx.x * 64;
    const int lr = lane & 15, hi = lane >> 4;
    const int kg = hi << 3;
    const int wr = (wid >> 1) * 32;
    const int wc = (wid & 1) * 32;
    const int has = info[b * 4 + 1], sep = info[b * 4 + 2];
    const size_t tok0 = (size_t)b * Ss;

    bf16x8 qf[2][2];
    #pragma unroll
    for (int mi = 0; mi < 2; ++mi)
        #pragma unroll
        for (int kk = 0; kk < 2; ++kk)
            qf[mi][kk] = *(const bf16x8*)&qkv[(tok0 + i0 + wr + mi * 16 + lr) * QKVN
                                             + h * DHh + kk * 32 + kg];

    f32x4 o[2][2];
    #pragma unroll
    for (int mi = 0; mi < 2; ++mi)
        #pragma unroll
        for (int ni = 0; ni < 2; ++ni)
            o[mi][ni] = (f32x4){0.f, 0.f, 0.f, 0.f};

    if (tid < 64) { m_s[tid] = -3.0e38f; l_s[tid] = 0.f; }
    __syncthreads();

    for (int j0 = 0; j0 < Ss; j0 += 64) {
        #pragma unroll
        for (int i = 0; i < 2; ++i) {
            int ix = i * 256 + tid;
            int r = ix >> 3, c = (ix & 7) << 3;
            uint4 kq = *(const uint4*)&qkv[(tok0 + j0 + r) * QKVN + Hh + h * DHh + c];
            *(uint4*)&K_lds[(size_t)r * VS + c] = kq;
        }
        {
            int kv0 = (tid & 15) * 4;
            int d0 = (tid >> 4) * 4;
            uint2 rv[4];
            #pragma unroll
            for (int r = 0; r < 4; ++r)
                rv[r] = *(const uint2*)&qkv[(tok0 + j0 + kv0 + r) * QKVN
                                            + 2 * Hh + h * DHh + d0];
            #pragma unroll
            for (int c = 0; c < 4; ++c) {
                unsigned e0 = (c < 2) ? (rv[0].x >> (16 * c)) : (rv[0].y >> (16 * (c - 2)));
                unsigned e1 = (c < 2) ? (rv[1].x >> (16 * c)) : (rv[1].y >> (16 * (c - 2)));
                unsigned e2 = (c < 2) ? (rv[2].x >> (16 * c)) : (rv[2].y >> (16 * (c - 2)));
                unsigned e3 = (c < 2) ? (rv[3].x >> (16 * c)) : (rv[3].y >> (16 * (c - 2)));
                uint2 packed;
                packed.x = (e0 & 0xffffu) | (e1 << 16);
                packed.y = (e2 & 0xffffu) | (e3 << 16);
                *(uint2*)&Vt_lds[(size_t)(d0 + c) * VS + kv0] = packed;
            }
        }
        __syncthreads();

        f32x4 s[2][2];
        #pragma unroll
        for (int mi = 0; mi < 2; ++mi)
            #pragma unroll
            for (int ni = 0; ni < 2; ++ni)
                s[mi][ni] = (f32x4){0.f, 0.f, 0.f, 0.f};
        #pragma unroll
        for (int ni = 0; ni < 2; ++ni)
            #pragma unroll
            for (int kk = 0; kk < 2; ++kk) {
                bf16x8 kf = *(const bf16x8*)&K_lds[(size_t)(wc + ni * 16 + lr) * VS
                                                   + kk * 32 + kg];
                #pragma unroll
                for (int mi = 0; mi < 2; ++mi)
                    s[mi][ni] = __builtin_amdgcn_mfma_f32_16x16x32_bf16(
                        qf[mi][kk], kf, s[mi][ni], 0, 0, 0);
            }
        #pragma unroll
        for (int mi = 0; mi < 2; ++mi)
            #pragma unroll
            for (int ni = 0; ni < 2; ++ni)
                #pragma unroll
                for (int q = 0; q < 4; ++q) {
                    int rl = wr + mi * 16 + hi * 4 + q;
                    int cl = wc + ni * 16 + lr;
                    int gi = i0 + rl, gj = j0 + cl;
                    bool vis = (!has) || (gj <= sep) || ((gi > sep) && (gj <= gi));
                    S_lds[rl * SP + cl] = s[mi][ni][q] * 0.125f
                                          + (vis ? 0.0f : -1000000000.0f);
                }
        __syncthreads();

        {
            int r = tid >> 2, c0 = (tid & 3) * 16;
            float mold = m_s[r];
            float sv[16];
            float tmax = -3.0e38f;
            #pragma unroll
            for (int c = 0; c < 16; ++c) {
                sv[c] = S_lds[r * SP + c0 + c];
                tmax = fmaxf(tmax, sv[c]);
            }
            tmax = fmaxf(tmax, __shfl_xor(tmax, 1));
            tmax = fmaxf(tmax, __shfl_xor(tmax, 2));
            float mnew = fmaxf(mold, tmax);
            float sum = 0.f;
            #pragma unroll
            for (int c = 0; c < 16; ++c) {
                float p = __expf(sv[c] - mnew);
                P_lds[r * PS + c0 + c] = f2bf(p);
                sum += p;
            }
            sum += __shfl_xor(sum, 1);
            sum += __shfl_xor(sum, 2);
            if ((tid & 3) == 0) {
                float rf = __expf(mold - mnew);
                rf_s[r] = rf;
                l_s[r] = l_s[r] * rf + sum;
                m_s[r] = mnew;
            }
        }
        __syncthreads();

        #pragma unroll
        for (int mi = 0; mi < 2; ++mi)
            #pragma unroll
            for (int q = 0; q < 4; ++q) {
                float rf = rf_s[wr + mi * 16 + hi * 4 + q];
                #pragma unroll
                for (int ni = 0; ni < 2; ++ni)
                    o[mi][ni][q] *= rf;
            }
        #pragma unroll
        for (int kk = 0; kk < 2; ++kk) {
            bf16x8 pf[2];
            #pragma unroll
            for (int mi = 0; mi < 2; ++mi)
                pf[mi] = *(const bf16x8*)&P_lds[(size_t)(wr + mi * 16 + lr) * PS
                                                + kk * 32 + kg];
            #pragma unroll
            for (int ni = 0; ni < 2; ++ni) {
                bf16x8 vf = *(const bf16x8*)&Vt_lds[(size_t)(wc + ni * 16 + lr) * VS
                                                    + kk * 32 + kg];
                #pragma unroll
                for (int mi = 0; mi < 2; ++mi)
                    o[mi][ni] = __builtin_amdgcn_mfma_f32_16x16x32_bf16(
                        pf[mi], vf, o[mi][ni], 0, 0, 0);
            }
        }
        __syncthreads();
    }

    #pragma unroll
    for (int mi = 0; mi < 2; ++mi)
        #pragma unroll
        for (int q = 0; q < 4; ++q) {
            int rl = wr + mi * 16 + hi * 4 + q;
            float inv = 1.0f / l_s[rl];
            #pragma unroll
            for (int ni = 0; ni < 2; ++ni)
                ctx[(tok0 + i0 + rl) * Hh + h * DHh + wc + ni * 16 + lr]
                    = f2bf(o[mi][ni][q] * inv);
        }
}

// ---------------------------------------------------------------------------
// 7. Fused MFMA classifier, fixed-shift LSE. Grid (NCH=42, 32).
// ---------------------------------------------------------------------------
__global__ __launch_bounds__(256) void cls_lse_kernel(
    const ushort* __restrict__ A,
    const ushort* __restrict__ WT,
    const float* __restrict__ cbp,
    const int* __restrict__ labels,
    float* __restrict__ psv, float* __restrict__ pll)
{
    __shared__ __align__(16) ushort As[128 * 32];
    __shared__ __align__(16) ushort Bs[128 * 32];
    __shared__ float ssum[2][128];
    __shared__ float sll[128];
    __shared__ int lab[128];
    const int tid = threadIdx.x;
    const int lane = tid & 63, wid = tid >> 6;
    const int m0 = blockIdx.y * 128;
    const int chunk = blockIdx.x;
    if (tid < 128) {
        sll[tid] = 0.f;
        lab[tid] = labels[m0 + tid];
    }
    const int wr = (wid >> 1) * 64, wcid = wid & 1, wc = wcid * 64;
    const int lr = lane & 15;
    const int hi = lane >> 4;
    const int kg = hi << 3;

    float sacc[16];
    #pragma unroll
    for (int i = 0; i < 16; ++i) sacc[i] = 0.f;

    for (int t = 0; t < TPC; ++t) {
        const int n0 = (chunk * TPC + t) * 128;
        f32x4 acc[4][4];
        #pragma unroll
        for (int mi = 0; mi < 4; ++mi)
            #pragma unroll
            for (int ni = 0; ni < 4; ++ni)
                acc[mi][ni] = (f32x4){0.f, 0.f, 0.f, 0.f};

        for (int k0 = 0; k0 < Hh; k0 += 32) {
            #pragma unroll
            for (int i = 0; i < 2; ++i) {
                int idx = i * 256 + tid;
                int r = idx >> 2, c = (idx & 3) << 3;
                __builtin_amdgcn_global_load_lds(
                    (const __attribute__((address_space(1))) void*)(A + (size_t)(m0 + r) * Hh + k0 + c),
                    (__attribute__((address_space(3))) void*)(As + (size_t)(i * 256 + (wid << 6)) * 8),
                    16, 0, 0);
            }
            #pragma unroll
            for (int i = 0; i < 2; ++i) {
                int idx = i * 256 + tid;
                int r = idx >> 2, c = (idx & 3) << 3;
                __builtin_amdgcn_global_load_lds(
                    (const __attribute__((address_space(1))) void*)(WT + (size_t)(n0 + r) * Hh + k0 + c),
                    (__attribute__((address_space(3))) void*)(Bs + (size_t)(i * 256 + (wid << 6)) * 8),
                    16, 0, 0);
            }
            __syncthreads();

            bf16x8 af[4], bfr[4];
            #pragma unroll
            for (int mi = 0; mi < 4; ++mi)
                af[mi] = *(const bf16x8*)(As + (size_t)(wr + mi * 16 + lr) * 32 + kg);
            #pragma unroll
            for (int ni = 0; ni < 4; ++ni)
                bfr[ni] = *(const bf16x8*)(Bs + (size_t)(wc + ni * 16 + lr) * 32 + kg);

            #pragma unroll
            for (int mi = 0; mi < 4; ++mi)
                #pragma unroll
                for (int ni = 0; ni < 4; ++ni)
                    acc[mi][ni] = __builtin_amdgcn_mfma_f32_16x16x32_bf16(
                        af[mi], bfr[ni], acc[mi][ni], 0, 0, 0);
            __syncthreads();
        }

        float bvs[4];
        int cols[4];
        #pragma unroll
        for (int ni = 0; ni < 4; ++ni) {
            cols[ni] = n0 + wc + ni * 16 + lr;
            bvs[ni] = cbp[cols[ni]];
        }
        #pragma unroll
        for (int mi = 0; mi < 4; ++mi) {
            #pragma unroll
            for (int q = 0; q < 4; ++q) {
                int rl = wr + mi * 16 + hi * 4 + q;
                float v0 = acc[mi][0][q] + bvs[0];
                float v1 = acc[mi][1][q] + bvs[1];
                float v2 = acc[mi][2][q] + bvs[2];
                float v3 = acc[mi][3][q] + bvs[3];
                int lb = lab[rl];
                if (lb == cols[0]) sll[rl] = v0;
                if (lb == cols[1]) sll[rl] = v1;
                if (lb == cols[2]) sll[rl] = v2;
                if (lb == cols[3]) sll[rl] = v3;
                sacc[mi * 4 + q] += __expf(v0 - LSE_SHIFT) + __expf(v1 - LSE_SHIFT)
                                  + __expf(v2 - LSE_SHIFT) + __expf(v3 - LSE_SHIFT);
            }
        }
    }

    #pragma unroll
    for (int mi = 0; mi < 4; ++mi) {
        #pragma unroll
        for (int q = 0; q < 4; ++q) {
            float s = sacc[mi * 4 + q];
            s += __shfl_xor(s, 1);
            s += __shfl_xor(s, 2);
            s += __shfl_xor(s, 4);
            s += __shfl_xor(s, 8);
            if (lr == 0) ssum[wcid][wr + mi * 16 + hi * 4 + q] = s;
        }
    }
    __syncthreads();
    if (tid < 128) {
        psv[(size_t)chunk * Mm + m0 + tid] = ssum[0][tid] + ssum[1][tid];
        pll[(size_t)chunk * Mm + m0 + tid] = sll[tid];
    }
}

// 7b. Merge chunk partials + masked per-sample mean (one block per batch)
__global__ __launch_bounds__(256) void cls_finish_kernel(
    const float* __restrict__ psv, const float* __restrict__ pll,
    const int* __restrict__ info, float* __restrict__ ps)
{
    int b = blockIdx.x, tid = threadIdx.x;
    int first = info[b * 4 + 0], has = info[b * 4 + 1];
    float sum = 0.f;
    #pragma unroll
    for (int rr = 0; rr < 2; ++rr) {
        int s = tid + rr * 256;
        int row = b * Ss + s;
        float sv = 0.f, l = 0.f;
        #pragma unroll 1
        for (int c = 0; c < NCH; ++c) {
            sv += psv[(size_t)c * Mm + row];
            l  += pll[(size_t)c * Mm + row];
        }
        float cev = (LSE_SHIFT + logf(sv)) - l;
        bool mv = has ? (s > first) : true;
        if (mv) sum += cev;
    }
    #pragma unroll
    for (int off = 32; off; off >>= 1) sum += __shfl_xor(sum, off);
    __shared__ float red[4];
    int lane = tid & 63, wid = tid >> 6;
    if (lane == 0) red[wid] = sum;
    __syncthreads();
    if (tid == 0) {
        float tot = red[0] + red[1] + red[2] + red[3];
        float cnt = has ? (float)(Ss - 1 - first) : (float)Ss;
        ps[b] = tot / cnt;
    }
}

__global__ void final_kernel(const float* __restrict__ ps, float* __restrict__ out)
{
    if (threadIdx.x == 0 && blockIdx.x == 0) {
        float t = 0.0f;
        #pragma unroll
        for (int b = 0; b < Bb; b++) t += ps[b];
        out[0] = t * (1.0f / Bb);
    }
}

// ---------------------------------------------------------------------------
// Host launcher
// ---------------------------------------------------------------------------
extern "C" void kernel_launch(void* const* d_in, const int* in_sizes, int n_in,
                              void* d_out, int out_size, void* d_ws, size_t ws_size,
                              hipStream_t stream)
{
    const int*   ids    = (const int*)d_in[0];
    const int*   labels = (const int*)d_in[1];
    const float* we     = (const float*)d_in[2];
    const float* pe     = (const float*)d_in[3];
    const float* te     = (const float*)d_in[4];
    const float* eg     = (const float*)d_in[5];
    const float* ebp    = (const float*)d_in[6];
    const float* Wq     = (const float*)d_in[7];
    const float* bq     = (const float*)d_in[8];
    const float* Wk     = (const float*)d_in[9];
    const float* bk     = (const float*)d_in[10];
    const float* Wv     = (const float*)d_in[11];
    const float* bv     = (const float*)d_in[12];
    const float* Wo     = (const float*)d_in[13];
    const float* bo     = (const float*)d_in[14];
    const float* l1g    = (const float*)d_in[15];
    const float* l1b    = (const float*)d_in[16];
    const float* W1     = (const float*)d_in[17];
    const float* b1     = (const float*)d_in[18];
    const float* W2     = (const float*)d_in[19];
    const float* b2     = (const float*)d_in[20];
    const float* l2g    = (const float*)d_in[21];
    const float* l2b    = (const float*)d_in[22];
    const float* cW     = (const float*)d_in[23];
    const float* cbias  = (const float*)d_in[24];

    const size_t MH  = (size_t)Mm * Hh;
    const size_t MF  = (size_t)Mm * Ff;
    const size_t HHe = (size_t)Hh * Hh;
    const size_t HFe = (size_t)Hh * Ff;

    // Workspace layout (~112 MB; proven >= 226.5 MB available)
    float* ws = (float*)d_ws;
    float* x      = ws;                                // MH f32
    float* ps     = x + MH;                            // 16 f32
    int*   info   = (int*)(ps + 16);                   // 64 ints reserved
    float* bqkv   = (float*)(info + 64);               // 2304 f32
    ushort* tmpb  = (ushort*)(bqkv + QKVN);            // 4*MH bf16 split-K partials
    ushort* xb    = tmpb + 4 * MH;                     // MH bf16
    ushort* qkvb  = xb + MH;                           // 3*MH bf16
    ushort* ctxb  = qkvb + 3 * MH;                     // MH
    ushort* f1b   = ctxb + MH;                         // MF
    ushort* wscr  = f1b + MF;                          // 4*HHe + 2*HFe bf16
    ushort* wqT = wscr;
    ushort* woT = wqT + 3 * HHe;                       // qkvoT[3] = Wo slot
    ushort* w1T = wscr + 4 * HHe;                      // [F][H]
    ushort* w2T = w1T + HFe;                           // [H][F]
    float* clsf = (float*)(w2T + HFe);
    float* cbp  = clsf;                                // VP
    float* psv  = cbp + VP;                            // NCH*Mm
    float* pll  = psv + (size_t)NCH * Mm;              // NCH*Mm
    ushort* cWT = qkvb;   // alias: qkvb..f1b dead at classifier time

    sep_kernel<<<Bb, 512, 0, stream>>>(ids, info);
    embed_ln_kernel<<<Mm, 256, 0, stream>>>(ids, we, pe, te, eg, ebp, x, xb);

    dim3 gQKV(QKVN / 128, Mm / 128);          // (18, 32)
    dim3 gWo(Hh / 128, Mm / 128, 4);          // (6, 32, 4) split-K
    dim3 gF(Ff / 128, Mm / 128);              // (24, 32)
    dim3 gW2(Hh / 128, Mm / 128, 4);          // (6, 32, 4) split-K
    dim3 gA(Ss / 64, Bb * NHh);               // (8, 96)

    for (int l = 0; l < Ll; l++) {
        const float* bo_l = bo + (size_t)l * Hh;
        const float* b1_l = b1 + (size_t)l * Ff;
        const float* b2_l = b2 + (size_t)l * Hh;
        const float* g1  = l1g + (size_t)l * Hh;
        const float* be1 = l1b + (size_t)l * Hh;
        const float* g2  = l2g + (size_t)l * Hh;
        const float* be2 = l2b + (size_t)l * Hh;

        prep_kernel<<<6913, 256, 0, stream>>>(
            Wq + (size_t)l * HHe, Wk + (size_t)l * HHe,
            Wv + (size_t)l * HHe, Wo + (size_t)l * HHe,
            W1 + (size_t)l * HFe, W2 + (size_t)l * HFe,
            bq + (size_t)l * Hh, bk + (size_t)l * Hh, bv + (size_t)l * Hh,
            wscr, w1T, w2T, bqkv);

        // Fused QKV projection: [M][768] @ [2304][768]^T -> [M][2304]
        mfma_gemm<0, 1, 1><<<gQKV, 256, 0, stream>>>(xb, wqT, bqkv, qkvb,
                                                     QKVN, Hh, Hh, Hh);

        flash_attn_kernel<<<gA, 256, 0, stream>>>(qkvb, info, ctxb);

        // Wo projection split-K x4: bf16 partials in tmpb, bias folded into LN
        mfma_gemm<0, 1, 0><<<gWo, 256, 0, stream>>>(ctxb, woT, nullptr, tmpb,
                                                    Hh, Hh / 4, Hh, Hh);
        resid_ln4_kernel<<<Mm, 256, 0, stream>>>(x, tmpb, bo_l, g1, be1, x, xb);

        mfma_gemm<1, 1, 1><<<gF, 256, 0, stream>>>(xb, w1T, b1_l, f1b,
                                                   Ff, Hh, Hh, Hh);
        // FFN2 split-K x4: bf16 partials in tmpb
        mfma_gemm<0, 1, 0><<<gW2, 256, 0, stream>>>(f1b, w2T, nullptr, tmpb,
                                                    Hh, Hh /*chunk*/, Ff, Ff);
        resid_ln4_kernel<<<Mm, 256, 0, stream>>>(x, tmpb, b2_l, g2, be2, x, xb);
    }

    // Classifier
    pad_transpose_kernel<<<dim3(VP / 32, Hh / 32), 256, 0, stream>>>(cW, cWT, Hh, Vv);
    bias_pad_kernel<<<(VP + 255) / 256, 256, 0, stream>>>(cbias, cbp);
    cls_lse_kernel<<<dim3(NCH, Mm / 128), 256, 0, stream>>>(
        xb, cWT, cbp, labels, psv, pll);
    cls_finish_kernel<<<Bb, 256, 0, stream>>>(psv, pll, info, ps);
    final_kernel<<<1, 64, 0, stream>>>(ps, (float*)d_out);
}